// Round 1
// baseline (445.757 us; speedup 1.0000x reference)
//
#include <hip/hip_runtime.h>
#include <math.h>

#define BB 4
#define HH 512
#define LL 4096
#define NN 32
#define DMOUT 512
#define SS 64
#define TT 64
#define HN (HH*NN)

// ---------------- Kernel A: per-(h,n) SSM constants ----------------
__global__ void prep_kernel(const float* __restrict__ log_dt,
                            const float* __restrict__ A_re, const float* __restrict__ A_im,
                            const float* __restrict__ B_re, const float* __restrict__ B_im,
                            const float* __restrict__ C_re, const float* __restrict__ C_im,
                            float* __restrict__ cst) {
    int idx = blockIdx.x * blockDim.x + threadIdx.x;
    if (idx >= HN) return;
    int h = idx / NN;
    float dt = expf(log_dt[h]);
    float ar = A_re[idx], ai = A_im[idx];
    float dtar = dt * ar, dtai = dt * ai;
    float ea = expf(dtar);
    float dA_r = ea * cosf(dtai), dA_i = ea * sinf(dtai);
    // (exp(dtA)-1)/A
    float em_r = dA_r - 1.0f, em_i = dA_i;
    float inv = 1.0f / (ar * ar + ai * ai);
    float t_r = (em_r * ar + em_i * ai) * inv;
    float t_i = (em_i * ar - em_r * ai) * inv;
    // * B
    float br = B_re[idx], bi = B_im[idx];
    float dB_r = t_r * br - t_i * bi;
    float dB_i = t_r * bi + t_i * br;
    cst[0 * HN + idx] = dtar;
    cst[1 * HN + idx] = dtai;
    cst[2 * HN + idx] = dA_r;
    cst[3 * HN + idx] = dA_i;
    cst[4 * HN + idx] = dB_r;
    cst[5 * HN + idx] = dB_i;
    cst[6 * HN + idx] = 2.0f * C_re[idx];
    cst[7 * HN + idx] = 2.0f * C_im[idx];
}

// ---------------- Kernel B: chunked-scan SSM conv + D skip + GELU ----------------
__global__ __launch_bounds__(256) void ssm_kernel(const float* __restrict__ u,
                                                  const float* __restrict__ D,
                                                  const float* __restrict__ cst,
                                                  float* __restrict__ yg) {
    const int h = blockIdx.x;
    const int b = blockIdx.y;
    const int tid = threadIdx.x;

    __shared__ float u_lds[LL];                    // 16 KB
    __shared__ float EcR[SS][NN + 1], EcI[SS][NN + 1];  // 2C * dA^{i+1}
    __shared__ float XR[TT][NN + 1], XI[TT][NN + 1];    // chunk summaries -> states
    __shared__ float kloc[SS];                     // first 64 real kernel taps

    const float* urow = u + ((size_t)(b * HH + h)) * LL;
    const float4* u4 = (const float4*)urow;
    float4* l4 = (float4*)u_lds;
#pragma unroll
    for (int r = 0; r < LL / 4 / 256; r++) l4[tid + 256 * r] = u4[tid + 256 * r];

    const float* dtAr = cst + 0 * HN + h * NN;
    const float* dtAi = cst + 1 * HN + h * NN;
    const float* dAr  = cst + 2 * HN + h * NN;
    const float* dAi  = cst + 3 * HN + h * NN;
    const float* dBr  = cst + 4 * HN + h * NN;
    const float* dBi  = cst + 5 * HN + h * NN;
    const float* tCr  = cst + 6 * HN + h * NN;
    const float* tCi  = cst + 7 * HN + h * NN;

    // kloc[j] = sum_n Re( (2C*dB) * dA^j )
    if (tid < SS) {
        float jf = (float)tid;
        float acc = 0.0f;
        for (int n = 0; n < NN; n++) {
            float mr = expf(jf * dtAr[n]);
            float ang = jf * dtAi[n];
            float pr = mr * cosf(ang), pi = mr * sinf(ang);
            float wr = tCr[n] * dBr[n] - tCi[n] * dBi[n];
            float wi = tCr[n] * dBi[n] + tCi[n] * dBr[n];
            acc += wr * pr - wi * pi;
        }
        kloc[tid] = acc;
    }
    // Ec[i][n] = 2C_n * dA_n^{i+1}
#pragma unroll
    for (int r = 0; r < (SS * NN) / 256; r++) {
        int id = tid + 256 * r;
        int i = id >> 5, n = id & 31;
        float f = (float)(i + 1);
        float mr = expf(f * dtAr[n]);
        float ang = f * dtAi[n];
        float pr = mr * cosf(ang), pi = mr * sinf(ang);
        EcR[i][n] = tCr[n] * pr - tCi[n] * pi;
        EcI[i][n] = tCr[n] * pi + tCi[n] * pr;
    }
    __syncthreads();

    // Phase 1: per-chunk Horner summaries F_t = dB * sum_j dA^{S-1-j} u[tS+j]
    {
        int n = tid & 31;
        int tb = tid >> 5;  // 0..7
        float ar_ = dAr[n], ai_ = dAi[n], br_ = dBr[n], bi_ = dBi[n];
#pragma unroll
        for (int rr = 0; rr < 4; rr++) {
            int t1 = tb + 8 * rr;
            int t2 = t1 + 32;
            float s1r = 0.f, s1i = 0.f, s2r = 0.f, s2i = 0.f;
            const float* up1 = u_lds + t1 * SS;
            const float* up2 = u_lds + t2 * SS;
#pragma unroll 8
            for (int j = 0; j < SS; j++) {
                float u1 = up1[j], u2 = up2[j];
                float n1r = s1r * ar_ - s1i * ai_ + u1;
                float n1i = s1r * ai_ + s1i * ar_;
                float n2r = s2r * ar_ - s2i * ai_ + u2;
                float n2i = s2r * ai_ + s2i * ar_;
                s1r = n1r; s1i = n1i; s2r = n2r; s2i = n2i;
            }
            XR[t1][n] = s1r * br_ - s1i * bi_;
            XI[t1][n] = s1r * bi_ + s1i * br_;
            XR[t2][n] = s2r * br_ - s2i * bi_;
            XI[t2][n] = s2r * bi_ + s2i * br_;
        }
    }
    __syncthreads();

    // Phase 2: sequential scan over chunks (in place: XR/XI[t] become state BEFORE chunk t)
    if (tid < NN) {
        int n = tid;
        float mr = expf(64.0f * dtAr[n]);
        float ang = 64.0f * dtAi[n];
        float Mr = mr * cosf(ang), Mi = mr * sinf(ang);
        float cr = 0.f, ci = 0.f;
        for (int t = 0; t < TT; t++) {
            float fr = XR[t][n], fi = XI[t][n];
            XR[t][n] = cr; XI[t][n] = ci;
            float nr = Mr * cr - Mi * ci + fr;
            float ni = Mr * ci + Mi * cr + fi;
            cr = nr; ci = ni;
        }
    }
    __syncthreads();

    // Phase 3: outputs
    float Dh = D[h];
    float* ygrow = yg + ((size_t)(b * HH + h)) * LL;
#pragma unroll
    for (int r = 0; r < LL / 256; r++) {
        int l = tid + 256 * r;
        int t = l >> 6, i = l & 63;
        float a0 = 0.f, a1 = 0.f;
#pragma unroll 8
        for (int n = 0; n < NN; n += 2) {
            a0 += EcR[i][n] * XR[t][n] - EcI[i][n] * XI[t][n];
            a1 += EcR[i][n + 1] * XR[t][n + 1] - EcI[i][n + 1] * XI[t][n + 1];
        }
        float c0 = 0.f, c1 = 0.f;
#pragma unroll 8
        for (int j = 0; j < SS; j += 2) {
            float uv0 = (j <= i) ? u_lds[l - j] : 0.0f;
            float uv1 = (j + 1 <= i) ? u_lds[l - j - 1] : 0.0f;
            c0 += kloc[j] * uv0;
            c1 += kloc[j + 1] * uv1;
        }
        float y = a0 + a1 + c0 + c1 + Dh * u_lds[l];
        float g = 0.5f * y * (1.0f + erff(y * 0.70710678118654752f));
        ygrow[l] = g;
    }
}

// ---------------- Kernel C: fused fp32 GEMM (both GLU halves) + bias + GLU ----------------
__global__ __launch_bounds__(256) void gemm_glu_kernel(const float* __restrict__ yg,
                                                       const float* __restrict__ W,
                                                       const float* __restrict__ bias,
                                                       float* __restrict__ out) {
    const int b = blockIdx.z;
    const int d0 = blockIdx.y * 64;
    const int l0 = blockIdx.x * 64;
    const int tid = threadIdx.x;
    const int tx = tid & 15, ty = tid >> 4;

    __shared__ float Ys[32][64];
    __shared__ float W1s[64][33], W2s[64][33];

    float acc1[4][4] = {{0.f}};
    float acc2[4][4] = {{0.f}};

    for (int kt = 0; kt < 16; kt++) {
        int h0 = kt * 32;
        __syncthreads();
        // stage y tile (32 h x 64 l)
#pragma unroll
        for (int q = 0; q < 2; q++) {
            int f4 = tid + 256 * q;
            int kk = f4 >> 4, c4 = f4 & 15;
            float4 v = *(const float4*)(yg + ((size_t)(b * HH) + h0 + kk) * LL + l0 + c4 * 4);
            *(float4*)(&Ys[kk][c4 * 4]) = v;
        }
        // stage W tiles (64 d x 32 h, both halves)
#pragma unroll
        for (int q = 0; q < 2; q++) {
            int f4 = tid + 256 * q;
            int dd = f4 >> 3, k4 = f4 & 7;
            float4 w1 = *(const float4*)(W + (size_t)(d0 + dd) * HH + h0 + k4 * 4);
            float4 w2 = *(const float4*)(W + (size_t)(DMOUT + d0 + dd) * HH + h0 + k4 * 4);
            W1s[dd][k4 * 4 + 0] = w1.x; W1s[dd][k4 * 4 + 1] = w1.y;
            W1s[dd][k4 * 4 + 2] = w1.z; W1s[dd][k4 * 4 + 3] = w1.w;
            W2s[dd][k4 * 4 + 0] = w2.x; W2s[dd][k4 * 4 + 1] = w2.y;
            W2s[dd][k4 * 4 + 2] = w2.z; W2s[dd][k4 * 4 + 3] = w2.w;
        }
        __syncthreads();
#pragma unroll 4
        for (int kk = 0; kk < 32; kk++) {
            float4 yv4 = *(const float4*)(&Ys[kk][tx * 4]);
            float yv[4] = {yv4.x, yv4.y, yv4.z, yv4.w};
            float w1j[4], w2j[4];
#pragma unroll
            for (int j = 0; j < 4; j++) {
                w1j[j] = W1s[ty * 4 + j][kk];
                w2j[j] = W2s[ty * 4 + j][kk];
            }
#pragma unroll
            for (int j = 0; j < 4; j++) {
#pragma unroll
                for (int q = 0; q < 4; q++) {
                    acc1[j][q] += w1j[j] * yv[q];
                    acc2[j][q] += w2j[j] * yv[q];
                }
            }
        }
    }
    // epilogue: bias + GLU, vectorized store
#pragma unroll
    for (int j = 0; j < 4; j++) {
        int d = d0 + ty * 4 + j;
        float b1 = bias[d], b2 = bias[DMOUT + d];
        float4 o;
        float z1, z2;
        z1 = acc1[j][0] + b1; z2 = acc2[j][0] + b2; o.x = z1 * (1.0f / (1.0f + expf(-z2)));
        z1 = acc1[j][1] + b1; z2 = acc2[j][1] + b2; o.y = z1 * (1.0f / (1.0f + expf(-z2)));
        z1 = acc1[j][2] + b1; z2 = acc2[j][2] + b2; o.z = z1 * (1.0f / (1.0f + expf(-z2)));
        z1 = acc1[j][3] + b1; z2 = acc2[j][3] + b2; o.w = z1 * (1.0f / (1.0f + expf(-z2)));
        *(float4*)(out + ((size_t)(b * DMOUT) + d) * LL + l0 + tx * 4) = o;
    }
}

extern "C" void kernel_launch(void* const* d_in, const int* in_sizes, int n_in,
                              void* d_out, int out_size, void* d_ws, size_t ws_size,
                              hipStream_t stream) {
    const float* u      = (const float*)d_in[0];
    const float* log_dt = (const float*)d_in[1];
    const float* A_re   = (const float*)d_in[2];
    const float* A_im   = (const float*)d_in[3];
    const float* B_re   = (const float*)d_in[4];
    const float* B_im   = (const float*)d_in[5];
    const float* C_re   = (const float*)d_in[6];
    const float* C_im   = (const float*)d_in[7];
    const float* D      = (const float*)d_in[8];
    const float* W      = (const float*)d_in[9];
    const float* bias   = (const float*)d_in[10];
    float* out = (float*)d_out;

    float* ws = (float*)d_ws;
    float* yg  = ws;                              // BB*HH*LL floats = 32 MB
    float* cst = ws + (size_t)BB * HH * LL;       // 8*HN floats

    prep_kernel<<<HN / 256, 256, 0, stream>>>(log_dt, A_re, A_im, B_re, B_im, C_re, C_im, cst);
    ssm_kernel<<<dim3(HH, BB), 256, 0, stream>>>(u, D, cst, yg);
    gemm_glu_kernel<<<dim3(LL / 64, DMOUT / 64, BB), 256, 0, stream>>>(yg, W, bias, out);
}

// Round 2
// 321.508 us; speedup vs baseline: 1.3865x; 1.3865x over previous
//
#include <hip/hip_runtime.h>
#include <math.h>

#define BB 4
#define HH 512
#define LL 4096
#define NN 32
#define DMOUT 512
#define HN (HH*NN)

typedef __attribute__((ext_vector_type(8))) short short8;
typedef __attribute__((ext_vector_type(4))) float f32x4;

__device__ __forceinline__ unsigned f2bf(float x) {
    unsigned u = __float_as_uint(x);
    return (u + 0x7fffu + ((u >> 16) & 1u)) >> 16;
}

__device__ __forceinline__ void gload_lds16(const void* g, void* l) {
    __builtin_amdgcn_global_load_lds((const __attribute__((address_space(1))) void*)g,
                                     (__attribute__((address_space(3))) void*)l, 16, 0, 0);
}

// ---------------- Kernel A: per-(h,n) SSM constants ----------------
__global__ void prep_kernel(const float* __restrict__ log_dt,
                            const float* __restrict__ A_re, const float* __restrict__ A_im,
                            const float* __restrict__ B_re, const float* __restrict__ B_im,
                            const float* __restrict__ C_re, const float* __restrict__ C_im,
                            float* __restrict__ cst) {
    int idx = blockIdx.x * blockDim.x + threadIdx.x;
    if (idx >= HN) return;
    int h = idx / NN;
    float dt = expf(log_dt[h]);
    float ar = A_re[idx], ai = A_im[idx];
    float dtar = dt * ar, dtai = dt * ai;
    float ea = expf(dtar);
    float dA_r = ea * cosf(dtai), dA_i = ea * sinf(dtai);
    float em_r = dA_r - 1.0f, em_i = dA_i;
    float inv = 1.0f / (ar * ar + ai * ai);
    float t_r = (em_r * ar + em_i * ai) * inv;
    float t_i = (em_i * ar - em_r * ai) * inv;
    float br = B_re[idx], bi = B_im[idx];
    float dB_r = t_r * br - t_i * bi;
    float dB_i = t_r * bi + t_i * br;
    cst[0 * HN + idx] = dtar;
    cst[1 * HN + idx] = dtai;
    cst[2 * HN + idx] = dA_r;
    cst[3 * HN + idx] = dA_i;
    cst[4 * HN + idx] = dB_r;
    cst[5 * HN + idx] = dB_i;
    cst[6 * HN + idx] = 2.0f * C_re[idx];
    cst[7 * HN + idx] = 2.0f * C_im[idx];
}

// ---------------- Kernel A2: W -> bf16 hi split (optional, needs ws room) ----------------
__global__ void wsplit_kernel(const float* __restrict__ W, unsigned short* __restrict__ whi) {
    int i = (blockIdx.x * 256 + threadIdx.x) * 4;
    float4 w = *(const float4*)(W + i);
    ushort4 o;
    o.x = (unsigned short)f2bf(w.x);
    o.y = (unsigned short)f2bf(w.y);
    o.z = (unsigned short)f2bf(w.z);
    o.w = (unsigned short)f2bf(w.w);
    *(ushort4*)(whi + i) = o;
}

// ---------------- Kernel B: chunked-scan SSM conv + D skip + GELU -> packed bf16 hi/lo ----------------
__global__ __launch_bounds__(256) void ssm_kernel(const float* __restrict__ u,
                                                  const float* __restrict__ D,
                                                  const float* __restrict__ cst,
                                                  unsigned* __restrict__ ypack) {
    const int h = blockIdx.x;
    const int b = blockIdx.y;
    const int tid = threadIdx.x;

    __shared__ float u_lds[LL];        // 16 KB
    __shared__ float XR[64 * 32];      // 8 KB
    __shared__ float XI[64 * 32];      // 8 KB
    __shared__ float karr[128];        // zero-padded kernel taps

    const float* urow = u + ((size_t)(b * HH + h)) * LL;
    {
        const float4* u4 = (const float4*)urow;
        float4* l4 = (float4*)u_lds;
#pragma unroll
        for (int r = 0; r < 4; r++) l4[tid + 256 * r] = u4[tid + 256 * r];
    }

    const float* dtAr = cst + 0 * HN + h * NN;
    const float* dtAi = cst + 1 * HN + h * NN;
    const float* dAr  = cst + 2 * HN + h * NN;
    const float* dAi  = cst + 3 * HN + h * NN;
    const float* dBr  = cst + 4 * HN + h * NN;
    const float* dBi  = cst + 5 * HN + h * NN;
    const float* tCr  = cst + 6 * HN + h * NN;
    const float* tCi  = cst + 7 * HN + h * NN;

    // karr[0..63] = 0 ; karr[64+j] = k[j] = Re(sum_n (2C*dB)*dA^j)
    if (tid < 64) {
        karr[tid] = 0.0f;
        float jf = (float)tid;
        float acc = 0.0f;
        for (int n = 0; n < NN; n++) {
            float mr = expf(jf * dtAr[n]);
            float s, c;
            sincosf(jf * dtAi[n], &s, &c);
            float pr = mr * c, pi = mr * s;
            float wr = tCr[n] * dBr[n] - tCi[n] * dBi[n];
            float wi = tCr[n] * dBi[n] + tCi[n] * dBr[n];
            acc += wr * pr - wi * pi;
        }
        karr[64 + tid] = acc;
    }
    __syncthreads();

    // ---- Phase 1: per-chunk Horner summaries (8-sample groups), F_t*dB -> XR/XI[t]
    {
        int n = tid & 31;
        int g = tid >> 5;  // 0..7, chunks g*8..g*8+7
        float P1r = dAr[n], P1i = dAi[n];
        float P2r = P1r * P1r - P1i * P1i, P2i = 2.0f * P1r * P1i;
        float P3r = P2r * P1r - P2i * P1i, P3i = P2r * P1i + P2i * P1r;
        float P4r = P3r * P1r - P3i * P1i, P4i = P3r * P1i + P3i * P1r;
        float P5r = P4r * P1r - P4i * P1i, P5i = P4r * P1i + P4i * P1r;
        float P6r = P5r * P1r - P5i * P1i, P6i = P5r * P1i + P5i * P1r;
        float P7r = P6r * P1r - P6i * P1i, P7i = P6r * P1i + P6i * P1r;
        float P8r = P7r * P1r - P7i * P1i, P8i = P7r * P1i + P7i * P1r;
        float br = dBr[n], bi = dBi[n];
#pragma unroll
        for (int kc = 0; kc < 8; kc++) {
            int t = g * 8 + kc;
            const float* ub = u_lds + t * 64;
            float sr = 0.0f, si = 0.0f;
#pragma unroll
            for (int q = 0; q < 8; q++) {
                float4 a = *(const float4*)(ub + q * 8);
                float4 c = *(const float4*)(ub + q * 8 + 4);
                float pr = fmaf(a.x, P7r, fmaf(a.y, P6r, fmaf(a.z, P5r, fmaf(a.w, P4r,
                           fmaf(c.x, P3r, fmaf(c.y, P2r, fmaf(c.z, P1r, c.w)))))));
                float pi = fmaf(a.x, P7i, fmaf(a.y, P6i, fmaf(a.z, P5i, fmaf(a.w, P4i,
                           fmaf(c.x, P3i, fmaf(c.y, P2i, c.z * P1i))))));
                float nsr = fmaf(sr, P8r, fmaf(-si, P8i, pr));
                float nsi = fmaf(sr, P8i, fmaf(si, P8r, pi));
                sr = nsr; si = nsi;
            }
            XR[t * 32 + n] = fmaf(sr, br, -si * bi);
            XI[t * 32 + n] = fmaf(sr, bi, si * br);
        }
    }
    __syncthreads();

    // ---- Phase 2: sequential scan over 64 chunks (XR/XI[t] <- state BEFORE chunk t)
    if (tid < 32) {
        int n = tid;
        float mr = expf(64.0f * dtAr[n]);
        float s, c;
        sincosf(64.0f * dtAi[n], &s, &c);
        float Mr = mr * c, Mi = mr * s;
        float cr = 0.0f, ci = 0.0f;
        for (int t = 0; t < 64; t++) {
            float fr = XR[t * 32 + n], fi2 = XI[t * 32 + n];
            XR[t * 32 + n] = cr;
            XI[t * 32 + n] = ci;
            float nr = fmaf(Mr, cr, fmaf(-Mi, ci, fr));
            float ni = fmaf(Mr, ci, fmaf(Mi, cr, fi2));
            cr = nr; ci = ni;
        }
    }
    __syncthreads();

    // ---- Phase 3: outputs; lane i fixed per thread; Ec in registers
    {
        const int lane = tid & 63;
        const int w = tid >> 6;
        float ecr[32], eci[32];
        float fi = (float)(lane + 1);
#pragma unroll
        for (int n = 0; n < 32; n++) {
            float mr = expf(fi * dtAr[n]);
            float s, c;
            sincosf(fi * dtAi[n], &s, &c);
            float pr = mr * c, pi = mr * s;
            ecr[n] = tCr[n] * pr - tCi[n] * pi;
            eci[n] = tCr[n] * pi + tCi[n] * pr;
        }
        float Dh = D[h];
        unsigned* orow = ypack + ((size_t)(b * HH + h)) * LL;
#pragma unroll 2
        for (int k = 0; k < 16; k++) {
            int t = w * 16 + k;
            int l = t * 64 + lane;
            const float* xr = XR + t * 32;
            const float* xi = XI + t * 32;
            float acc = 0.0f;
#pragma unroll
            for (int n4 = 0; n4 < 8; n4++) {
                float4 a = *(const float4*)(xr + n4 * 4);
                float4 bq = *(const float4*)(xi + n4 * 4);
                acc = fmaf(ecr[n4 * 4 + 0], a.x, acc); acc = fmaf(-eci[n4 * 4 + 0], bq.x, acc);
                acc = fmaf(ecr[n4 * 4 + 1], a.y, acc); acc = fmaf(-eci[n4 * 4 + 1], bq.y, acc);
                acc = fmaf(ecr[n4 * 4 + 2], a.z, acc); acc = fmaf(-eci[n4 * 4 + 2], bq.z, acc);
                acc = fmaf(ecr[n4 * 4 + 3], a.w, acc); acc = fmaf(-eci[n4 * 4 + 3], bq.w, acc);
            }
            float cv = 0.0f;
            const float* ub = u_lds + t * 64;
#pragma unroll
            for (int m4 = 0; m4 < 16; m4++) {
                float4 uu = *(const float4*)(ub + m4 * 4);
                cv = fmaf(karr[64 + lane - (m4 * 4 + 0)], uu.x, cv);
                cv = fmaf(karr[64 + lane - (m4 * 4 + 1)], uu.y, cv);
                cv = fmaf(karr[64 + lane - (m4 * 4 + 2)], uu.z, cv);
                cv = fmaf(karr[64 + lane - (m4 * 4 + 3)], uu.w, cv);
            }
            float y = acc + cv + Dh * u_lds[l];
            float gl = 0.5f * y * (1.0f + erff(y * 0.70710678118654752f));
            unsigned hb = f2bf(gl);
            float ghi = __uint_as_float(hb << 16);
            unsigned lb = f2bf(gl - ghi);
            orow[l] = (hb << 16) | lb;
        }
    }
}

// ---------------- Kernel C: MFMA bf16 GEMM (y hi/lo split) + bias + GLU ----------------
__global__ __launch_bounds__(256) void gemm_glu_mfma(const unsigned* __restrict__ ypack,
                                                     const float* __restrict__ W,
                                                     const unsigned short* __restrict__ whi,
                                                     const float* __restrict__ bias,
                                                     float* __restrict__ out, int preW) {
    const int b = blockIdx.z;
    const int d0 = blockIdx.x * 64;    // d-tile fast dim -> same-Y blocks concurrent
    const int l0 = blockIdx.y * 128;
    const int tid = threadIdx.x;
    const int lane = tid & 63;
    const int wid = tid >> 6;
    const int wave_m = wid & 1;
    const int wave_n = wid >> 1;

    __shared__ unsigned Ysh[32 * 128];   // 16 KB packed bf16 hi|lo, col-xor-swizzled
    __shared__ char Wlds[128 * 64];      // 8 KB bf16-hi, group-xor-swizzled

    f32x4 acc[4][4];
#pragma unroll
    for (int i = 0; i < 4; i++)
#pragma unroll
        for (int j = 0; j < 4; j++) acc[i][j] = (f32x4){0.f, 0.f, 0.f, 0.f};

    for (int kt = 0; kt < 16; kt++) {
        const int h0 = kt * 32;
        __syncthreads();
        // ---- stage Y tile [32 k][128 l] via global_load_lds, source pre-swizzled
#pragma unroll
        for (int q = 0; q < 4; q++) {
            int cid = q * 256 + tid;          // 16B chunk id, 0..1023
            int kr = cid >> 5;                // k row 0..31
            int c0 = (cid & 31) * 4;          // col0
            int sc = c0 ^ ((kr & 8) ? 16 : 0);
            const unsigned* src = ypack + ((size_t)(b * HH + h0 + kr)) * LL + l0 + sc;
            gload_lds16(src, (char*)Ysh + cid * 16);
        }
        // ---- stage W-hi tile [128 row][32 k] bf16, swizzled groups
        if (preW) {
#pragma unroll
            for (int e = 0; e < 2; e++) {
                int c = e * 256 + tid;        // 0..511
                int row = c >> 2;
                int gx = c & 3;
                int qq = (row >> 1) & 3;
                int grow = (row < 64) ? (d0 + row) : (448 + d0 + row);
                const unsigned short* src = whi + (size_t)grow * 512 + h0 + ((gx ^ qq) * 8);
                gload_lds16(src, Wlds + c * 16);
            }
        } else {
            int row = tid >> 1;
            int kb = (tid & 1) * 16;
            int qq = (row >> 1) & 3;
            int grow = (row < 64) ? (d0 + row) : (448 + d0 + row);
            const float* src = W + (size_t)grow * 512 + h0 + kb;
            float4 w0 = *(const float4*)(src);
            float4 w1 = *(const float4*)(src + 4);
            float4 w2 = *(const float4*)(src + 8);
            float4 w3 = *(const float4*)(src + 12);
            short8 v0, v1;
            v0[0] = (short)f2bf(w0.x); v0[1] = (short)f2bf(w0.y);
            v0[2] = (short)f2bf(w0.z); v0[3] = (short)f2bf(w0.w);
            v0[4] = (short)f2bf(w1.x); v0[5] = (short)f2bf(w1.y);
            v0[6] = (short)f2bf(w1.z); v0[7] = (short)f2bf(w1.w);
            v1[0] = (short)f2bf(w2.x); v1[1] = (short)f2bf(w2.y);
            v1[2] = (short)f2bf(w2.z); v1[3] = (short)f2bf(w2.w);
            v1[4] = (short)f2bf(w3.x); v1[5] = (short)f2bf(w3.y);
            v1[6] = (short)f2bf(w3.z); v1[7] = (short)f2bf(w3.w);
            int g0 = kb >> 3;  // 0 or 2
            *(short8*)(Wlds + row * 64 + ((g0 ^ qq) * 16)) = v0;
            *(short8*)(Wlds + row * 64 + (((g0 + 1) ^ qq) * 16)) = v1;
        }
        __syncthreads();

        // ---- fragments + MFMA
        short8 af[4];
#pragma unroll
        for (int mi = 0; mi < 4; mi++) {
            int rowb = (mi < 2) ? (wave_m * 32 + mi * 16) : (64 + wave_m * 32 + (mi - 2) * 16);
            int row = rowb + (lane & 15);
            int qq = (row >> 1) & 3;
            int gp = lane >> 4;
            af[mi] = *(const short8*)(Wlds + row * 64 + ((gp ^ qq) * 16));
        }
#pragma unroll
        for (int ni = 0; ni < 4; ni++) {
            int col = wave_n * 64 + ni * 16 + (lane & 15);
            int g = lane >> 4;
            int cs = col ^ ((g & 1) << 4);
            const unsigned* yb = Ysh + (8 * g) * 128 + cs;
            unsigned p0 = yb[0 * 128], p1 = yb[1 * 128], p2 = yb[2 * 128], p3 = yb[3 * 128];
            unsigned p4 = yb[4 * 128], p5 = yb[5 * 128], p6 = yb[6 * 128], p7 = yb[7 * 128];
            short8 bh, bl;
            bh[0] = (short)(p0 >> 16); bl[0] = (short)(p0 & 0xffff);
            bh[1] = (short)(p1 >> 16); bl[1] = (short)(p1 & 0xffff);
            bh[2] = (short)(p2 >> 16); bl[2] = (short)(p2 & 0xffff);
            bh[3] = (short)(p3 >> 16); bl[3] = (short)(p3 & 0xffff);
            bh[4] = (short)(p4 >> 16); bl[4] = (short)(p4 & 0xffff);
            bh[5] = (short)(p5 >> 16); bl[5] = (short)(p5 & 0xffff);
            bh[6] = (short)(p6 >> 16); bl[6] = (short)(p6 & 0xffff);
            bh[7] = (short)(p7 >> 16); bl[7] = (short)(p7 & 0xffff);
#pragma unroll
            for (int mi = 0; mi < 4; mi++) {
                acc[mi][ni] = __builtin_amdgcn_mfma_f32_16x16x32_bf16(af[mi], bh, acc[mi][ni], 0, 0, 0);
                acc[mi][ni] = __builtin_amdgcn_mfma_f32_16x16x32_bf16(af[mi], bl, acc[mi][ni], 0, 0, 0);
            }
        }
    }

    // ---- epilogue: bias + GLU (wave holds both halves for its d rows)
#pragma unroll
    for (int mi = 0; mi < 2; mi++) {
        int dbase = d0 + wave_m * 32 + mi * 16 + ((lane >> 4) << 2);
#pragma unroll
        for (int r = 0; r < 4; r++) {
            int d = dbase + r;
            float b1 = bias[d], b2 = bias[DMOUT + d];
#pragma unroll
            for (int ni = 0; ni < 4; ni++) {
                int l = l0 + wave_n * 64 + ni * 16 + (lane & 15);
                float z1 = acc[mi][ni][r] + b1;
                float z2 = acc[mi + 2][ni][r] + b2;
                out[((size_t)(b * DMOUT + d)) * LL + l] = z1 * (1.0f / (1.0f + expf(-z2)));
            }
        }
    }
}

extern "C" void kernel_launch(void* const* d_in, const int* in_sizes, int n_in,
                              void* d_out, int out_size, void* d_ws, size_t ws_size,
                              hipStream_t stream) {
    const float* u      = (const float*)d_in[0];
    const float* log_dt = (const float*)d_in[1];
    const float* A_re   = (const float*)d_in[2];
    const float* A_im   = (const float*)d_in[3];
    const float* B_re   = (const float*)d_in[4];
    const float* B_im   = (const float*)d_in[5];
    const float* C_re   = (const float*)d_in[6];
    const float* C_im   = (const float*)d_in[7];
    const float* D      = (const float*)d_in[8];
    const float* W      = (const float*)d_in[9];
    const float* bias   = (const float*)d_in[10];
    float* out = (float*)d_out;

    char* ws = (char*)d_ws;
    unsigned* ypack = (unsigned*)ws;                                   // 33,554,432 B
    float* cst = (float*)(ws + 33554432);                              // 524,288 B
    unsigned short* whi = (unsigned short*)(ws + 33554432 + 524288);   // 1,048,576 B (optional)
    int preW = (ws_size >= (size_t)(33554432 + 524288 + 1048576)) ? 1 : 0;

    prep_kernel<<<HN / 256, 256, 0, stream>>>(log_dt, A_re, A_im, B_re, B_im, C_re, C_im, cst);
    if (preW) wsplit_kernel<<<512, 256, 0, stream>>>(W, whi);
    ssm_kernel<<<dim3(HH, BB), 256, 0, stream>>>(u, D, cst, ypack);
    gemm_glu_mfma<<<dim3(8, 32, BB), 256, 0, stream>>>(ypack, W, whi, bias, out, preW);
}

// Round 4
// 143.462 us; speedup vs baseline: 3.1071x; 2.2411x over previous
//
#include <hip/hip_runtime.h>
#include <math.h>

#define BB 4
#define HH 512
#define LL 4096
#define NN 32
#define DMOUT 512
#define HN (HH*NN)

typedef __attribute__((ext_vector_type(8))) short short8;
typedef __attribute__((ext_vector_type(4))) float f32x4;

__device__ __forceinline__ unsigned f2bf(float x) {
    unsigned u = __float_as_uint(x);
    return (u + 0x7fffu + ((u >> 16) & 1u)) >> 16;
}
__device__ __forceinline__ unsigned packhl(float x) {
    unsigned hb = f2bf(x);
    float xh = __uint_as_float(hb << 16);
    return (hb << 16) | f2bf(x - xh);
}
__device__ __forceinline__ void cvt8(const float* p, short8 &h, short8 &l) {
    float4 a = *(const float4*)p;
    float4 b = *(const float4*)(p + 4);
    unsigned v;
    v = packhl(a.x); h[0] = (short)(v >> 16); l[0] = (short)(v & 0xffffu);
    v = packhl(a.y); h[1] = (short)(v >> 16); l[1] = (short)(v & 0xffffu);
    v = packhl(a.z); h[2] = (short)(v >> 16); l[2] = (short)(v & 0xffffu);
    v = packhl(a.w); h[3] = (short)(v >> 16); l[3] = (short)(v & 0xffffu);
    v = packhl(b.x); h[4] = (short)(v >> 16); l[4] = (short)(v & 0xffffu);
    v = packhl(b.y); h[5] = (short)(v >> 16); l[5] = (short)(v & 0xffffu);
    v = packhl(b.z); h[6] = (short)(v >> 16); l[6] = (short)(v & 0xffffu);
    v = packhl(b.w); h[7] = (short)(v >> 16); l[7] = (short)(v & 0xffffu);
}
__device__ __forceinline__ void gload_lds16(const void* g, void* l) {
    __builtin_amdgcn_global_load_lds((const __attribute__((address_space(1))) void*)g,
                                     (__attribute__((address_space(3))) void*)l, 16, 0, 0);
}

// ---------------- Kernel A2: W -> bf16 hi split ----------------
__global__ void wsplit_kernel(const float* __restrict__ W, unsigned short* __restrict__ whi) {
    int i = (blockIdx.x * 256 + threadIdx.x) * 4;
    float4 w = *(const float4*)(W + i);
    ushort4 o;
    o.x = (unsigned short)f2bf(w.x);
    o.y = (unsigned short)f2bf(w.y);
    o.z = (unsigned short)f2bf(w.z);
    o.w = (unsigned short)f2bf(w.w);
    *(ushort4*)(whi + i) = o;
}

// ---------------- Kernel B: SSM conv via MFMA chunked scan + D skip + GELU ----------------
__global__ __launch_bounds__(256, 4) void ssm_kernel(
    const float* __restrict__ u, const float* __restrict__ log_dt,
    const float* __restrict__ A_re, const float* __restrict__ A_im,
    const float* __restrict__ B_re, const float* __restrict__ B_im,
    const float* __restrict__ C_re, const float* __restrict__ C_im,
    const float* __restrict__ D, unsigned* __restrict__ ypack) {
    const int h = blockIdx.x;
    const int b = blockIdx.y;
    const int tid = threadIdx.x;
    const int lane = tid & 63;
    const int w = tid >> 6;
    const int g = lane >> 4;

    __shared__ float u_lds[64 * 68];       // 17.4 KB, [t][m] pad 68
    __shared__ unsigned XsR[32 * 65];      // 8.3 KB  (F real -> packed state)
    __shared__ unsigned XsI[32 * 65];      // 8.3 KB
    __shared__ float karr[128];            // taps, zero-padded below 64
    __shared__ unsigned karr_pk[128];      // hi/lo packed taps
    __shared__ float cst_lds[256];         // 8 rows x 32 modes

    // ---- stage u into [t][68] padded layout
    {
        const float* urow = u + ((size_t)(b * HH + h)) * LL;
        const float4* up = (const float4*)(urow + tid * 16);
        float4 v0 = up[0], v1 = up[1], v2 = up[2], v3 = up[3];
        int t = tid >> 2, mb = (tid & 3) * 16;
        float* dst = u_lds + t * 68 + mb;
        *(float4*)dst = v0; *(float4*)(dst + 4) = v1;
        *(float4*)(dst + 8) = v2; *(float4*)(dst + 12) = v3;
    }
    // ---- per-mode constants (folded prep)
    if (tid < 32) {
        int n = tid;
        float dt = expf(log_dt[h]);
        float ar = A_re[h * NN + n], ai = A_im[h * NN + n];
        float dtar = dt * ar, dtai = dt * ai;
        float ea = expf(dtar);
        float s, c; sincosf(dtai, &s, &c);
        float dA_r = ea * c, dA_i = ea * s;
        float em_r = dA_r - 1.0f, em_i = dA_i;
        float inv = 1.0f / (ar * ar + ai * ai);
        float t_r = (em_r * ar + em_i * ai) * inv;
        float t_i = (em_i * ar - em_r * ai) * inv;
        float br = B_re[h * NN + n], bi = B_im[h * NN + n];
        cst_lds[0 * 32 + n] = dtar;
        cst_lds[1 * 32 + n] = dtai;
        cst_lds[2 * 32 + n] = dA_r;
        cst_lds[3 * 32 + n] = dA_i;
        cst_lds[4 * 32 + n] = t_r * br - t_i * bi;
        cst_lds[5 * 32 + n] = t_r * bi + t_i * br;
        cst_lds[6 * 32 + n] = 2.0f * C_re[h * NN + n];
        cst_lds[7 * 32 + n] = 2.0f * C_im[h * NN + n];
    }
    __syncthreads();

    // ---- kernel taps k[j] (threads 0..63)
    if (tid < 64) {
        karr[tid] = 0.0f;
        float jf = (float)tid;
        float acc = 0.0f;
        for (int n = 0; n < NN; n++) {
            float mr = expf(jf * cst_lds[0 * 32 + n]);
            float s, c; sincosf(jf * cst_lds[1 * 32 + n], &s, &c);
            float pr = mr * c, pi = mr * s;
            float dbr = cst_lds[4 * 32 + n], dbi = cst_lds[5 * 32 + n];
            float tcr = cst_lds[6 * 32 + n], tci = cst_lds[7 * 32 + n];
            float wr = tcr * dbr - tci * dbi;
            float wi = tcr * dbi + tci * dbr;
            acc += wr * pr - wi * pi;
        }
        karr[64 + tid] = acc;
    }

    // ---- Phase 1 (MFMA): F[n'][t] = sum_m A3[n'][m] * u[t*64+m]
    // wave w owns rows n' in [16w,16w+16): w<2 -> real part rows, w>=2 -> imag
    {
        int nprime = w * 16 + (lane & 15);
        int isReal = (nprime < 32);
        int n = isReal ? nprime : (nprime - 32);
        float dtar = cst_lds[0 * 32 + n], dtai = cst_lds[1 * 32 + n];
        float dbr = cst_lds[4 * 32 + n], dbi = cst_lds[5 * 32 + n];
        short8 a3h0, a3l0, a3h1, a3l1;
#pragma unroll
        for (int j = 0; j < 8; j++) {
            {
                int m = g * 8 + j;
                float p = (float)(63 - m);
                float mr = expf(p * dtar);
                float s, c; sincosf(p * dtai, &s, &c);
                float pr = mr * c, pi = mr * s;
                float val = isReal ? (dbr * pr - dbi * pi) : (dbr * pi + dbi * pr);
                unsigned v = packhl(val);
                a3h0[j] = (short)(v >> 16); a3l0[j] = (short)(v & 0xffffu);
            }
            {
                int m = 32 + g * 8 + j;
                float p = (float)(63 - m);
                float mr = expf(p * dtar);
                float s, c; sincosf(p * dtai, &s, &c);
                float pr = mr * c, pi = mr * s;
                float val = isReal ? (dbr * pr - dbi * pi) : (dbr * pi + dbi * pr);
                unsigned v = packhl(val);
                a3h1[j] = (short)(v >> 16); a3l1[j] = (short)(v & 0xffffu);
            }
        }
#pragma unroll
        for (int ni = 0; ni < 4; ni++) {
            int t = ni * 16 + (lane & 15);
            const float* ub = u_lds + t * 68;
            short8 uh0, ul0, uh1, ul1;
            cvt8(ub + g * 8, uh0, ul0);
            cvt8(ub + 32 + g * 8, uh1, ul1);
            f32x4 a = (f32x4){0.f, 0.f, 0.f, 0.f};
            a = __builtin_amdgcn_mfma_f32_16x16x32_bf16(a3h0, uh0, a, 0, 0, 0);
            a = __builtin_amdgcn_mfma_f32_16x16x32_bf16(a3h0, ul0, a, 0, 0, 0);
            a = __builtin_amdgcn_mfma_f32_16x16x32_bf16(a3l0, uh0, a, 0, 0, 0);
            a = __builtin_amdgcn_mfma_f32_16x16x32_bf16(a3h1, uh1, a, 0, 0, 0);
            a = __builtin_amdgcn_mfma_f32_16x16x32_bf16(a3h1, ul1, a, 0, 0, 0);
            a = __builtin_amdgcn_mfma_f32_16x16x32_bf16(a3l1, uh1, a, 0, 0, 0);
#pragma unroll
            for (int r = 0; r < 4; r++) {
                int nn2 = w * 16 + g * 4 + r;
                if (isReal) XsR[nn2 * 65 + t] = __float_as_uint(a[r]);
                else        XsI[(nn2 - 32) * 65 + t] = __float_as_uint(a[r]);
            }
        }
    }
    __syncthreads();

    // ---- pack taps (threads 128..255)
    if (tid >= 128) karr_pk[tid - 128] = packhl(karr[tid - 128]);

    // ---- Phase 2: sequential chunk scan (threads 0..31), in-place F -> packed state
    if (tid < 32) {
        int n = tid;
        float dtar = cst_lds[0 * 32 + n], dtai = cst_lds[1 * 32 + n];
        float mr = expf(64.0f * dtar);
        float s, c; sincosf(64.0f * dtai, &s, &c);
        float Mr = mr * c, Mi = mr * s;
        float cr = 0.f, ci = 0.f;
        unsigned* pR = XsR + n * 65;
        unsigned* pI = XsI + n * 65;
        float fr = __uint_as_float(pR[0]);
        float fi2 = __uint_as_float(pI[0]);
#pragma unroll 4
        for (int t = 0; t < 64; t++) {
            float frn = 0.f, fin = 0.f;
            if (t < 63) { frn = __uint_as_float(pR[t + 1]); fin = __uint_as_float(pI[t + 1]); }
            pR[t] = packhl(cr);
            pI[t] = packhl(ci);
            float nr = fmaf(Mr, cr, fmaf(-Mi, ci, fr));
            float nic = fmaf(Mr, ci, fmaf(Mi, cr, fi2));
            cr = nr; ci = nic;
            fr = frn; fi2 = fin;
        }
    }
    __syncthreads();

    // ---- Phase 3 (MFMA): y[i][t] = K·U + E·X ; epilogue D-skip + GELU + pack
    {
        int i = w * 16 + (lane & 15);
        short8 kh0, kl0, kh1, kl1;
#pragma unroll
        for (int j = 0; j < 8; j++) {
            unsigned v0 = karr_pk[64 + i - (g * 8 + j)];
            kh0[j] = (short)(v0 >> 16); kl0[j] = (short)(v0 & 0xffffu);
            unsigned v1 = karr_pk[64 + i - (32 + g * 8 + j)];
            kh1[j] = (short)(v1 >> 16); kl1[j] = (short)(v1 & 0xffffu);
        }
        short8 e0h, e0l, e1h, e1l;
        float fi1 = (float)(i + 1);
#pragma unroll
        for (int j = 0; j < 8; j++) {
            int n = g * 8 + j;
            float dtar = cst_lds[0 * 32 + n], dtai = cst_lds[1 * 32 + n];
            float tcr = cst_lds[6 * 32 + n], tci = cst_lds[7 * 32 + n];
            float mr = expf(fi1 * dtar);
            float s, c; sincosf(fi1 * dtai, &s, &c);
            float pr = mr * c, pi = mr * s;
            unsigned v = packhl(tcr * pr - tci * pi);
            e0h[j] = (short)(v >> 16); e0l[j] = (short)(v & 0xffffu);
            unsigned v2 = packhl(-(tcr * pi + tci * pr));
            e1h[j] = (short)(v2 >> 16); e1l[j] = (short)(v2 & 0xffffu);
        }
        float Dh = D[h];
        unsigned* orow = ypack + ((size_t)(b * HH + h)) * LL;
#pragma unroll
        for (int ni = 0; ni < 4; ni++) {
            int t = ni * 16 + (lane & 15);
            const float* ub = u_lds + t * 68;
            short8 uh0, ul0, uh1, ul1;
            cvt8(ub + g * 8, uh0, ul0);
            cvt8(ub + 32 + g * 8, uh1, ul1);
            short8 xrh, xrl, xih, xil;
#pragma unroll
            for (int j = 0; j < 8; j++) {
                unsigned v = XsR[(g * 8 + j) * 65 + t];
                xrh[j] = (short)(v >> 16); xrl[j] = (short)(v & 0xffffu);
                unsigned v2 = XsI[(g * 8 + j) * 65 + t];
                xih[j] = (short)(v2 >> 16); xil[j] = (short)(v2 & 0xffffu);
            }
            f32x4 a = (f32x4){0.f, 0.f, 0.f, 0.f};
            a = __builtin_amdgcn_mfma_f32_16x16x32_bf16(kh0, uh0, a, 0, 0, 0);
            a = __builtin_amdgcn_mfma_f32_16x16x32_bf16(kh0, ul0, a, 0, 0, 0);
            a = __builtin_amdgcn_mfma_f32_16x16x32_bf16(kl0, uh0, a, 0, 0, 0);
            a = __builtin_amdgcn_mfma_f32_16x16x32_bf16(kh1, uh1, a, 0, 0, 0);
            a = __builtin_amdgcn_mfma_f32_16x16x32_bf16(kh1, ul1, a, 0, 0, 0);
            a = __builtin_amdgcn_mfma_f32_16x16x32_bf16(kl1, uh1, a, 0, 0, 0);
            a = __builtin_amdgcn_mfma_f32_16x16x32_bf16(e0h, xrh, a, 0, 0, 0);
            a = __builtin_amdgcn_mfma_f32_16x16x32_bf16(e0h, xrl, a, 0, 0, 0);
            a = __builtin_amdgcn_mfma_f32_16x16x32_bf16(e0l, xrh, a, 0, 0, 0);
            a = __builtin_amdgcn_mfma_f32_16x16x32_bf16(e1h, xih, a, 0, 0, 0);
            a = __builtin_amdgcn_mfma_f32_16x16x32_bf16(e1h, xil, a, 0, 0, 0);
            a = __builtin_amdgcn_mfma_f32_16x16x32_bf16(e1l, xih, a, 0, 0, 0);
#pragma unroll
            for (int r = 0; r < 4; r++) {
                int io = w * 16 + g * 4 + r;
                float y = a[r] + Dh * u_lds[t * 68 + io];
                float gl = 0.5f * y * (1.0f + erff(y * 0.70710678118654752f));
                orow[t * 64 + io] = packhl(gl);
            }
        }
    }
}

// ---------------- Kernel C: MFMA bf16 GEMM (y hi/lo split) + bias + GLU ----------------
__global__ __launch_bounds__(256) void gemm_glu_mfma(const unsigned* __restrict__ ypack,
                                                     const float* __restrict__ W,
                                                     const unsigned short* __restrict__ whi,
                                                     const float* __restrict__ bias,
                                                     float* __restrict__ out, int preW) {
    const int b = blockIdx.z;
    const int d0 = blockIdx.x * 64;
    const int l0 = blockIdx.y * 128;
    const int tid = threadIdx.x;
    const int lane = tid & 63;
    const int wid = tid >> 6;
    const int wave_m = wid & 1;
    const int wave_n = wid >> 1;

    __shared__ unsigned Ysh[32 * 128];
    __shared__ char Wlds[128 * 64];

    f32x4 acc[4][4];
#pragma unroll
    for (int i = 0; i < 4; i++)
#pragma unroll
        for (int j = 0; j < 4; j++) acc[i][j] = (f32x4){0.f, 0.f, 0.f, 0.f};

    for (int kt = 0; kt < 16; kt++) {
        const int h0 = kt * 32;
        __syncthreads();
#pragma unroll
        for (int q = 0; q < 4; q++) {
            int cid = q * 256 + tid;
            int kr = cid >> 5;
            int c0 = (cid & 31) * 4;
            int sc = c0 ^ ((kr & 8) ? 16 : 0);
            const unsigned* src = ypack + ((size_t)(b * HH + h0 + kr)) * LL + l0 + sc;
            gload_lds16(src, (char*)Ysh + cid * 16);
        }
        if (preW) {
#pragma unroll
            for (int e = 0; e < 2; e++) {
                int c = e * 256 + tid;
                int row = c >> 2;
                int gx = c & 3;
                int qq = (row >> 1) & 3;
                int grow = (row < 64) ? (d0 + row) : (448 + d0 + row);
                const unsigned short* src = whi + (size_t)grow * 512 + h0 + ((gx ^ qq) * 8);
                gload_lds16(src, Wlds + c * 16);
            }
        } else {
            int row = tid >> 1;
            int kb = (tid & 1) * 16;
            int qq = (row >> 1) & 3;
            int grow = (row < 64) ? (d0 + row) : (448 + d0 + row);
            const float* src = W + (size_t)grow * 512 + h0 + kb;
            float4 w0 = *(const float4*)(src);
            float4 w1 = *(const float4*)(src + 4);
            float4 w2 = *(const float4*)(src + 8);
            float4 w3 = *(const float4*)(src + 12);
            short8 v0, v1;
            v0[0] = (short)f2bf(w0.x); v0[1] = (short)f2bf(w0.y);
            v0[2] = (short)f2bf(w0.z); v0[3] = (short)f2bf(w0.w);
            v0[4] = (short)f2bf(w1.x); v0[5] = (short)f2bf(w1.y);
            v0[6] = (short)f2bf(w1.z); v0[7] = (short)f2bf(w1.w);
            v1[0] = (short)f2bf(w2.x); v1[1] = (short)f2bf(w2.y);
            v1[2] = (short)f2bf(w2.z); v1[3] = (short)f2bf(w2.w);
            v1[4] = (short)f2bf(w3.x); v1[5] = (short)f2bf(w3.y);
            v1[6] = (short)f2bf(w3.z); v1[7] = (short)f2bf(w3.w);
            int g0 = kb >> 3;
            *(short8*)(Wlds + row * 64 + ((g0 ^ qq) * 16)) = v0;
            *(short8*)(Wlds + row * 64 + (((g0 + 1) ^ qq) * 16)) = v1;
        }
        __syncthreads();

        short8 af[4];
#pragma unroll
        for (int mi = 0; mi < 4; mi++) {
            int rowb = (mi < 2) ? (wave_m * 32 + mi * 16) : (64 + wave_m * 32 + (mi - 2) * 16);
            int row = rowb + (lane & 15);
            int qq = (row >> 1) & 3;
            int gp = lane >> 4;
            af[mi] = *(const short8*)(Wlds + row * 64 + ((gp ^ qq) * 16));
        }
#pragma unroll
        for (int ni = 0; ni < 4; ni++) {
            int col = wave_n * 64 + ni * 16 + (lane & 15);
            int gq = lane >> 4;
            int cs = col ^ ((gq & 1) << 4);
            const unsigned* yb = Ysh + (8 * gq) * 128 + cs;
            unsigned p0 = yb[0 * 128], p1 = yb[1 * 128], p2 = yb[2 * 128], p3 = yb[3 * 128];
            unsigned p4 = yb[4 * 128], p5 = yb[5 * 128], p6 = yb[6 * 128], p7 = yb[7 * 128];
            short8 bh, bl;
            bh[0] = (short)(p0 >> 16); bl[0] = (short)(p0 & 0xffff);
            bh[1] = (short)(p1 >> 16); bl[1] = (short)(p1 & 0xffff);
            bh[2] = (short)(p2 >> 16); bl[2] = (short)(p2 & 0xffff);
            bh[3] = (short)(p3 >> 16); bl[3] = (short)(p3 & 0xffff);
            bh[4] = (short)(p4 >> 16); bl[4] = (short)(p4 & 0xffff);
            bh[5] = (short)(p5 >> 16); bl[5] = (short)(p5 & 0xffff);
            bh[6] = (short)(p6 >> 16); bl[6] = (short)(p6 & 0xffff);
            bh[7] = (short)(p7 >> 16); bl[7] = (short)(p7 & 0xffff);
#pragma unroll
            for (int mi = 0; mi < 4; mi++) {
                acc[mi][ni] = __builtin_amdgcn_mfma_f32_16x16x32_bf16(af[mi], bh, acc[mi][ni], 0, 0, 0);
                acc[mi][ni] = __builtin_amdgcn_mfma_f32_16x16x32_bf16(af[mi], bl, acc[mi][ni], 0, 0, 0);
            }
        }
    }

#pragma unroll
    for (int mi = 0; mi < 2; mi++) {
        int dbase = d0 + wave_m * 32 + mi * 16 + ((lane >> 4) << 2);
#pragma unroll
        for (int r = 0; r < 4; r++) {
            int d = dbase + r;
            float b1 = bias[d], b2 = bias[DMOUT + d];
#pragma unroll
            for (int ni = 0; ni < 4; ni++) {
                int l = l0 + wave_n * 64 + ni * 16 + (lane & 15);
                float z1 = acc[mi][ni][r] + b1;
                float z2 = acc[mi + 2][ni][r] + b2;
                out[((size_t)(b * DMOUT + d)) * LL + l] = z1 * (1.0f / (1.0f + expf(-z2)));
            }
        }
    }
}

extern "C" void kernel_launch(void* const* d_in, const int* in_sizes, int n_in,
                              void* d_out, int out_size, void* d_ws, size_t ws_size,
                              hipStream_t stream) {
    const float* u      = (const float*)d_in[0];
    const float* log_dt = (const float*)d_in[1];
    const float* A_re   = (const float*)d_in[2];
    const float* A_im   = (const float*)d_in[3];
    const float* B_re   = (const float*)d_in[4];
    const float* B_im   = (const float*)d_in[5];
    const float* C_re   = (const float*)d_in[6];
    const float* C_im   = (const float*)d_in[7];
    const float* D      = (const float*)d_in[8];
    const float* W      = (const float*)d_in[9];
    const float* bias   = (const float*)d_in[10];
    float* out = (float*)d_out;

    char* ws = (char*)d_ws;
    unsigned* ypack = (unsigned*)ws;                                   // 33,554,432 B
    unsigned short* whi = (unsigned short*)(ws + 33554432);            // 1,048,576 B
    int preW = (ws_size >= (size_t)(33554432 + 1048576)) ? 1 : 0;

    if (preW) wsplit_kernel<<<512, 256, 0, stream>>>(W, whi);
    ssm_kernel<<<dim3(HH, BB), 256, 0, stream>>>(u, log_dt, A_re, A_im, B_re, B_im,
                                                 C_re, C_im, D, ypack);
    gemm_glu_mfma<<<dim3(8, 32, BB), 256, 0, stream>>>(ypack, W, whi, bias, out, preW);
}

// Round 8
// 137.140 us; speedup vs baseline: 3.2504x; 1.0461x over previous
//
#include <hip/hip_runtime.h>
#include <math.h>

#define BB 4
#define HH 512
#define LL 4096
#define NN 32
#define DMOUT 512

typedef __attribute__((ext_vector_type(8))) short short8;
typedef __attribute__((ext_vector_type(4))) float f32x4;

__device__ __forceinline__ unsigned f2bf(float x) {
    unsigned u = __float_as_uint(x);
    return (u + 0x7fffu + ((u >> 16) & 1u)) >> 16;
}
__device__ __forceinline__ unsigned packhl(float x) {
    unsigned hb = f2bf(x);
    float xh = __uint_as_float(hb << 16);
    return (hb << 16) | f2bf(x - xh);
}
__device__ __forceinline__ void cvt8(const float* p, short8 &h, short8 &l) {
    float4 a = *(const float4*)p;
    float4 b = *(const float4*)(p + 4);
    unsigned v;
    v = packhl(a.x); h[0] = (short)(v >> 16); l[0] = (short)(v & 0xffffu);
    v = packhl(a.y); h[1] = (short)(v >> 16); l[1] = (short)(v & 0xffffu);
    v = packhl(a.z); h[2] = (short)(v >> 16); l[2] = (short)(v & 0xffffu);
    v = packhl(a.w); h[3] = (short)(v >> 16); l[3] = (short)(v & 0xffffu);
    v = packhl(b.x); h[4] = (short)(v >> 16); l[4] = (short)(v & 0xffffu);
    v = packhl(b.y); h[5] = (short)(v >> 16); l[5] = (short)(v & 0xffffu);
    v = packhl(b.z); h[6] = (short)(v >> 16); l[6] = (short)(v & 0xffffu);
    v = packhl(b.w); h[7] = (short)(v >> 16); l[7] = (short)(v & 0xffffu);
}
__device__ __forceinline__ void gload_lds16(const void* g, void* l) {
    __builtin_amdgcn_global_load_lds((const __attribute__((address_space(1))) void*)g,
                                     (__attribute__((address_space(3))) void*)l, 16, 0, 0);
}

// ---------------- Kernel A2: W -> bf16 hi split ----------------
__global__ void wsplit_kernel(const float* __restrict__ W, unsigned short* __restrict__ whi) {
    int i = (blockIdx.x * 256 + threadIdx.x) * 4;
    float4 w = *(const float4*)(W + i);
    ushort4 o;
    o.x = (unsigned short)f2bf(w.x);
    o.y = (unsigned short)f2bf(w.y);
    o.z = (unsigned short)f2bf(w.z);
    o.w = (unsigned short)f2bf(w.w);
    *(ushort4*)(whi + i) = o;
}

// ---------------- Kernel B: SSM conv via MFMA chunked scan + D skip + GELU ----------------
__global__ __launch_bounds__(256, 4) void ssm_kernel(
    const float* __restrict__ u, const float* __restrict__ log_dt,
    const float* __restrict__ A_re, const float* __restrict__ A_im,
    const float* __restrict__ B_re, const float* __restrict__ B_im,
    const float* __restrict__ C_re, const float* __restrict__ C_im,
    const float* __restrict__ D, unsigned* __restrict__ ypack) {
    const int h = blockIdx.x;
    const int b = blockIdx.y;
    const int tid = threadIdx.x;
    const int lane = tid & 63;
    const int w = tid >> 6;
    const int g = lane >> 4;
    const int l15 = lane & 15;

    __shared__ float u_lds[64 * 68];       // 17.4 KB, [t][m] pad 68
    __shared__ unsigned XsR[32 * 65];      // 8.3 KB  (F real f32-bits -> packed state)
    __shared__ unsigned XsI[32 * 65];      // 8.3 KB
    __shared__ float karr[128];            // taps, zero-padded below 64
    __shared__ unsigned karr_pk[128];      // hi/lo packed taps
    __shared__ float cst_lds[256];         // 8 rows x 32 modes

    // ---- stage u into [t][68] padded layout
    {
        const float* urow = u + ((size_t)(b * HH + h)) * LL;
        const float4* up = (const float4*)(urow + tid * 16);
        float4 v0 = up[0], v1 = up[1], v2 = up[2], v3 = up[3];
        int t = tid >> 2, mb = (tid & 3) * 16;
        float* dst = u_lds + t * 68 + mb;
        *(float4*)dst = v0; *(float4*)(dst + 4) = v1;
        *(float4*)(dst + 8) = v2; *(float4*)(dst + 12) = v3;
    }
    // ---- per-mode constants (folded prep)
    if (tid < 32) {
        int n = tid;
        float dt = expf(log_dt[h]);
        float ar = A_re[h * NN + n], ai = A_im[h * NN + n];
        float dtar = dt * ar, dtai = dt * ai;
        float ea = expf(dtar);
        float s, c; sincosf(dtai, &s, &c);
        float dA_r = ea * c, dA_i = ea * s;
        float em_r = dA_r - 1.0f, em_i = dA_i;
        float inv = 1.0f / (ar * ar + ai * ai);
        float t_r = (em_r * ar + em_i * ai) * inv;
        float t_i = (em_i * ar - em_r * ai) * inv;
        float br = B_re[h * NN + n], bi = B_im[h * NN + n];
        cst_lds[0 * 32 + n] = dtar;
        cst_lds[1 * 32 + n] = dtai;
        cst_lds[2 * 32 + n] = dA_r;
        cst_lds[3 * 32 + n] = dA_i;
        cst_lds[4 * 32 + n] = t_r * br - t_i * bi;
        cst_lds[5 * 32 + n] = t_r * bi + t_i * br;
        cst_lds[6 * 32 + n] = 2.0f * C_re[h * NN + n];
        cst_lds[7 * 32 + n] = 2.0f * C_im[h * NN + n];
    }
    __syncthreads();

    // ---- kernel taps k[j] (threads 0..63)
    if (tid < 64) {
        karr[tid] = 0.0f;
        float jf = (float)tid;
        float acc = 0.0f;
        for (int n = 0; n < NN; n++) {
            float mr = expf(jf * cst_lds[0 * 32 + n]);
            float s, c; sincosf(jf * cst_lds[1 * 32 + n], &s, &c);
            float pr = mr * c, pi = mr * s;
            float dbr = cst_lds[4 * 32 + n], dbi = cst_lds[5 * 32 + n];
            float tcr = cst_lds[6 * 32 + n], tci = cst_lds[7 * 32 + n];
            float wr = tcr * dbr - tci * dbi;
            float wi = tcr * dbi + tci * dbr;
            acc += wr * pr - wi * pi;
        }
        karr[64 + tid] = acc;
    }

    // ---- Phase 1 (MFMA): F[n'][t] = sum_m dB*dA^(63-m) * u[t*64+m]
    // A3 powers built incrementally: one libm pair per 8-consecutive-power group.
    {
        int nprime = w * 16 + l15;
        int isReal = (nprime < 32);
        int n = isReal ? nprime : (nprime - 32);
        float dtar = cst_lds[0 * 32 + n], dtai = cst_lds[1 * 32 + n];
        float dAr = cst_lds[2 * 32 + n], dAi = cst_lds[3 * 32 + n];
        float dbr = cst_lds[4 * 32 + n], dbi = cst_lds[5 * 32 + n];
        short8 a3h0, a3l0, a3h1, a3l1;
        // group 0: element j ~ m = g*8+j, power p = 63-m; j=7 -> p=56-g*8 (base), ascend
        {
            float p = (float)(56 - g * 8);
            float mr = expf(p * dtar);
            float s, c; sincosf(p * dtai, &s, &c);
            float pr = mr * c, pi = mr * s;
#pragma unroll
            for (int j = 7; j >= 0; j--) {
                float val = isReal ? (dbr * pr - dbi * pi) : (dbr * pi + dbi * pr);
                unsigned v = packhl(val);
                a3h0[j] = (short)(v >> 16); a3l0[j] = (short)(v & 0xffffu);
                float nr2 = pr * dAr - pi * dAi;
                pi = pr * dAi + pi * dAr;
                pr = nr2;
            }
        }
        // group 1: element j ~ m = 32+g*8+j, power p = 31-g*8-j; j=7 -> p=24-g*8 (base)
        {
            float p = (float)(24 - g * 8);
            float mr = expf(p * dtar);
            float s, c; sincosf(p * dtai, &s, &c);
            float pr = mr * c, pi = mr * s;
#pragma unroll
            for (int j = 7; j >= 0; j--) {
                float val = isReal ? (dbr * pr - dbi * pi) : (dbr * pi + dbi * pr);
                unsigned v = packhl(val);
                a3h1[j] = (short)(v >> 16); a3l1[j] = (short)(v & 0xffffu);
                float nr2 = pr * dAr - pi * dAi;
                pi = pr * dAi + pi * dAr;
                pr = nr2;
            }
        }
#pragma unroll
        for (int ni = 0; ni < 4; ni++) {
            int t = ni * 16 + l15;
            const float* ub = u_lds + t * 68;
            short8 uh0, ul0, uh1, ul1;
            cvt8(ub + g * 8, uh0, ul0);
            cvt8(ub + 32 + g * 8, uh1, ul1);
            f32x4 a = (f32x4){0.f, 0.f, 0.f, 0.f};
            a = __builtin_amdgcn_mfma_f32_16x16x32_bf16(a3h0, uh0, a, 0, 0, 0);
            a = __builtin_amdgcn_mfma_f32_16x16x32_bf16(a3l0, uh0, a, 0, 0, 0);
            a = __builtin_amdgcn_mfma_f32_16x16x32_bf16(a3h0, ul0, a, 0, 0, 0);
            a = __builtin_amdgcn_mfma_f32_16x16x32_bf16(a3h1, uh1, a, 0, 0, 0);
            a = __builtin_amdgcn_mfma_f32_16x16x32_bf16(a3l1, uh1, a, 0, 0, 0);
            a = __builtin_amdgcn_mfma_f32_16x16x32_bf16(a3h1, ul1, a, 0, 0, 0);
#pragma unroll
            for (int r = 0; r < 4; r++) {
                int nn2 = w * 16 + g * 4 + r;
                if (isReal) XsR[nn2 * 65 + t] = __float_as_uint(a[r]);
                else        XsI[(nn2 - 32) * 65 + t] = __float_as_uint(a[r]);
            }
        }
    }
    __syncthreads();

    // ---- pack taps (threads 128..255)
    if (tid >= 128) karr_pk[tid - 128] = packhl(karr[tid - 128]);

    // ---- Phase 2: sequential chunk scan (threads 0..31), in-place F -> packed state
    if (tid < 32) {
        int n = tid;
        float dtar = cst_lds[0 * 32 + n], dtai = cst_lds[1 * 32 + n];
        float mr = expf(64.0f * dtar);
        float s, c; sincosf(64.0f * dtai, &s, &c);
        float Mr = mr * c, Mi = mr * s;
        float cr = 0.f, ci = 0.f;
        unsigned* pR = XsR + n * 65;
        unsigned* pI = XsI + n * 65;
        float fr = __uint_as_float(pR[0]);
        float fi2 = __uint_as_float(pI[0]);
#pragma unroll 4
        for (int t = 0; t < 64; t++) {
            float frn = 0.f, fin = 0.f;
            if (t < 63) { frn = __uint_as_float(pR[t + 1]); fin = __uint_as_float(pI[t + 1]); }
            pR[t] = packhl(cr);
            pI[t] = packhl(ci);
            float nr = fmaf(Mr, cr, fmaf(-Mi, ci, fr));
            float nic = fmaf(Mr, ci, fmaf(Mi, cr, fi2));
            cr = nr; ci = nic;
            fr = frn; fi2 = fin;
        }
    }
    __syncthreads();

    // ---- Phase 3 (MFMA): y[i][t] = K·U + E·X ; epilogue D-skip + GELU + pack
    {
        int i = w * 16 + l15;
        short8 kh0, kl0, kh1, kl1;
#pragma unroll
        for (int j = 0; j < 8; j++) {
            unsigned v0 = karr_pk[64 + i - (g * 8 + j)];
            kh0[j] = (short)(v0 >> 16); kl0[j] = (short)(v0 & 0xffffu);
            unsigned v1 = karr_pk[64 + i - (32 + g * 8 + j)];
            kh1[j] = (short)(v1 >> 16); kl1[j] = (short)(v1 & 0xffffu);
        }
        short8 e0h, e0l, e1h, e1l;
        float fi1 = (float)(i + 1);
#pragma unroll
        for (int j = 0; j < 8; j++) {
            int n = g * 8 + j;
            float dtar = cst_lds[0 * 32 + n], dtai = cst_lds[1 * 32 + n];
            float tcr = cst_lds[6 * 32 + n], tci = cst_lds[7 * 32 + n];
            float mr = expf(fi1 * dtar);
            float s, c; sincosf(fi1 * dtai, &s, &c);
            float pr = mr * c, pi = mr * s;
            unsigned v = packhl(tcr * pr - tci * pi);
            e0h[j] = (short)(v >> 16); e0l[j] = (short)(v & 0xffffu);
            unsigned v2 = packhl(-(tcr * pi + tci * pr));
            e1h[j] = (short)(v2 >> 16); e1l[j] = (short)(v2 & 0xffffu);
        }
        float Dh = D[h];
        unsigned* orow = ypack + ((size_t)(b * HH + h)) * LL;
#pragma unroll
        for (int ni = 0; ni < 4; ni++) {
            int t = ni * 16 + l15;
            const float* ub = u_lds + t * 68;
            short8 uh0, ul0, uh1, ul1;
            cvt8(ub + g * 8, uh0, ul0);
            cvt8(ub + 32 + g * 8, uh1, ul1);
            short8 xrh, xrl, xih, xil;
#pragma unroll
            for (int j = 0; j < 8; j++) {
                unsigned v = XsR[(g * 8 + j) * 65 + t];
                xrh[j] = (short)(v >> 16); xrl[j] = (short)(v & 0xffffu);
                unsigned v2 = XsI[(g * 8 + j) * 65 + t];
                xih[j] = (short)(v2 >> 16); xil[j] = (short)(v2 & 0xffffu);
            }
            f32x4 a = (f32x4){0.f, 0.f, 0.f, 0.f};
            a = __builtin_amdgcn_mfma_f32_16x16x32_bf16(kh0, uh0, a, 0, 0, 0);
            a = __builtin_amdgcn_mfma_f32_16x16x32_bf16(kl0, uh0, a, 0, 0, 0);
            a = __builtin_amdgcn_mfma_f32_16x16x32_bf16(kh0, ul0, a, 0, 0, 0);
            a = __builtin_amdgcn_mfma_f32_16x16x32_bf16(kh1, uh1, a, 0, 0, 0);
            a = __builtin_amdgcn_mfma_f32_16x16x32_bf16(kl1, uh1, a, 0, 0, 0);
            a = __builtin_amdgcn_mfma_f32_16x16x32_bf16(kh1, ul1, a, 0, 0, 0);
            a = __builtin_amdgcn_mfma_f32_16x16x32_bf16(e0h, xrh, a, 0, 0, 0);
            a = __builtin_amdgcn_mfma_f32_16x16x32_bf16(e0h, xrl, a, 0, 0, 0);
            a = __builtin_amdgcn_mfma_f32_16x16x32_bf16(e0l, xrh, a, 0, 0, 0);
            a = __builtin_amdgcn_mfma_f32_16x16x32_bf16(e1h, xih, a, 0, 0, 0);
            a = __builtin_amdgcn_mfma_f32_16x16x32_bf16(e1h, xil, a, 0, 0, 0);
            a = __builtin_amdgcn_mfma_f32_16x16x32_bf16(e1l, xih, a, 0, 0, 0);
#pragma unroll
            for (int r = 0; r < 4; r++) {
                int io = w * 16 + g * 4 + r;
                float y = a[r] + Dh * u_lds[t * 68 + io];
                float gl = 0.5f * y * (1.0f + erff(y * 0.70710678118654752f));
                orow[t * 64 + io] = packhl(gl);
            }
        }
    }
}

// ---------------- Kernel C: MFMA bf16 GEMM (y hi/lo split) + bias + GLU ----------------
__global__ __launch_bounds__(256) void gemm_glu_mfma(const unsigned* __restrict__ ypack,
                                                     const float* __restrict__ W,
                                                     const unsigned short* __restrict__ whi,
                                                     const float* __restrict__ bias,
                                                     float* __restrict__ out, int preW) {
    const int b = blockIdx.z;
    const int d0 = blockIdx.x * 64;
    const int l0 = blockIdx.y * 128;
    const int tid = threadIdx.x;
    const int lane = tid & 63;
    const int wid = tid >> 6;
    const int wave_m = wid & 1;
    const int wave_n = wid >> 1;

    __shared__ unsigned Ysh[32 * 128];
    __shared__ char Wlds[128 * 64];

    f32x4 acc[4][4];
#pragma unroll
    for (int i = 0; i < 4; i++)
#pragma unroll
        for (int j = 0; j < 4; j++) acc[i][j] = (f32x4){0.f, 0.f, 0.f, 0.f};

    for (int kt = 0; kt < 16; kt++) {
        const int h0 = kt * 32;
        __syncthreads();
#pragma unroll
        for (int q = 0; q < 4; q++) {
            int cid = q * 256 + tid;
            int kr = cid >> 5;
            int c0 = (cid & 31) * 4;
            int sc = c0 ^ ((kr & 8) ? 16 : 0);
            const unsigned* src = ypack + ((size_t)(b * HH + h0 + kr)) * LL + l0 + sc;
            gload_lds16(src, (char*)Ysh + cid * 16);
        }
        if (preW) {
#pragma unroll
            for (int e = 0; e < 2; e++) {
                int c = e * 256 + tid;
                int row = c >> 2;
                int gx = c & 3;
                int qq = (row >> 1) & 3;
                int grow = (row < 64) ? (d0 + row) : (448 + d0 + row);
                const unsigned short* src = whi + (size_t)grow * 512 + h0 + ((gx ^ qq) * 8);
                gload_lds16(src, Wlds + c * 16);
            }
        } else {
            int row = tid >> 1;
            int kb = (tid & 1) * 16;
            int qq = (row >> 1) & 3;
            int grow = (row < 64) ? (d0 + row) : (448 + d0 + row);
            const float* src = W + (size_t)grow * 512 + h0 + kb;
            float4 w0 = *(const float4*)(src);
            float4 w1 = *(const float4*)(src + 4);
            float4 w2 = *(const float4*)(src + 8);
            float4 w3 = *(const float4*)(src + 12);
            short8 v0, v1;
            v0[0] = (short)f2bf(w0.x); v0[1] = (short)f2bf(w0.y);
            v0[2] = (short)f2bf(w0.z); v0[3] = (short)f2bf(w0.w);
            v0[4] = (short)f2bf(w1.x); v0[5] = (short)f2bf(w1.y);
            v0[6] = (short)f2bf(w1.z); v0[7] = (short)f2bf(w1.w);
            v1[0] = (short)f2bf(w2.x); v1[1] = (short)f2bf(w2.y);
            v1[2] = (short)f2bf(w2.z); v1[3] = (short)f2bf(w2.w);
            v1[4] = (short)f2bf(w3.x); v1[5] = (short)f2bf(w3.y);
            v1[6] = (short)f2bf(w3.z); v1[7] = (short)f2bf(w3.w);
            int g0 = kb >> 3;
            *(short8*)(Wlds + row * 64 + ((g0 ^ qq) * 16)) = v0;
            *(short8*)(Wlds + row * 64 + (((g0 + 1) ^ qq) * 16)) = v1;
        }
        __syncthreads();

        short8 af[4];
#pragma unroll
        for (int mi = 0; mi < 4; mi++) {
            int rowb = (mi < 2) ? (wave_m * 32 + mi * 16) : (64 + wave_m * 32 + (mi - 2) * 16);
            int row = rowb + (lane & 15);
            int qq = (row >> 1) & 3;
            int gp = lane >> 4;
            af[mi] = *(const short8*)(Wlds + row * 64 + ((gp ^ qq) * 16));
        }
#pragma unroll
        for (int ni = 0; ni < 4; ni++) {
            int col = wave_n * 64 + ni * 16 + (lane & 15);
            int gq = lane >> 4;
            int cs = col ^ ((gq & 1) << 4);
            const unsigned* yb = Ysh + (8 * gq) * 128 + cs;
            unsigned p0 = yb[0 * 128], p1 = yb[1 * 128], p2 = yb[2 * 128], p3 = yb[3 * 128];
            unsigned p4 = yb[4 * 128], p5 = yb[5 * 128], p6 = yb[6 * 128], p7 = yb[7 * 128];
            short8 bh, bl;
            bh[0] = (short)(p0 >> 16); bl[0] = (short)(p0 & 0xffff);
            bh[1] = (short)(p1 >> 16); bl[1] = (short)(p1 & 0xffff);
            bh[2] = (short)(p2 >> 16); bl[2] = (short)(p2 & 0xffff);
            bh[3] = (short)(p3 >> 16); bl[3] = (short)(p3 & 0xffff);
            bh[4] = (short)(p4 >> 16); bl[4] = (short)(p4 & 0xffff);
            bh[5] = (short)(p5 >> 16); bl[5] = (short)(p5 & 0xffff);
            bh[6] = (short)(p6 >> 16); bl[6] = (short)(p6 & 0xffff);
            bh[7] = (short)(p7 >> 16); bl[7] = (short)(p7 & 0xffff);
#pragma unroll
            for (int mi = 0; mi < 4; mi++) {
                acc[mi][ni] = __builtin_amdgcn_mfma_f32_16x16x32_bf16(af[mi], bh, acc[mi][ni], 0, 0, 0);
                acc[mi][ni] = __builtin_amdgcn_mfma_f32_16x16x32_bf16(af[mi], bl, acc[mi][ni], 0, 0, 0);
            }
        }
    }

#pragma unroll
    for (int mi = 0; mi < 2; mi++) {
        int dbase = d0 + wave_m * 32 + mi * 16 + ((lane >> 4) << 2);
#pragma unroll
        for (int r = 0; r < 4; r++) {
            int d = dbase + r;
            float b1 = bias[d], b2 = bias[DMOUT + d];
#pragma unroll
            for (int ni = 0; ni < 4; ni++) {
                int l = l0 + wave_n * 64 + ni * 16 + (lane & 15);
                float z1 = acc[mi][ni][r] + b1;
                float z2 = acc[mi + 2][ni][r] + b2;
                out[((size_t)(b * DMOUT + d)) * LL + l] = z1 * (1.0f / (1.0f + expf(-z2)));
            }
        }
    }
}

extern "C" void kernel_launch(void* const* d_in, const int* in_sizes, int n_in,
                              void* d_out, int out_size, void* d_ws, size_t ws_size,
                              hipStream_t stream) {
    const float* u      = (const float*)d_in[0];
    const float* log_dt = (const float*)d_in[1];
    const float* A_re   = (const float*)d_in[2];
    const float* A_im   = (const float*)d_in[3];
    const float* B_re   = (const float*)d_in[4];
    const float* B_im   = (const float*)d_in[5];
    const float* C_re   = (const float*)d_in[6];
    const float* C_im   = (const float*)d_in[7];
    const float* D      = (const float*)d_in[8];
    const float* W      = (const float*)d_in[9];
    const float* bias   = (const float*)d_in[10];
    float* out = (float*)d_out;

    char* ws = (char*)d_ws;
    unsigned* ypack = (unsigned*)ws;                                   // 33,554,432 B
    unsigned short* whi = (unsigned short*)(ws + 33554432);            // 1,048,576 B
    int preW = (ws_size >= (size_t)(33554432 + 1048576)) ? 1 : 0;

    if (preW) wsplit_kernel<<<512, 256, 0, stream>>>(W, whi);
    ssm_kernel<<<dim3(HH, BB), 256, 0, stream>>>(u, log_dt, A_re, A_im, B_re, B_im,
                                                 C_re, C_im, D, ypack);
    gemm_glu_mfma<<<dim3(8, 32, BB), 256, 0, stream>>>(ypack, W, whi, bias, out, preW);
}

// Round 10
// 127.166 us; speedup vs baseline: 3.5053x; 1.0784x over previous
//
#include <hip/hip_runtime.h>
#include <math.h>

#define BB 4
#define HH 512
#define LL 4096
#define NN 32
#define DMOUT 512

typedef __attribute__((ext_vector_type(8))) short short8;
typedef __attribute__((ext_vector_type(4))) float f32x4;

__device__ __forceinline__ unsigned f2bf(float x) {
    unsigned u = __float_as_uint(x);
    return (u + 0x7fffu + ((u >> 16) & 1u)) >> 16;
}
__device__ __forceinline__ unsigned packhl(float x) {
    unsigned hb = f2bf(x);
    float xh = __uint_as_float(hb << 16);
    return (hb << 16) | f2bf(x - xh);
}
__device__ __forceinline__ void gload_lds16(const void* g, void* l) {
    __builtin_amdgcn_global_load_lds((const __attribute__((address_space(1))) void*)g,
                                     (__attribute__((address_space(3))) void*)l, 16, 0, 0);
}

// ---------------- Kernel A2: W -> bf16 hi split ----------------
__global__ void wsplit_kernel(const float* __restrict__ W, unsigned short* __restrict__ whi) {
    int i = (blockIdx.x * 256 + threadIdx.x) * 4;
    float4 w = *(const float4*)(W + i);
    ushort4 o;
    o.x = (unsigned short)f2bf(w.x);
    o.y = (unsigned short)f2bf(w.y);
    o.z = (unsigned short)f2bf(w.z);
    o.w = (unsigned short)f2bf(w.w);
    *(ushort4*)(whi + i) = o;
}

// ---------------- Kernel B: SSM conv via MFMA chunked scan + D skip + GELU ----------------
__global__ __launch_bounds__(256, 4) void ssm_kernel(
    const float* __restrict__ u, const float* __restrict__ log_dt,
    const float* __restrict__ A_re, const float* __restrict__ A_im,
    const float* __restrict__ B_re, const float* __restrict__ B_im,
    const float* __restrict__ C_re, const float* __restrict__ C_im,
    const float* __restrict__ D, unsigned* __restrict__ ypack) {
    const int h = blockIdx.x;
    const int b = blockIdx.y;
    const int tid = threadIdx.x;
    const int lane = tid & 63;
    const int w = tid >> 6;
    const int g = lane >> 4;
    const int l15 = lane & 15;

    __shared__ unsigned short uh[64 * 72];  // 9.2 KB  u bf16-hi, [t][m] stride 72
    __shared__ unsigned short ul[64 * 72];  // 9.2 KB  u bf16-lo residual
    __shared__ unsigned XsR[32 * 65];       // 8.3 KB  (F real f32-bits -> packed state)
    __shared__ unsigned XsI[32 * 65];       // 8.3 KB
    __shared__ float karr[128];             // taps, zero-padded below 64
    __shared__ unsigned karr_pk[128];       // hi/lo packed taps
    __shared__ float cst_lds[256];          // 8 rows x 32 modes (K8 layout)

    // ---- stage u -> bf16 hi/lo LDS (same splits cvt8 produced, done once)
    {
        const float* urow = u + ((size_t)(b * HH + h)) * LL;
#pragma unroll
        for (int r = 0; r < 4; r++) {
            int f = tid + 256 * r;
            float4 v = *(const float4*)(urow + f * 4);
            int t = f >> 4, mb = (f & 15) << 2;
            unsigned hx = f2bf(v.x), hy = f2bf(v.y), hz = f2bf(v.z), hw = f2bf(v.w);
            uint2 hwv;
            hwv.x = hx | (hy << 16);
            hwv.y = hz | (hw << 16);
            float rx = v.x - __uint_as_float(hx << 16);
            float ry = v.y - __uint_as_float(hy << 16);
            float rz = v.z - __uint_as_float(hz << 16);
            float rw = v.w - __uint_as_float(hw << 16);
            uint2 lwv;
            lwv.x = f2bf(rx) | (f2bf(ry) << 16);
            lwv.y = f2bf(rz) | (f2bf(rw) << 16);
            *(uint2*)(&uh[t * 72 + mb]) = hwv;
            *(uint2*)(&ul[t * 72 + mb]) = lwv;
        }
    }
    // ---- per-mode constants (K8 layout: dtar,dtai,dAr,dAi,dbr,dbi,2Cr,2Ci)
    if (tid < 32) {
        int n = tid;
        float dt = expf(log_dt[h]);
        float ar = A_re[h * NN + n], ai = A_im[h * NN + n];
        float dtar = dt * ar, dtai = dt * ai;
        float ea = expf(dtar);
        float s, c; sincosf(dtai, &s, &c);
        float dA_r = ea * c, dA_i = ea * s;
        float em_r = dA_r - 1.0f, em_i = dA_i;
        float inv = 1.0f / (ar * ar + ai * ai);
        float t_r = (em_r * ar + em_i * ai) * inv;
        float t_i = (em_i * ar - em_r * ai) * inv;
        float br = B_re[h * NN + n], bi = B_im[h * NN + n];
        cst_lds[0 * 32 + n] = dtar;
        cst_lds[1 * 32 + n] = dtai;
        cst_lds[2 * 32 + n] = dA_r;
        cst_lds[3 * 32 + n] = dA_i;
        cst_lds[4 * 32 + n] = t_r * br - t_i * bi;
        cst_lds[5 * 32 + n] = t_r * bi + t_i * br;
        cst_lds[6 * 32 + n] = 2.0f * C_re[h * NN + n];
        cst_lds[7 * 32 + n] = 2.0f * C_im[h * NN + n];
    }
    __syncthreads();

    // ---- kernel taps k[j] (threads 0..63) — K8 verbatim
    if (tid < 64) {
        karr[tid] = 0.0f;
        float jf = (float)tid;
        float acc = 0.0f;
        for (int n = 0; n < NN; n++) {
            float mr = expf(jf * cst_lds[0 * 32 + n]);
            float s, c; sincosf(jf * cst_lds[1 * 32 + n], &s, &c);
            float pr = mr * c, pi = mr * s;
            float dbr = cst_lds[4 * 32 + n], dbi = cst_lds[5 * 32 + n];
            float tcr = cst_lds[6 * 32 + n], tci = cst_lds[7 * 32 + n];
            float wr = tcr * dbr - tci * dbi;
            float wi = tcr * dbi + tci * dbr;
            acc += wr * pr - wi * pi;
        }
        karr[64 + tid] = acc;
    }

    // ---- Phase 1 (MFMA): F[n'][t] = sum_m dB*dA^(63-m) * u[t*64+m]
    // A3 powers: one libm pair per 8-consecutive-power group (K8 verbatim)
    {
        int nprime = w * 16 + l15;
        int isReal = (nprime < 32);
        int n = isReal ? nprime : (nprime - 32);
        float dtar = cst_lds[0 * 32 + n], dtai = cst_lds[1 * 32 + n];
        float dAr = cst_lds[2 * 32 + n], dAi = cst_lds[3 * 32 + n];
        float dbr = cst_lds[4 * 32 + n], dbi = cst_lds[5 * 32 + n];
        short8 a3h0, a3l0, a3h1, a3l1;
        {
            float p = (float)(56 - g * 8);
            float mr = expf(p * dtar);
            float s, c; sincosf(p * dtai, &s, &c);
            float pr = mr * c, pi = mr * s;
#pragma unroll
            for (int j = 7; j >= 0; j--) {
                float val = isReal ? (dbr * pr - dbi * pi) : (dbr * pi + dbi * pr);
                unsigned v = packhl(val);
                a3h0[j] = (short)(v >> 16); a3l0[j] = (short)(v & 0xffffu);
                float nr2 = pr * dAr - pi * dAi;
                pi = pr * dAi + pi * dAr;
                pr = nr2;
            }
        }
        {
            float p = (float)(24 - g * 8);
            float mr = expf(p * dtar);
            float s, c; sincosf(p * dtai, &s, &c);
            float pr = mr * c, pi = mr * s;
#pragma unroll
            for (int j = 7; j >= 0; j--) {
                float val = isReal ? (dbr * pr - dbi * pi) : (dbr * pi + dbi * pr);
                unsigned v = packhl(val);
                a3h1[j] = (short)(v >> 16); a3l1[j] = (short)(v & 0xffffu);
                float nr2 = pr * dAr - pi * dAi;
                pi = pr * dAi + pi * dAr;
                pr = nr2;
            }
        }
#pragma unroll
        for (int ni = 0; ni < 4; ni++) {
            int t = ni * 16 + l15;
            short8 uH0 = *(const short8*)(uh + t * 72 + g * 8);
            short8 uL0 = *(const short8*)(ul + t * 72 + g * 8);
            short8 uH1 = *(const short8*)(uh + t * 72 + 32 + g * 8);
            short8 uL1 = *(const short8*)(ul + t * 72 + 32 + g * 8);
            f32x4 a = (f32x4){0.f, 0.f, 0.f, 0.f};
            a = __builtin_amdgcn_mfma_f32_16x16x32_bf16(a3h0, uH0, a, 0, 0, 0);
            a = __builtin_amdgcn_mfma_f32_16x16x32_bf16(a3l0, uH0, a, 0, 0, 0);
            a = __builtin_amdgcn_mfma_f32_16x16x32_bf16(a3h0, uL0, a, 0, 0, 0);
            a = __builtin_amdgcn_mfma_f32_16x16x32_bf16(a3h1, uH1, a, 0, 0, 0);
            a = __builtin_amdgcn_mfma_f32_16x16x32_bf16(a3l1, uH1, a, 0, 0, 0);
            a = __builtin_amdgcn_mfma_f32_16x16x32_bf16(a3h1, uL1, a, 0, 0, 0);
#pragma unroll
            for (int r = 0; r < 4; r++) {
                int nn2 = w * 16 + g * 4 + r;
                if (isReal) XsR[nn2 * 65 + t] = __float_as_uint(a[r]);
                else        XsI[(nn2 - 32) * 65 + t] = __float_as_uint(a[r]);
            }
        }
    }
    __syncthreads();

    // ---- pack taps (threads 128..255)
    if (tid >= 128) karr_pk[tid - 128] = packhl(karr[tid - 128]);

    // ---- Phase 2: sequential chunk scan (threads 0..31) — K8 verbatim
    if (tid < 32) {
        int n = tid;
        float dtar = cst_lds[0 * 32 + n], dtai = cst_lds[1 * 32 + n];
        float mr = expf(64.0f * dtar);
        float s, c; sincosf(64.0f * dtai, &s, &c);
        float Mr = mr * c, Mi = mr * s;
        float cr = 0.f, ci = 0.f;
        unsigned* pR = XsR + n * 65;
        unsigned* pI = XsI + n * 65;
        float fr = __uint_as_float(pR[0]);
        float fi2 = __uint_as_float(pI[0]);
#pragma unroll 4
        for (int t = 0; t < 64; t++) {
            float frn = 0.f, fin = 0.f;
            if (t < 63) { frn = __uint_as_float(pR[t + 1]); fin = __uint_as_float(pI[t + 1]); }
            pR[t] = packhl(cr);
            pI[t] = packhl(ci);
            float nr = fmaf(Mr, cr, fmaf(-Mi, ci, fr));
            float nic = fmaf(Mr, ci, fmaf(Mi, cr, fi2));
            cr = nr; ci = nic;
            fr = frn; fi2 = fin;
        }
    }
    __syncthreads();

    // ---- Phase 3 (MFMA): y[i][t] = K·U + E·X ; epilogue D-skip + GELU + pack
    {
        int i = w * 16 + l15;
        short8 kh0, kl0, kh1, kl1;
#pragma unroll
        for (int j = 0; j < 8; j++) {
            unsigned v0 = karr_pk[64 + i - (g * 8 + j)];
            kh0[j] = (short)(v0 >> 16); kl0[j] = (short)(v0 & 0xffffu);
            unsigned v1 = karr_pk[64 + i - (32 + g * 8 + j)];
            kh1[j] = (short)(v1 >> 16); kl1[j] = (short)(v1 & 0xffffu);
        }
        short8 e0h, e0l, e1h, e1l;
        float fi1 = (float)(i + 1);
#pragma unroll
        for (int j = 0; j < 8; j++) {
            int n = g * 8 + j;
            float dtar = cst_lds[0 * 32 + n], dtai = cst_lds[1 * 32 + n];
            float tcr = cst_lds[6 * 32 + n], tci = cst_lds[7 * 32 + n];
            float mr = expf(fi1 * dtar);
            float s, c; sincosf(fi1 * dtai, &s, &c);
            float pr = mr * c, pi = mr * s;
            unsigned v = packhl(tcr * pr - tci * pi);
            e0h[j] = (short)(v >> 16); e0l[j] = (short)(v & 0xffffu);
            unsigned v2 = packhl(-(tcr * pi + tci * pr));
            e1h[j] = (short)(v2 >> 16); e1l[j] = (short)(v2 & 0xffffu);
        }
        float Dh = D[h];
        unsigned* orow = ypack + ((size_t)(b * HH + h)) * LL;
#pragma unroll
        for (int ni = 0; ni < 4; ni++) {
            int t = ni * 16 + l15;
            short8 uH0 = *(const short8*)(uh + t * 72 + g * 8);
            short8 uL0 = *(const short8*)(ul + t * 72 + g * 8);
            short8 uH1 = *(const short8*)(uh + t * 72 + 32 + g * 8);
            short8 uL1 = *(const short8*)(ul + t * 72 + 32 + g * 8);
            short8 xrh, xrl, xih, xil;
#pragma unroll
            for (int j = 0; j < 8; j++) {
                unsigned v = XsR[(g * 8 + j) * 65 + t];
                xrh[j] = (short)(v >> 16); xrl[j] = (short)(v & 0xffffu);
                unsigned v2 = XsI[(g * 8 + j) * 65 + t];
                xih[j] = (short)(v2 >> 16); xil[j] = (short)(v2 & 0xffffu);
            }
            f32x4 a = (f32x4){0.f, 0.f, 0.f, 0.f};
            a = __builtin_amdgcn_mfma_f32_16x16x32_bf16(kh0, uH0, a, 0, 0, 0);
            a = __builtin_amdgcn_mfma_f32_16x16x32_bf16(kl0, uH0, a, 0, 0, 0);
            a = __builtin_amdgcn_mfma_f32_16x16x32_bf16(kh0, uL0, a, 0, 0, 0);
            a = __builtin_amdgcn_mfma_f32_16x16x32_bf16(kh1, uH1, a, 0, 0, 0);
            a = __builtin_amdgcn_mfma_f32_16x16x32_bf16(kl1, uH1, a, 0, 0, 0);
            a = __builtin_amdgcn_mfma_f32_16x16x32_bf16(kh1, uL1, a, 0, 0, 0);
            a = __builtin_amdgcn_mfma_f32_16x16x32_bf16(e0h, xrh, a, 0, 0, 0);
            a = __builtin_amdgcn_mfma_f32_16x16x32_bf16(e0h, xrl, a, 0, 0, 0);
            a = __builtin_amdgcn_mfma_f32_16x16x32_bf16(e0l, xrh, a, 0, 0, 0);
            a = __builtin_amdgcn_mfma_f32_16x16x32_bf16(e1h, xih, a, 0, 0, 0);
            a = __builtin_amdgcn_mfma_f32_16x16x32_bf16(e1h, xil, a, 0, 0, 0);
            a = __builtin_amdgcn_mfma_f32_16x16x32_bf16(e1l, xih, a, 0, 0, 0);
#pragma unroll
            for (int r = 0; r < 4; r++) {
                int io = w * 16 + g * 4 + r;
                float uv = __uint_as_float(((unsigned)uh[t * 72 + io]) << 16)
                         + __uint_as_float(((unsigned)ul[t * 72 + io]) << 16);
                float y = a[r] + Dh * uv;
                float gl = 0.5f * y * (1.0f + erff(y * 0.70710678118654752f));
                orow[t * 64 + io] = packhl(gl);
            }
        }
    }
}

// ---------------- Kernel C: MFMA bf16 GEMM (y hi only) + bias + GLU ----------------
__global__ __launch_bounds__(256) void gemm_glu_mfma(const unsigned* __restrict__ ypack,
                                                     const float* __restrict__ W,
                                                     const unsigned short* __restrict__ whi,
                                                     const float* __restrict__ bias,
                                                     float* __restrict__ out, int preW) {
    const int b = blockIdx.z;
    const int d0 = blockIdx.x * 64;
    const int l0 = blockIdx.y * 128;
    const int tid = threadIdx.x;
    const int lane = tid & 63;
    const int wid = tid >> 6;
    const int wave_m = wid & 1;
    const int wave_n = wid >> 1;

    __shared__ unsigned Ysh[32 * 128];
    __shared__ char Wlds[128 * 64];

    f32x4 acc[4][4];
#pragma unroll
    for (int i = 0; i < 4; i++)
#pragma unroll
        for (int j = 0; j < 4; j++) acc[i][j] = (f32x4){0.f, 0.f, 0.f, 0.f};

    for (int kt = 0; kt < 16; kt++) {
        const int h0 = kt * 32;
        __syncthreads();
#pragma unroll
        for (int q = 0; q < 4; q++) {
            int cid = q * 256 + tid;
            int kr = cid >> 5;
            int c0 = (cid & 31) * 4;
            int sc = c0 ^ ((kr & 8) ? 16 : 0);
            const unsigned* src = ypack + ((size_t)(b * HH + h0 + kr)) * LL + l0 + sc;
            gload_lds16(src, (char*)Ysh + cid * 16);
        }
        if (preW) {
#pragma unroll
            for (int e = 0; e < 2; e++) {
                int c = e * 256 + tid;
                int row = c >> 2;
                int gx = c & 3;
                int qq = (row >> 1) & 3;
                int grow = (row < 64) ? (d0 + row) : (448 + d0 + row);
                const unsigned short* src = whi + (size_t)grow * 512 + h0 + ((gx ^ qq) * 8);
                gload_lds16(src, Wlds + c * 16);
            }
        } else {
            int row = tid >> 1;
            int kb = (tid & 1) * 16;
            int qq = (row >> 1) & 3;
            int grow = (row < 64) ? (d0 + row) : (448 + d0 + row);
            const float* src = W + (size_t)grow * 512 + h0 + kb;
            float4 w0 = *(const float4*)(src);
            float4 w1 = *(const float4*)(src + 4);
            float4 w2 = *(const float4*)(src + 8);
            float4 w3 = *(const float4*)(src + 12);
            short8 v0, v1;
            v0[0] = (short)f2bf(w0.x); v0[1] = (short)f2bf(w0.y);
            v0[2] = (short)f2bf(w0.z); v0[3] = (short)f2bf(w0.w);
            v0[4] = (short)f2bf(w1.x); v0[5] = (short)f2bf(w1.y);
            v0[6] = (short)f2bf(w1.z); v0[7] = (short)f2bf(w1.w);
            v1[0] = (short)f2bf(w2.x); v1[1] = (short)f2bf(w2.y);
            v1[2] = (short)f2bf(w2.z); v1[3] = (short)f2bf(w2.w);
            v1[4] = (short)f2bf(w3.x); v1[5] = (short)f2bf(w3.y);
            v1[6] = (short)f2bf(w3.z); v1[7] = (short)f2bf(w3.w);
            int g0 = kb >> 3;
            *(short8*)(Wlds + row * 64 + ((g0 ^ qq) * 16)) = v0;
            *(short8*)(Wlds + row * 64 + (((g0 + 1) ^ qq) * 16)) = v1;
        }
        __syncthreads();

        short8 af[4];
#pragma unroll
        for (int mi = 0; mi < 4; mi++) {
            int rowb = (mi < 2) ? (wave_m * 32 + mi * 16) : (64 + wave_m * 32 + (mi - 2) * 16);
            int row = rowb + (lane & 15);
            int qq = (row >> 1) & 3;
            int gp = lane >> 4;
            af[mi] = *(const short8*)(Wlds + row * 64 + ((gp ^ qq) * 16));
        }
#pragma unroll
        for (int ni = 0; ni < 4; ni++) {
            int col = wave_n * 64 + ni * 16 + (lane & 15);
            int gq = lane >> 4;
            int cs = col ^ ((gq & 1) << 4);
            const unsigned* yb = Ysh + (8 * gq) * 128 + cs;
            unsigned p0 = yb[0 * 128], p1 = yb[1 * 128], p2 = yb[2 * 128], p3 = yb[3 * 128];
            unsigned p4 = yb[4 * 128], p5 = yb[5 * 128], p6 = yb[6 * 128], p7 = yb[7 * 128];
            short8 bh;
            bh[0] = (short)(p0 >> 16);
            bh[1] = (short)(p1 >> 16);
            bh[2] = (short)(p2 >> 16);
            bh[3] = (short)(p3 >> 16);
            bh[4] = (short)(p4 >> 16);
            bh[5] = (short)(p5 >> 16);
            bh[6] = (short)(p6 >> 16);
            bh[7] = (short)(p7 >> 16);
#pragma unroll
            for (int mi = 0; mi < 4; mi++) {
                acc[mi][ni] = __builtin_amdgcn_mfma_f32_16x16x32_bf16(af[mi], bh, acc[mi][ni], 0, 0, 0);
            }
        }
    }

#pragma unroll
    for (int mi = 0; mi < 2; mi++) {
        int dbase = d0 + wave_m * 32 + mi * 16 + ((lane >> 4) << 2);
#pragma unroll
        for (int r = 0; r < 4; r++) {
            int d = dbase + r;
            float b1 = bias[d], b2 = bias[DMOUT + d];
#pragma unroll
            for (int ni = 0; ni < 4; ni++) {
                int l = l0 + wave_n * 64 + ni * 16 + (lane & 15);
                float z1 = acc[mi][ni][r] + b1;
                float z2 = acc[mi + 2][ni][r] + b2;
                out[((size_t)(b * DMOUT + d)) * LL + l] = z1 * (1.0f / (1.0f + expf(-z2)));
            }
        }
    }
}

extern "C" void kernel_launch(void* const* d_in, const int* in_sizes, int n_in,
                              void* d_out, int out_size, void* d_ws, size_t ws_size,
                              hipStream_t stream) {
    const float* u      = (const float*)d_in[0];
    const float* log_dt = (const float*)d_in[1];
    const float* A_re   = (const float*)d_in[2];
    const float* A_im   = (const float*)d_in[3];
    const float* B_re   = (const float*)d_in[4];
    const float* B_im   = (const float*)d_in[5];
    const float* C_re   = (const float*)d_in[6];
    const float* C_im   = (const float*)d_in[7];
    const float* D      = (const float*)d_in[8];
    const float* W      = (const float*)d_in[9];
    const float* bias   = (const float*)d_in[10];
    float* out = (float*)d_out;

    char* ws = (char*)d_ws;
    unsigned* ypack = (unsigned*)ws;                                   // 33,554,432 B
    unsigned short* whi = (unsigned short*)(ws + 33554432);            // 1,048,576 B
    int preW = (ws_size >= (size_t)(33554432 + 1048576)) ? 1 : 0;

    if (preW) wsplit_kernel<<<512, 256, 0, stream>>>(W, whi);
    ssm_kernel<<<dim3(HH, BB), 256, 0, stream>>>(u, log_dt, A_re, A_im, B_re, B_im,
                                                 C_re, C_im, D, ypack);
    gemm_glu_mfma<<<dim3(8, 32, BB), 256, 0, stream>>>(ypack, W, whi, bias, out, preW);
}

// Round 13
// 115.227 us; speedup vs baseline: 3.8685x; 1.1036x over previous
//
#include <hip/hip_runtime.h>
#include <math.h>

#define BB 4
#define HH 512
#define LL 4096
#define NN 32
#define DMOUT 512

typedef __attribute__((ext_vector_type(8))) short short8;
typedef __attribute__((ext_vector_type(4))) float f32x4;

__device__ __forceinline__ unsigned f2bf(float x) {
    unsigned u = __float_as_uint(x);
    return (u + 0x7fffu + ((u >> 16) & 1u)) >> 16;
}
__device__ __forceinline__ unsigned packhl(float x) {
    unsigned hb = f2bf(x);
    float xh = __uint_as_float(hb << 16);
    return (hb << 16) | f2bf(x - xh);
}
__device__ __forceinline__ void gload_lds16(const void* g, void* l) {
    __builtin_amdgcn_global_load_lds((const __attribute__((address_space(1))) void*)g,
                                     (__attribute__((address_space(3))) void*)l, 16, 0, 0);
}

// ---------------- Kernel A2: W -> bf16 hi split ----------------
__global__ void wsplit_kernel(const float* __restrict__ W, unsigned short* __restrict__ whi) {
    int i = (blockIdx.x * 256 + threadIdx.x) * 4;
    float4 w = *(const float4*)(W + i);
    ushort4 o;
    o.x = (unsigned short)f2bf(w.x);
    o.y = (unsigned short)f2bf(w.y);
    o.z = (unsigned short)f2bf(w.z);
    o.w = (unsigned short)f2bf(w.w);
    *(ushort4*)(whi + i) = o;
}

// ---------------- Kernel B: SSM conv via MFMA chunked scan + D skip + GELU ----------------
__global__ __launch_bounds__(256, 4) void ssm_kernel(
    const float* __restrict__ u, const float* __restrict__ log_dt,
    const float* __restrict__ A_re, const float* __restrict__ A_im,
    const float* __restrict__ B_re, const float* __restrict__ B_im,
    const float* __restrict__ C_re, const float* __restrict__ C_im,
    const float* __restrict__ D, unsigned* __restrict__ ypack) {
    const int h = blockIdx.x;
    const int b = blockIdx.y;
    const int tid = threadIdx.x;
    const int lane = tid & 63;
    const int w = tid >> 6;
    const int g = lane >> 4;
    const int l15 = lane & 15;

    __shared__ unsigned short uh[64 * 72];  // 9.2 KB  u bf16-hi, [t][m] stride 72
    __shared__ unsigned short ul[64 * 72];  // 9.2 KB  u bf16-lo residual
    __shared__ unsigned XsR[32 * 65];       // 8.3 KB  (F real f32-bits -> packed state)
    __shared__ unsigned XsI[32 * 65];       // 8.3 KB
    __shared__ unsigned karr_pk[128];       // hi/lo packed taps, [0..63]=0 pad
    __shared__ float kpart[256];            // karr partials [nr][j]
    __shared__ float cst_lds[256];          // 8 rows x 32 modes (K8 layout)

    // ---- stage u -> bf16 hi/lo LDS (pack once)
    {
        const float* urow = u + ((size_t)(b * HH + h)) * LL;
#pragma unroll
        for (int r = 0; r < 4; r++) {
            int f = tid + 256 * r;
            float4 v = *(const float4*)(urow + f * 4);
            int t = f >> 4, mb = (f & 15) << 2;
            unsigned hx = f2bf(v.x), hy = f2bf(v.y), hz = f2bf(v.z), hw = f2bf(v.w);
            uint2 hwv;
            hwv.x = hx | (hy << 16);
            hwv.y = hz | (hw << 16);
            float rx = v.x - __uint_as_float(hx << 16);
            float ry = v.y - __uint_as_float(hy << 16);
            float rz = v.z - __uint_as_float(hz << 16);
            float rw = v.w - __uint_as_float(hw << 16);
            uint2 lwv;
            lwv.x = f2bf(rx) | (f2bf(ry) << 16);
            lwv.y = f2bf(rz) | (f2bf(rw) << 16);
            *(uint2*)(&uh[t * 72 + mb]) = hwv;
            *(uint2*)(&ul[t * 72 + mb]) = lwv;
        }
    }
    // ---- per-mode constants (K8 layout: dtar,dtai,dAr,dAi,dbr,dbi,2Cr,2Ci)
    if (tid < 32) {
        int n = tid;
        float dt = expf(log_dt[h]);
        float ar = A_re[h * NN + n], ai = A_im[h * NN + n];
        float dtar = dt * ar, dtai = dt * ai;
        float ea = expf(dtar);
        float s, c; sincosf(dtai, &s, &c);
        float dA_r = ea * c, dA_i = ea * s;
        float em_r = dA_r - 1.0f, em_i = dA_i;
        float inv = 1.0f / (ar * ar + ai * ai);
        float t_r = (em_r * ar + em_i * ai) * inv;
        float t_i = (em_i * ar - em_r * ai) * inv;
        float br = B_re[h * NN + n], bi = B_im[h * NN + n];
        cst_lds[0 * 32 + n] = dtar;
        cst_lds[1 * 32 + n] = dtai;
        cst_lds[2 * 32 + n] = dA_r;
        cst_lds[3 * 32 + n] = dA_i;
        cst_lds[4 * 32 + n] = t_r * br - t_i * bi;
        cst_lds[5 * 32 + n] = t_r * bi + t_i * br;
        cst_lds[6 * 32 + n] = 2.0f * C_re[h * NN + n];
        cst_lds[7 * 32 + n] = 2.0f * C_im[h * NN + n];
    }
    __syncthreads();   // S0

    // ---- Phase 1 (MFMA): F[n'][t] = sum_m dB*dA^(63-m) * u[t*64+m]
    {
        int nprime = w * 16 + l15;
        int isReal = (nprime < 32);
        int n = isReal ? nprime : (nprime - 32);
        float dtar = cst_lds[0 * 32 + n], dtai = cst_lds[1 * 32 + n];
        float dAr = cst_lds[2 * 32 + n], dAi = cst_lds[3 * 32 + n];
        float dbr = cst_lds[4 * 32 + n], dbi = cst_lds[5 * 32 + n];
        short8 a3h0, a3l0, a3h1, a3l1;
        {
            float p = (float)(56 - g * 8);
            float mr = expf(p * dtar);
            float s, c; sincosf(p * dtai, &s, &c);
            float pr = mr * c, pi = mr * s;
#pragma unroll
            for (int j = 7; j >= 0; j--) {
                float val = isReal ? (dbr * pr - dbi * pi) : (dbr * pi + dbi * pr);
                unsigned v = packhl(val);
                a3h0[j] = (short)(v >> 16); a3l0[j] = (short)(v & 0xffffu);
                float nr2 = pr * dAr - pi * dAi;
                pi = pr * dAi + pi * dAr;
                pr = nr2;
            }
        }
        {
            float p = (float)(24 - g * 8);
            float mr = expf(p * dtar);
            float s, c; sincosf(p * dtai, &s, &c);
            float pr = mr * c, pi = mr * s;
#pragma unroll
            for (int j = 7; j >= 0; j--) {
                float val = isReal ? (dbr * pr - dbi * pi) : (dbr * pi + dbi * pr);
                unsigned v = packhl(val);
                a3h1[j] = (short)(v >> 16); a3l1[j] = (short)(v & 0xffffu);
                float nr2 = pr * dAr - pi * dAi;
                pi = pr * dAi + pi * dAr;
                pr = nr2;
            }
        }
#pragma unroll
        for (int ni = 0; ni < 4; ni++) {
            int t = ni * 16 + l15;
            short8 uH0 = *(const short8*)(uh + t * 72 + g * 8);
            short8 uL0 = *(const short8*)(ul + t * 72 + g * 8);
            short8 uH1 = *(const short8*)(uh + t * 72 + 32 + g * 8);
            short8 uL1 = *(const short8*)(ul + t * 72 + 32 + g * 8);
            f32x4 a = (f32x4){0.f, 0.f, 0.f, 0.f};
            a = __builtin_amdgcn_mfma_f32_16x16x32_bf16(a3h0, uH0, a, 0, 0, 0);
            a = __builtin_amdgcn_mfma_f32_16x16x32_bf16(a3l0, uH0, a, 0, 0, 0);
            a = __builtin_amdgcn_mfma_f32_16x16x32_bf16(a3h0, uL0, a, 0, 0, 0);
            a = __builtin_amdgcn_mfma_f32_16x16x32_bf16(a3h1, uH1, a, 0, 0, 0);
            a = __builtin_amdgcn_mfma_f32_16x16x32_bf16(a3l1, uH1, a, 0, 0, 0);
            a = __builtin_amdgcn_mfma_f32_16x16x32_bf16(a3h1, uL1, a, 0, 0, 0);
#pragma unroll
            for (int r = 0; r < 4; r++) {
                int nn2 = w * 16 + g * 4 + r;
                if (isReal) XsR[nn2 * 65 + t] = __float_as_uint(a[r]);
                else        XsI[(nn2 - 32) * 65 + t] = __float_as_uint(a[r]);
            }
        }
    }
    // ---- kpart (all threads): partial k[j] over 8 modes each (libm)
    {
        int j = tid & 63, nr = tid >> 6;
        float jf = (float)j;
        float acc = 0.0f;
#pragma unroll
        for (int q = 0; q < 8; q++) {
            int n = nr * 8 + q;
            float mr = expf(jf * cst_lds[0 * 32 + n]);
            float s, c; sincosf(jf * cst_lds[1 * 32 + n], &s, &c);
            float pr = mr * c, pi = mr * s;
            float dbr = cst_lds[4 * 32 + n], dbi = cst_lds[5 * 32 + n];
            float tcr = cst_lds[6 * 32 + n], tci = cst_lds[7 * 32 + n];
            float wr = tcr * dbr - tci * dbi;
            float wi = tcr * dbi + tci * dbr;
            acc += wr * pr - wi * pi;
        }
        kpart[nr * 64 + j] = acc;
    }
    __syncthreads();   // S1: F + kpart ready

    // ---- scan (tid<32) | karr finalize (tid 64..127) | zero pad (tid 128..191)
    // NOTE: explicit lower bounds — tid 32..63 must do NOTHING (was the K11/K12 bug)
    if (tid < 32) {
        int n = tid;
        float dtar = cst_lds[0 * 32 + n], dtai = cst_lds[1 * 32 + n];
        float mr = expf(64.0f * dtar);
        float s, c; sincosf(64.0f * dtai, &s, &c);
        float Mr = mr * c, Mi = mr * s;
        float cr = 0.f, ci = 0.f;
        unsigned* pR = XsR + n * 65;
        unsigned* pI = XsI + n * 65;
        float fr = __uint_as_float(pR[0]);
        float fi2 = __uint_as_float(pI[0]);
#pragma unroll 4
        for (int t = 0; t < 64; t++) {
            float frn = 0.f, fin = 0.f;
            if (t < 63) { frn = __uint_as_float(pR[t + 1]); fin = __uint_as_float(pI[t + 1]); }
            pR[t] = packhl(cr);
            pI[t] = packhl(ci);
            float nr = fmaf(Mr, cr, fmaf(-Mi, ci, fr));
            float nic = fmaf(Mr, ci, fmaf(Mi, cr, fi2));
            cr = nr; ci = nic;
            fr = frn; fi2 = fin;
        }
    } else if (tid >= 64 && tid < 128) {
        int j = tid - 64;
        float k = kpart[j] + kpart[64 + j] + kpart[128 + j] + kpart[192 + j];
        karr_pk[64 + j] = packhl(k);
    } else if (tid >= 128 && tid < 192) {
        karr_pk[tid - 128] = 0u;
    }
    __syncthreads();   // S2: state + karr_pk ready

    // ---- Phase 3 (MFMA, 12x full hi/lo): y = K·U + E·X ; D-skip + GELU
    {
        int i = w * 16 + l15;
        short8 kh0, kl0, kh1, kl1;
#pragma unroll
        for (int j = 0; j < 8; j++) {
            unsigned v0 = karr_pk[64 + i - (g * 8 + j)];
            kh0[j] = (short)(v0 >> 16); kl0[j] = (short)(v0 & 0xffffu);
            unsigned v1 = karr_pk[64 + i - (32 + g * 8 + j)];
            kh1[j] = (short)(v1 >> 16); kl1[j] = (short)(v1 & 0xffffu);
        }
        short8 e0h, e0l, e1h, e1l;
        float fi1 = (float)(i + 1);
#pragma unroll
        for (int j = 0; j < 8; j++) {
            int n = g * 8 + j;
            float dtar = cst_lds[0 * 32 + n], dtai = cst_lds[1 * 32 + n];
            float tcr = cst_lds[6 * 32 + n], tci = cst_lds[7 * 32 + n];
            float mr = expf(fi1 * dtar);
            float s, c; sincosf(fi1 * dtai, &s, &c);
            float pr = mr * c, pi = mr * s;
            unsigned v = packhl(tcr * pr - tci * pi);
            e0h[j] = (short)(v >> 16); e0l[j] = (short)(v & 0xffffu);
            unsigned v2 = packhl(-(tcr * pi + tci * pr));
            e1h[j] = (short)(v2 >> 16); e1l[j] = (short)(v2 & 0xffffu);
        }
        float Dh = D[h];
        unsigned* orow = ypack + ((size_t)(b * HH + h)) * LL;
#pragma unroll
        for (int ni = 0; ni < 4; ni++) {
            int t = ni * 16 + l15;
            short8 uH0 = *(const short8*)(uh + t * 72 + g * 8);
            short8 uL0 = *(const short8*)(ul + t * 72 + g * 8);
            short8 uH1 = *(const short8*)(uh + t * 72 + 32 + g * 8);
            short8 uL1 = *(const short8*)(ul + t * 72 + 32 + g * 8);
            short8 xrh, xrl, xih, xil;
#pragma unroll
            for (int j = 0; j < 8; j++) {
                unsigned v = XsR[(g * 8 + j) * 65 + t];
                xrh[j] = (short)(v >> 16); xrl[j] = (short)(v & 0xffffu);
                unsigned v2 = XsI[(g * 8 + j) * 65 + t];
                xih[j] = (short)(v2 >> 16); xil[j] = (short)(v2 & 0xffffu);
            }
            f32x4 a = (f32x4){0.f, 0.f, 0.f, 0.f};
            a = __builtin_amdgcn_mfma_f32_16x16x32_bf16(kh0, uH0, a, 0, 0, 0);
            a = __builtin_amdgcn_mfma_f32_16x16x32_bf16(kl0, uH0, a, 0, 0, 0);
            a = __builtin_amdgcn_mfma_f32_16x16x32_bf16(kh0, uL0, a, 0, 0, 0);
            a = __builtin_amdgcn_mfma_f32_16x16x32_bf16(kh1, uH1, a, 0, 0, 0);
            a = __builtin_amdgcn_mfma_f32_16x16x32_bf16(kl1, uH1, a, 0, 0, 0);
            a = __builtin_amdgcn_mfma_f32_16x16x32_bf16(kh1, uL1, a, 0, 0, 0);
            a = __builtin_amdgcn_mfma_f32_16x16x32_bf16(e0h, xrh, a, 0, 0, 0);
            a = __builtin_amdgcn_mfma_f32_16x16x32_bf16(e0h, xrl, a, 0, 0, 0);
            a = __builtin_amdgcn_mfma_f32_16x16x32_bf16(e0l, xrh, a, 0, 0, 0);
            a = __builtin_amdgcn_mfma_f32_16x16x32_bf16(e1h, xih, a, 0, 0, 0);
            a = __builtin_amdgcn_mfma_f32_16x16x32_bf16(e1h, xil, a, 0, 0, 0);
            a = __builtin_amdgcn_mfma_f32_16x16x32_bf16(e1l, xih, a, 0, 0, 0);
#pragma unroll
            for (int r = 0; r < 4; r++) {
                int io = w * 16 + g * 4 + r;
                float uv = __uint_as_float(((unsigned)uh[t * 72 + io]) << 16)
                         + __uint_as_float(((unsigned)ul[t * 72 + io]) << 16);
                float y = a[r] + Dh * uv;
                float gl = 0.5f * y * (1.0f + erff(y * 0.70710678118654752f));
                orow[t * 64 + io] = f2bf(gl) << 16;
            }
        }
    }
}

// ---------------- Kernel C: MFMA bf16 GEMM (y hi only) + bias + GLU ----------------
__global__ __launch_bounds__(256) void gemm_glu_mfma(const unsigned* __restrict__ ypack,
                                                     const float* __restrict__ W,
                                                     const unsigned short* __restrict__ whi,
                                                     const float* __restrict__ bias,
                                                     float* __restrict__ out, int preW) {
    const int b = blockIdx.z;
    const int d0 = blockIdx.x * 64;
    const int l0 = blockIdx.y * 128;
    const int tid = threadIdx.x;
    const int lane = tid & 63;
    const int wid = tid >> 6;
    const int wave_m = wid & 1;
    const int wave_n = wid >> 1;

    __shared__ unsigned Ysh[32 * 128];
    __shared__ char Wlds[128 * 64];

    f32x4 acc[4][4];
#pragma unroll
    for (int i = 0; i < 4; i++)
#pragma unroll
        for (int j = 0; j < 4; j++) acc[i][j] = (f32x4){0.f, 0.f, 0.f, 0.f};

    for (int kt = 0; kt < 16; kt++) {
        const int h0 = kt * 32;
        __syncthreads();
#pragma unroll
        for (int q = 0; q < 4; q++) {
            int cid = q * 256 + tid;
            int kr = cid >> 5;
            int c0 = (cid & 31) * 4;
            int sc = c0 ^ ((kr & 8) ? 16 : 0);
            const unsigned* src = ypack + ((size_t)(b * HH + h0 + kr)) * LL + l0 + sc;
            gload_lds16(src, (char*)Ysh + cid * 16);
        }
        if (preW) {
#pragma unroll
            for (int e = 0; e < 2; e++) {
                int c = e * 256 + tid;
                int row = c >> 2;
                int gx = c & 3;
                int qq = (row >> 1) & 3;
                int grow = (row < 64) ? (d0 + row) : (448 + d0 + row);
                const unsigned short* src = whi + (size_t)grow * 512 + h0 + ((gx ^ qq) * 8);
                gload_lds16(src, Wlds + c * 16);
            }
        } else {
            int row = tid >> 1;
            int kb = (tid & 1) * 16;
            int qq = (row >> 1) & 3;
            int grow = (row < 64) ? (d0 + row) : (448 + d0 + row);
            const float* src = W + (size_t)grow * 512 + h0 + kb;
            float4 w0 = *(const float4*)(src);
            float4 w1 = *(const float4*)(src + 4);
            float4 w2 = *(const float4*)(src + 8);
            float4 w3 = *(const float4*)(src + 12);
            short8 v0, v1;
            v0[0] = (short)f2bf(w0.x); v0[1] = (short)f2bf(w0.y);
            v0[2] = (short)f2bf(w0.z); v0[3] = (short)f2bf(w0.w);
            v0[4] = (short)f2bf(w1.x); v0[5] = (short)f2bf(w1.y);
            v0[6] = (short)f2bf(w1.z); v0[7] = (short)f2bf(w1.w);
            v1[0] = (short)f2bf(w2.x); v1[1] = (short)f2bf(w2.y);
            v1[2] = (short)f2bf(w2.z); v1[3] = (short)f2bf(w2.w);
            v1[4] = (short)f2bf(w3.x); v1[5] = (short)f2bf(w3.y);
            v1[6] = (short)f2bf(w3.z); v1[7] = (short)f2bf(w3.w);
            int g0 = kb >> 3;
            *(short8*)(Wlds + row * 64 + ((g0 ^ qq) * 16)) = v0;
            *(short8*)(Wlds + row * 64 + (((g0 + 1) ^ qq) * 16)) = v1;
        }
        __syncthreads();

        short8 af[4];
#pragma unroll
        for (int mi = 0; mi < 4; mi++) {
            int rowb = (mi < 2) ? (wave_m * 32 + mi * 16) : (64 + wave_m * 32 + (mi - 2) * 16);
            int row = rowb + (lane & 15);
            int qq = (row >> 1) & 3;
            int gp = lane >> 4;
            af[mi] = *(const short8*)(Wlds + row * 64 + ((gp ^ qq) * 16));
        }
#pragma unroll
        for (int ni = 0; ni < 4; ni++) {
            int col = wave_n * 64 + ni * 16 + (lane & 15);
            int gq = lane >> 4;
            int cs = col ^ ((gq & 1) << 4);
            const unsigned* yb = Ysh + (8 * gq) * 128 + cs;
            unsigned p0 = yb[0 * 128], p1 = yb[1 * 128], p2 = yb[2 * 128], p3 = yb[3 * 128];
            unsigned p4 = yb[4 * 128], p5 = yb[5 * 128], p6 = yb[6 * 128], p7 = yb[7 * 128];
            short8 bh;
            bh[0] = (short)(p0 >> 16);
            bh[1] = (short)(p1 >> 16);
            bh[2] = (short)(p2 >> 16);
            bh[3] = (short)(p3 >> 16);
            bh[4] = (short)(p4 >> 16);
            bh[5] = (short)(p5 >> 16);
            bh[6] = (short)(p6 >> 16);
            bh[7] = (short)(p7 >> 16);
#pragma unroll
            for (int mi = 0; mi < 4; mi++) {
                acc[mi][ni] = __builtin_amdgcn_mfma_f32_16x16x32_bf16(af[mi], bh, acc[mi][ni], 0, 0, 0);
            }
        }
    }

#pragma unroll
    for (int mi = 0; mi < 2; mi++) {
        int dbase = d0 + wave_m * 32 + mi * 16 + ((lane >> 4) << 2);
#pragma unroll
        for (int r = 0; r < 4; r++) {
            int d = dbase + r;
            float b1 = bias[d], b2 = bias[DMOUT + d];
#pragma unroll
            for (int ni = 0; ni < 4; ni++) {
                int l = l0 + wave_n * 64 + ni * 16 + (lane & 15);
                float z1 = acc[mi][ni][r] + b1;
                float z2 = acc[mi + 2][ni][r] + b2;
                out[((size_t)(b * DMOUT + d)) * LL + l] = z1 * (1.0f / (1.0f + expf(-z2)));
            }
        }
    }
}

extern "C" void kernel_launch(void* const* d_in, const int* in_sizes, int n_in,
                              void* d_out, int out_size, void* d_ws, size_t ws_size,
                              hipStream_t stream) {
    const float* u      = (const float*)d_in[0];
    const float* log_dt = (const float*)d_in[1];
    const float* A_re   = (const float*)d_in[2];
    const float* A_im   = (const float*)d_in[3];
    const float* B_re   = (const float*)d_in[4];
    const float* B_im   = (const float*)d_in[5];
    const float* C_re   = (const float*)d_in[6];
    const float* C_im   = (const float*)d_in[7];
    const float* D      = (const float*)d_in[8];
    const float* W      = (const float*)d_in[9];
    const float* bias   = (const float*)d_in[10];
    float* out = (float*)d_out;

    char* ws = (char*)d_ws;
    unsigned* ypack = (unsigned*)ws;                                   // 33,554,432 B
    unsigned short* whi = (unsigned short*)(ws + 33554432);            // 1,048,576 B
    int preW = (ws_size >= (size_t)(33554432 + 1048576)) ? 1 : 0;

    if (preW) wsplit_kernel<<<512, 256, 0, stream>>>(W, whi);
    ssm_kernel<<<dim3(HH, BB), 256, 0, stream>>>(u, log_dt, A_re, A_im, B_re, B_im,
                                                 C_re, C_im, D, ypack);
    gemm_glu_mfma<<<dim3(8, 32, BB), 256, 0, stream>>>(ypack, W, whi, bias, out, preW);
}

// Round 14
// 98.099 us; speedup vs baseline: 4.5440x; 1.1746x over previous
//
#include <hip/hip_runtime.h>
#include <math.h>

#define BB 4
#define HH 512
#define LL 4096
#define NN 32
#define DMOUT 512

typedef __attribute__((ext_vector_type(8))) short short8;
typedef __attribute__((ext_vector_type(4))) float f32x4;

__device__ __forceinline__ unsigned f2bf(float x) {
    unsigned u = __float_as_uint(x);
    return (u + 0x7fffu + ((u >> 16) & 1u)) >> 16;
}
__device__ __forceinline__ unsigned packhl(float x) {
    unsigned hb = f2bf(x);
    float xh = __uint_as_float(hb << 16);
    return (hb << 16) | f2bf(x - xh);
}
__device__ __forceinline__ void gload_lds16(const void* g, void* l) {
    __builtin_amdgcn_global_load_lds((const __attribute__((address_space(1))) void*)g,
                                     (__attribute__((address_space(3))) void*)l, 16, 0, 0);
}

// ---------------- Kernel A2: W -> bf16 hi split ----------------
__global__ void wsplit_kernel(const float* __restrict__ W, unsigned short* __restrict__ whi) {
    int i = (blockIdx.x * 256 + threadIdx.x) * 4;
    float4 w = *(const float4*)(W + i);
    ushort4 o;
    o.x = (unsigned short)f2bf(w.x);
    o.y = (unsigned short)f2bf(w.y);
    o.z = (unsigned short)f2bf(w.z);
    o.w = (unsigned short)f2bf(w.w);
    *(ushort4*)(whi + i) = o;
}

// ---------------- Kernel B: SSM conv via MFMA chunked scan + D skip + GELU ----------------
__global__ __launch_bounds__(256, 4) void ssm_kernel(
    const float* __restrict__ u, const float* __restrict__ log_dt,
    const float* __restrict__ A_re, const float* __restrict__ A_im,
    const float* __restrict__ B_re, const float* __restrict__ B_im,
    const float* __restrict__ C_re, const float* __restrict__ C_im,
    const float* __restrict__ D, unsigned short* __restrict__ yhi) {
    const int h = blockIdx.x;
    const int b = blockIdx.y;
    const int tid = threadIdx.x;
    const int lane = tid & 63;
    const int w = tid >> 6;
    const int g = lane >> 4;
    const int l15 = lane & 15;

    __shared__ unsigned short uh[64 * 72];  // 9.2 KB  u bf16-hi, [t][m] stride 72
    __shared__ unsigned short ul[64 * 72];  // 9.2 KB  u bf16-lo residual
    __shared__ unsigned XsR[32 * 65];       // 8.3 KB  (F real f32-bits -> packed state)
    __shared__ unsigned XsI[32 * 65];       // 8.3 KB
    __shared__ unsigned karr_pk[128];       // hi/lo packed taps, [0..63]=0 pad
    __shared__ float kpart[256];            // karr partials [nr][j]
    __shared__ float cst_lds[256];          // 8 rows x 32 modes (K8 layout)

    // ---- stage u -> bf16 hi/lo LDS (pack once)
    {
        const float* urow = u + ((size_t)(b * HH + h)) * LL;
#pragma unroll
        for (int r = 0; r < 4; r++) {
            int f = tid + 256 * r;
            float4 v = *(const float4*)(urow + f * 4);
            int t = f >> 4, mb = (f & 15) << 2;
            unsigned hx = f2bf(v.x), hy = f2bf(v.y), hz = f2bf(v.z), hw = f2bf(v.w);
            uint2 hwv;
            hwv.x = hx | (hy << 16);
            hwv.y = hz | (hw << 16);
            float rx = v.x - __uint_as_float(hx << 16);
            float ry = v.y - __uint_as_float(hy << 16);
            float rz = v.z - __uint_as_float(hz << 16);
            float rw = v.w - __uint_as_float(hw << 16);
            uint2 lwv;
            lwv.x = f2bf(rx) | (f2bf(ry) << 16);
            lwv.y = f2bf(rz) | (f2bf(rw) << 16);
            *(uint2*)(&uh[t * 72 + mb]) = hwv;
            *(uint2*)(&ul[t * 72 + mb]) = lwv;
        }
    }
    // ---- per-mode constants (K8 layout: dtar,dtai,dAr,dAi,dbr,dbi,2Cr,2Ci)
    if (tid < 32) {
        int n = tid;
        float dt = expf(log_dt[h]);
        float ar = A_re[h * NN + n], ai = A_im[h * NN + n];
        float dtar = dt * ar, dtai = dt * ai;
        float ea = expf(dtar);
        float s, c; sincosf(dtai, &s, &c);
        float dA_r = ea * c, dA_i = ea * s;
        float em_r = dA_r - 1.0f, em_i = dA_i;
        float inv = 1.0f / (ar * ar + ai * ai);
        float t_r = (em_r * ar + em_i * ai) * inv;
        float t_i = (em_i * ar - em_r * ai) * inv;
        float br = B_re[h * NN + n], bi = B_im[h * NN + n];
        cst_lds[0 * 32 + n] = dtar;
        cst_lds[1 * 32 + n] = dtai;
        cst_lds[2 * 32 + n] = dA_r;
        cst_lds[3 * 32 + n] = dA_i;
        cst_lds[4 * 32 + n] = t_r * br - t_i * bi;
        cst_lds[5 * 32 + n] = t_r * bi + t_i * br;
        cst_lds[6 * 32 + n] = 2.0f * C_re[h * NN + n];
        cst_lds[7 * 32 + n] = 2.0f * C_im[h * NN + n];
    }
    __syncthreads();   // S0

    // ---- Phase 1 (MFMA): F[n'][t] = sum_m dB*dA^(63-m) * u[t*64+m]
    {
        int nprime = w * 16 + l15;
        int isReal = (nprime < 32);
        int n = isReal ? nprime : (nprime - 32);
        float dtar = cst_lds[0 * 32 + n], dtai = cst_lds[1 * 32 + n];
        float dAr = cst_lds[2 * 32 + n], dAi = cst_lds[3 * 32 + n];
        float dbr = cst_lds[4 * 32 + n], dbi = cst_lds[5 * 32 + n];
        short8 a3h0, a3l0, a3h1, a3l1;
        {
            float p = (float)(56 - g * 8);
            float mr = expf(p * dtar);
            float s, c; sincosf(p * dtai, &s, &c);
            float pr = mr * c, pi = mr * s;
#pragma unroll
            for (int j = 7; j >= 0; j--) {
                float val = isReal ? (dbr * pr - dbi * pi) : (dbr * pi + dbi * pr);
                unsigned v = packhl(val);
                a3h0[j] = (short)(v >> 16); a3l0[j] = (short)(v & 0xffffu);
                float nr2 = pr * dAr - pi * dAi;
                pi = pr * dAi + pi * dAr;
                pr = nr2;
            }
        }
        {
            float p = (float)(24 - g * 8);
            float mr = expf(p * dtar);
            float s, c; sincosf(p * dtai, &s, &c);
            float pr = mr * c, pi = mr * s;
#pragma unroll
            for (int j = 7; j >= 0; j--) {
                float val = isReal ? (dbr * pr - dbi * pi) : (dbr * pi + dbi * pr);
                unsigned v = packhl(val);
                a3h1[j] = (short)(v >> 16); a3l1[j] = (short)(v & 0xffffu);
                float nr2 = pr * dAr - pi * dAi;
                pi = pr * dAi + pi * dAr;
                pr = nr2;
            }
        }
#pragma unroll
        for (int ni = 0; ni < 4; ni++) {
            int t = ni * 16 + l15;
            short8 uH0 = *(const short8*)(uh + t * 72 + g * 8);
            short8 uL0 = *(const short8*)(ul + t * 72 + g * 8);
            short8 uH1 = *(const short8*)(uh + t * 72 + 32 + g * 8);
            short8 uL1 = *(const short8*)(ul + t * 72 + 32 + g * 8);
            f32x4 a = (f32x4){0.f, 0.f, 0.f, 0.f};
            a = __builtin_amdgcn_mfma_f32_16x16x32_bf16(a3h0, uH0, a, 0, 0, 0);
            a = __builtin_amdgcn_mfma_f32_16x16x32_bf16(a3l0, uH0, a, 0, 0, 0);
            a = __builtin_amdgcn_mfma_f32_16x16x32_bf16(a3h0, uL0, a, 0, 0, 0);
            a = __builtin_amdgcn_mfma_f32_16x16x32_bf16(a3h1, uH1, a, 0, 0, 0);
            a = __builtin_amdgcn_mfma_f32_16x16x32_bf16(a3l1, uH1, a, 0, 0, 0);
            a = __builtin_amdgcn_mfma_f32_16x16x32_bf16(a3h1, uL1, a, 0, 0, 0);
#pragma unroll
            for (int r = 0; r < 4; r++) {
                int nn2 = w * 16 + g * 4 + r;
                if (isReal) XsR[nn2 * 65 + t] = __float_as_uint(a[r]);
                else        XsI[(nn2 - 32) * 65 + t] = __float_as_uint(a[r]);
            }
        }
    }
    // ---- kpart (all threads): partial k[j] over 8 modes each (libm)
    {
        int j = tid & 63, nr = tid >> 6;
        float jf = (float)j;
        float acc = 0.0f;
#pragma unroll
        for (int q = 0; q < 8; q++) {
            int n = nr * 8 + q;
            float mr = expf(jf * cst_lds[0 * 32 + n]);
            float s, c; sincosf(jf * cst_lds[1 * 32 + n], &s, &c);
            float pr = mr * c, pi = mr * s;
            float dbr = cst_lds[4 * 32 + n], dbi = cst_lds[5 * 32 + n];
            float tcr = cst_lds[6 * 32 + n], tci = cst_lds[7 * 32 + n];
            float wr = tcr * dbr - tci * dbi;
            float wi = tcr * dbi + tci * dbr;
            acc += wr * pr - wi * pi;
        }
        kpart[nr * 64 + j] = acc;
    }
    __syncthreads();   // S1: F + kpart ready

    // ---- scan (tid<32) | karr finalize (tid 64..127) | zero pad (tid 128..191)
    // explicit lower bounds — tid 32..63 must do NOTHING
    if (tid < 32) {
        int n = tid;
        float dtar = cst_lds[0 * 32 + n], dtai = cst_lds[1 * 32 + n];
        float mr = expf(64.0f * dtar);
        float s, c; sincosf(64.0f * dtai, &s, &c);
        float Mr = mr * c, Mi = mr * s;
        float cr = 0.f, ci = 0.f;
        unsigned* pR = XsR + n * 65;
        unsigned* pI = XsI + n * 65;
        float fr = __uint_as_float(pR[0]);
        float fi2 = __uint_as_float(pI[0]);
#pragma unroll 4
        for (int t = 0; t < 64; t++) {
            float frn = 0.f, fin = 0.f;
            if (t < 63) { frn = __uint_as_float(pR[t + 1]); fin = __uint_as_float(pI[t + 1]); }
            pR[t] = packhl(cr);
            pI[t] = packhl(ci);
            float nr = fmaf(Mr, cr, fmaf(-Mi, ci, fr));
            float nic = fmaf(Mr, ci, fmaf(Mi, cr, fi2));
            cr = nr; ci = nic;
            fr = frn; fi2 = fin;
        }
    } else if (tid >= 64 && tid < 128) {
        int j = tid - 64;
        float k = kpart[j] + kpart[64 + j] + kpart[128 + j] + kpart[192 + j];
        karr_pk[64 + j] = packhl(k);
    } else if (tid >= 128 && tid < 192) {
        karr_pk[tid - 128] = 0u;
    }
    __syncthreads();   // S2: state + karr_pk ready

    // ---- Phase 3 (MFMA, 12x full hi/lo): y = K·U + E·X ; D-skip + GELU; store bf16-hi
    {
        int i = w * 16 + l15;
        short8 kh0, kl0, kh1, kl1;
#pragma unroll
        for (int j = 0; j < 8; j++) {
            unsigned v0 = karr_pk[64 + i - (g * 8 + j)];
            kh0[j] = (short)(v0 >> 16); kl0[j] = (short)(v0 & 0xffffu);
            unsigned v1 = karr_pk[64 + i - (32 + g * 8 + j)];
            kh1[j] = (short)(v1 >> 16); kl1[j] = (short)(v1 & 0xffffu);
        }
        short8 e0h, e0l, e1h, e1l;
        float fi1 = (float)(i + 1);
#pragma unroll
        for (int j = 0; j < 8; j++) {
            int n = g * 8 + j;
            float dtar = cst_lds[0 * 32 + n], dtai = cst_lds[1 * 32 + n];
            float tcr = cst_lds[6 * 32 + n], tci = cst_lds[7 * 32 + n];
            float mr = expf(fi1 * dtar);
            float s, c; sincosf(fi1 * dtai, &s, &c);
            float pr = mr * c, pi = mr * s;
            unsigned v = packhl(tcr * pr - tci * pi);
            e0h[j] = (short)(v >> 16); e0l[j] = (short)(v & 0xffffu);
            unsigned v2 = packhl(-(tcr * pi + tci * pr));
            e1h[j] = (short)(v2 >> 16); e1l[j] = (short)(v2 & 0xffffu);
        }
        float Dh = D[h];
        unsigned short* orow = yhi + ((size_t)(b * HH + h)) * LL;
#pragma unroll
        for (int ni = 0; ni < 4; ni++) {
            int t = ni * 16 + l15;
            short8 uH0 = *(const short8*)(uh + t * 72 + g * 8);
            short8 uL0 = *(const short8*)(ul + t * 72 + g * 8);
            short8 uH1 = *(const short8*)(uh + t * 72 + 32 + g * 8);
            short8 uL1 = *(const short8*)(ul + t * 72 + 32 + g * 8);
            short8 xrh, xrl, xih, xil;
#pragma unroll
            for (int j = 0; j < 8; j++) {
                unsigned v = XsR[(g * 8 + j) * 65 + t];
                xrh[j] = (short)(v >> 16); xrl[j] = (short)(v & 0xffffu);
                unsigned v2 = XsI[(g * 8 + j) * 65 + t];
                xih[j] = (short)(v2 >> 16); xil[j] = (short)(v2 & 0xffffu);
            }
            f32x4 a = (f32x4){0.f, 0.f, 0.f, 0.f};
            a = __builtin_amdgcn_mfma_f32_16x16x32_bf16(kh0, uH0, a, 0, 0, 0);
            a = __builtin_amdgcn_mfma_f32_16x16x32_bf16(kl0, uH0, a, 0, 0, 0);
            a = __builtin_amdgcn_mfma_f32_16x16x32_bf16(kh0, uL0, a, 0, 0, 0);
            a = __builtin_amdgcn_mfma_f32_16x16x32_bf16(kh1, uH1, a, 0, 0, 0);
            a = __builtin_amdgcn_mfma_f32_16x16x32_bf16(kl1, uH1, a, 0, 0, 0);
            a = __builtin_amdgcn_mfma_f32_16x16x32_bf16(kh1, uL1, a, 0, 0, 0);
            a = __builtin_amdgcn_mfma_f32_16x16x32_bf16(e0h, xrh, a, 0, 0, 0);
            a = __builtin_amdgcn_mfma_f32_16x16x32_bf16(e0h, xrl, a, 0, 0, 0);
            a = __builtin_amdgcn_mfma_f32_16x16x32_bf16(e0l, xrh, a, 0, 0, 0);
            a = __builtin_amdgcn_mfma_f32_16x16x32_bf16(e1h, xih, a, 0, 0, 0);
            a = __builtin_amdgcn_mfma_f32_16x16x32_bf16(e1h, xil, a, 0, 0, 0);
            a = __builtin_amdgcn_mfma_f32_16x16x32_bf16(e1l, xih, a, 0, 0, 0);
            ushort4 ov;
            unsigned short* op = &ov.x;
#pragma unroll
            for (int r = 0; r < 4; r++) {
                int io = w * 16 + g * 4 + r;
                float uv = __uint_as_float(((unsigned)uh[t * 72 + io]) << 16)
                         + __uint_as_float(((unsigned)ul[t * 72 + io]) << 16);
                float y = a[r] + Dh * uv;
                float gl = 0.5f * y * (1.0f + erff(y * 0.70710678118654752f));
                op[r] = (unsigned short)f2bf(gl);
            }
            *(ushort4*)(&orow[t * 64 + w * 16 + g * 4]) = ov;
        }
    }
}

// ---------------- Kernel C: MFMA bf16 GEMM (y bf16-hi ushort) + bias + GLU ----------------
// grid = dim3(32 l-tiles, 8 d-tiles, B): same-Y blocks (all d) land on the same XCD.
__global__ __launch_bounds__(256) void gemm_glu_mfma(const unsigned short* __restrict__ yhi,
                                                     const float* __restrict__ W,
                                                     const unsigned short* __restrict__ whi,
                                                     const float* __restrict__ bias,
                                                     float* __restrict__ out, int preW) {
    const int b = blockIdx.z;
    const int d0 = blockIdx.y * 64;
    const int l0 = blockIdx.x * 128;
    const int tid = threadIdx.x;
    const int lane = tid & 63;
    const int wid = tid >> 6;
    const int wave_m = wid & 1;
    const int wave_n = wid >> 1;

    __shared__ unsigned short Ysh[32 * 128];  // 8 KB, col-xor-16 swizzle by row-bit3
    __shared__ char Wlds[128 * 64];           // 8 KB bf16-hi, group-xor-swizzled

    f32x4 acc[4][4];
#pragma unroll
    for (int i = 0; i < 4; i++)
#pragma unroll
        for (int j = 0; j < 4; j++) acc[i][j] = (f32x4){0.f, 0.f, 0.f, 0.f};

    for (int kt = 0; kt < 16; kt++) {
        const int h0 = kt * 32;
        __syncthreads();
        // stage Y tile [32 k][128 l] ushort: 512 16B chunks, source pre-swizzled
#pragma unroll
        for (int q = 0; q < 2; q++) {
            int cid = q * 256 + tid;
            int kr = cid >> 4;              // row 0..31
            int cc = cid & 15;              // 16B chunk in row (8 ushorts)
            int scol = (cc * 8) ^ ((kr & 8) ? 16 : 0);
            const unsigned short* src = yhi + ((size_t)(b * HH + h0 + kr)) * LL + l0 + scol;
            gload_lds16(src, (char*)Ysh + cid * 16);
        }
        if (preW) {
#pragma unroll
            for (int e = 0; e < 2; e++) {
                int c = e * 256 + tid;
                int row = c >> 2;
                int gx = c & 3;
                int qq = (row >> 1) & 3;
                int grow = (row < 64) ? (d0 + row) : (448 + d0 + row);
                const unsigned short* src = whi + (size_t)grow * 512 + h0 + ((gx ^ qq) * 8);
                gload_lds16(src, Wlds + c * 16);
            }
        } else {
            int row = tid >> 1;
            int kb = (tid & 1) * 16;
            int qq = (row >> 1) & 3;
            int grow = (row < 64) ? (d0 + row) : (448 + d0 + row);
            const float* src = W + (size_t)grow * 512 + h0 + kb;
            float4 w0 = *(const float4*)(src);
            float4 w1 = *(const float4*)(src + 4);
            float4 w2 = *(const float4*)(src + 8);
            float4 w3 = *(const float4*)(src + 12);
            short8 v0, v1;
            v0[0] = (short)f2bf(w0.x); v0[1] = (short)f2bf(w0.y);
            v0[2] = (short)f2bf(w0.z); v0[3] = (short)f2bf(w0.w);
            v0[4] = (short)f2bf(w1.x); v0[5] = (short)f2bf(w1.y);
            v0[6] = (short)f2bf(w1.z); v0[7] = (short)f2bf(w1.w);
            v1[0] = (short)f2bf(w2.x); v1[1] = (short)f2bf(w2.y);
            v1[2] = (short)f2bf(w2.z); v1[3] = (short)f2bf(w2.w);
            v1[4] = (short)f2bf(w3.x); v1[5] = (short)f2bf(w3.y);
            v1[6] = (short)f2bf(w3.z); v1[7] = (short)f2bf(w3.w);
            int g0 = kb >> 3;
            *(short8*)(Wlds + row * 64 + ((g0 ^ qq) * 16)) = v0;
            *(short8*)(Wlds + row * 64 + (((g0 + 1) ^ qq) * 16)) = v1;
        }
        __syncthreads();

        short8 af[4];
#pragma unroll
        for (int mi = 0; mi < 4; mi++) {
            int rowb = (mi < 2) ? (wave_m * 32 + mi * 16) : (64 + wave_m * 32 + (mi - 2) * 16);
            int row = rowb + (lane & 15);
            int qq = (row >> 1) & 3;
            int gp = lane >> 4;
            af[mi] = *(const short8*)(Wlds + row * 64 + ((gp ^ qq) * 16));
        }
#pragma unroll
        for (int ni = 0; ni < 4; ni++) {
            int col = wave_n * 64 + ni * 16 + (lane & 15);
            int gq = lane >> 4;
            int cs = col ^ ((gq & 1) << 4);
            const unsigned short* yb = Ysh + (8 * gq) * 128 + cs;
            short8 bh;
            bh[0] = (short)yb[0 * 128];
            bh[1] = (short)yb[1 * 128];
            bh[2] = (short)yb[2 * 128];
            bh[3] = (short)yb[3 * 128];
            bh[4] = (short)yb[4 * 128];
            bh[5] = (short)yb[5 * 128];
            bh[6] = (short)yb[6 * 128];
            bh[7] = (short)yb[7 * 128];
#pragma unroll
            for (int mi = 0; mi < 4; mi++) {
                acc[mi][ni] = __builtin_amdgcn_mfma_f32_16x16x32_bf16(af[mi], bh, acc[mi][ni], 0, 0, 0);
            }
        }
    }

#pragma unroll
    for (int mi = 0; mi < 2; mi++) {
        int dbase = d0 + wave_m * 32 + mi * 16 + ((lane >> 4) << 2);
#pragma unroll
        for (int r = 0; r < 4; r++) {
            int d = dbase + r;
            float b1 = bias[d], b2 = bias[DMOUT + d];
#pragma unroll
            for (int ni = 0; ni < 4; ni++) {
                int l = l0 + wave_n * 64 + ni * 16 + (lane & 15);
                float z1 = acc[mi][ni][r] + b1;
                float z2 = acc[mi + 2][ni][r] + b2;
                out[((size_t)(b * DMOUT + d)) * LL + l] = z1 * (1.0f / (1.0f + expf(-z2)));
            }
        }
    }
}

extern "C" void kernel_launch(void* const* d_in, const int* in_sizes, int n_in,
                              void* d_out, int out_size, void* d_ws, size_t ws_size,
                              hipStream_t stream) {
    const float* u      = (const float*)d_in[0];
    const float* log_dt = (const float*)d_in[1];
    const float* A_re   = (const float*)d_in[2];
    const float* A_im   = (const float*)d_in[3];
    const float* B_re   = (const float*)d_in[4];
    const float* B_im   = (const float*)d_in[5];
    const float* C_re   = (const float*)d_in[6];
    const float* C_im   = (const float*)d_in[7];
    const float* D      = (const float*)d_in[8];
    const float* W      = (const float*)d_in[9];
    const float* bias   = (const float*)d_in[10];
    float* out = (float*)d_out;

    char* ws = (char*)d_ws;
    unsigned short* yhi = (unsigned short*)ws;                         // 16,777,216 B
    unsigned short* whi = (unsigned short*)(ws + 16777216);            // 1,048,576 B
    int preW = (ws_size >= (size_t)(16777216 + 1048576)) ? 1 : 0;

    if (preW) wsplit_kernel<<<512, 256, 0, stream>>>(W, whi);
    ssm_kernel<<<dim3(HH, BB), 256, 0, stream>>>(u, log_dt, A_re, A_im, B_re, B_im,
                                                 C_re, C_im, D, yhi);
    gemm_glu_mfma<<<dim3(32, 8, BB), 256, 0, stream>>>(yhi, W, whi, bias, out, preW);
}

// Round 15
// 95.931 us; speedup vs baseline: 4.6466x; 1.0226x over previous
//
#include <hip/hip_runtime.h>
#include <math.h>

#define BB 4
#define HH 512
#define LL 4096
#define NN 32
#define DMOUT 512

typedef __attribute__((ext_vector_type(8))) short short8;
typedef __attribute__((ext_vector_type(4))) float f32x4;

__device__ __forceinline__ unsigned f2bf(float x) {
    unsigned u = __float_as_uint(x);
    return (u + 0x7fffu + ((u >> 16) & 1u)) >> 16;
}
__device__ __forceinline__ unsigned packhl(float x) {
    unsigned hb = f2bf(x);
    float xh = __uint_as_float(hb << 16);
    return (hb << 16) | f2bf(x - xh);
}
__device__ __forceinline__ float reconhl(unsigned v) {
    return __uint_as_float(v & 0xffff0000u) + __uint_as_float(v << 16);
}
__device__ __forceinline__ void gload_lds16(const void* g, void* l) {
    __builtin_amdgcn_global_load_lds((const __attribute__((address_space(1))) void*)g,
                                     (__attribute__((address_space(3))) void*)l, 16, 0, 0);
}

// ---------------- Kernel P: per-h tables (A3t, Et), libm-base + incremental muls ----------------
__global__ __launch_bounds__(256) void prep_kernel(
    const float* __restrict__ log_dt,
    const float* __restrict__ A_re, const float* __restrict__ A_im,
    const float* __restrict__ B_re, const float* __restrict__ B_im,
    const float* __restrict__ C_re, const float* __restrict__ C_im,
    unsigned* __restrict__ A3t, unsigned* __restrict__ Et) {
    const int h = blockIdx.x;
    const int tid = threadIdx.x;
    __shared__ float cst_lds[256];

    if (tid < 32) {
        int n = tid;
        float dt = expf(log_dt[h]);
        float ar = A_re[h * NN + n], ai = A_im[h * NN + n];
        float dtar = dt * ar, dtai = dt * ai;
        float ea = expf(dtar);
        float s, c; sincosf(dtai, &s, &c);
        float dA_r = ea * c, dA_i = ea * s;
        float em_r = dA_r - 1.0f, em_i = dA_i;
        float inv = 1.0f / (ar * ar + ai * ai);
        float t_r = (em_r * ar + em_i * ai) * inv;
        float t_i = (em_i * ar - em_r * ai) * inv;
        float br = B_re[h * NN + n], bi = B_im[h * NN + n];
        cst_lds[0 * 32 + n] = dtar;
        cst_lds[1 * 32 + n] = dtai;
        cst_lds[2 * 32 + n] = dA_r;
        cst_lds[3 * 32 + n] = dA_i;
        cst_lds[4 * 32 + n] = t_r * br - t_i * bi;
        cst_lds[5 * 32 + n] = t_r * bi + t_i * br;
        cst_lds[6 * 32 + n] = 2.0f * C_re[h * NN + n];
        cst_lds[7 * 32 + n] = 2.0f * C_im[h * NN + n];
    }
    __syncthreads();

    const int n = tid & 31, q = tid >> 5;   // q in [0,8)
    const float dtar = cst_lds[0 * 32 + n], dtai = cst_lds[1 * 32 + n];
    const float dAr = cst_lds[2 * 32 + n], dAi = cst_lds[3 * 32 + n];
    const float dbr = cst_lds[4 * 32 + n], dbi = cst_lds[5 * 32 + n];
    const float tcr = cst_lds[6 * 32 + n], tci = cst_lds[7 * 32 + n];

    // A3t[h][m][n'] : n'<32 -> dbr*Re - dbi*Im ; n'>=32 -> dbr*Im + dbi*Re, of dA^(63-m)
    {
        float p = (float)(56 - q * 8);
        float mr = expf(p * dtar);
        float s, c; sincosf(p * dtai, &s, &c);
        float pr = mr * c, pi = mr * s;
        unsigned* base = A3t + (size_t)h * 4096;
#pragma unroll
        for (int jj = 7; jj >= 0; jj--) {
            int m = q * 8 + jj;            // p == 63 - m here
            base[m * 64 + n]      = packhl(dbr * pr - dbi * pi);
            base[m * 64 + 32 + n] = packhl(dbr * pi + dbi * pr);
            float nr2 = pr * dAr - pi * dAi;
            pi = pr * dAi + pi * dAr;
            pr = nr2;
        }
    }
    // Et[h][i][n'] : n'<32 -> tcr*Re - tci*Im ; n'>=32 -> -(tcr*Im + tci*Re), of dA^(i+1)
    {
        float p = (float)(q * 8 + 1);
        float mr = expf(p * dtar);
        float s, c; sincosf(p * dtai, &s, &c);
        float pr = mr * c, pi = mr * s;
        unsigned* base = Et + (size_t)h * 4096;
#pragma unroll
        for (int i = q * 8; i <= q * 8 + 7; i++) {   // p == i + 1 here
            base[i * 64 + n]      = packhl(tcr * pr - tci * pi);
            base[i * 64 + 32 + n] = packhl(-(tcr * pi + tci * pr));
            float nr2 = pr * dAr - pi * dAi;
            pi = pr * dAi + pi * dAr;
            pr = nr2;
        }
    }
}

// ---------------- Kernel B: SSM conv via MFMA chunked scan + D skip + GELU ----------------
__global__ __launch_bounds__(256, 4) void ssm_kernel(
    const float* __restrict__ u, const float* __restrict__ log_dt,
    const float* __restrict__ A_re, const float* __restrict__ A_im,
    const float* __restrict__ B_re, const float* __restrict__ B_im,
    const float* __restrict__ C_re, const float* __restrict__ C_im,
    const float* __restrict__ D,
    const unsigned* __restrict__ A3t, const unsigned* __restrict__ Et,
    unsigned short* __restrict__ yhi) {
    const int h = blockIdx.x;
    const int b = blockIdx.y;
    const int tid = threadIdx.x;
    const int lane = tid & 63;
    const int w = tid >> 6;
    const int g = lane >> 4;
    const int l15 = lane & 15;

    __shared__ unsigned short uh[64 * 72];
    __shared__ unsigned short ul[64 * 72];
    __shared__ unsigned XsR[32 * 65];
    __shared__ unsigned XsI[32 * 65];
    __shared__ unsigned karr_pk[128];
    __shared__ float kpart[256];
    __shared__ float cst_lds[256];

    // ---- stage u -> bf16 hi/lo LDS
    {
        const float* urow = u + ((size_t)(b * HH + h)) * LL;
#pragma unroll
        for (int r = 0; r < 4; r++) {
            int f = tid + 256 * r;
            float4 v = *(const float4*)(urow + f * 4);
            int t = f >> 4, mb = (f & 15) << 2;
            unsigned hx = f2bf(v.x), hy = f2bf(v.y), hz = f2bf(v.z), hw = f2bf(v.w);
            uint2 hwv;
            hwv.x = hx | (hy << 16);
            hwv.y = hz | (hw << 16);
            float rx = v.x - __uint_as_float(hx << 16);
            float ry = v.y - __uint_as_float(hy << 16);
            float rz = v.z - __uint_as_float(hz << 16);
            float rw = v.w - __uint_as_float(hw << 16);
            uint2 lwv;
            lwv.x = f2bf(rx) | (f2bf(ry) << 16);
            lwv.y = f2bf(rz) | (f2bf(rw) << 16);
            *(uint2*)(&uh[t * 72 + mb]) = hwv;
            *(uint2*)(&ul[t * 72 + mb]) = lwv;
        }
    }
    // ---- per-mode constants (needed by kpart j==0, scan M)
    if (tid < 32) {
        int n = tid;
        float dt = expf(log_dt[h]);
        float ar = A_re[h * NN + n], ai = A_im[h * NN + n];
        float dtar = dt * ar, dtai = dt * ai;
        float ea = expf(dtar);
        float s, c; sincosf(dtai, &s, &c);
        float dA_r = ea * c, dA_i = ea * s;
        float em_r = dA_r - 1.0f, em_i = dA_i;
        float inv = 1.0f / (ar * ar + ai * ai);
        float t_r = (em_r * ar + em_i * ai) * inv;
        float t_i = (em_i * ar - em_r * ai) * inv;
        float br = B_re[h * NN + n], bi = B_im[h * NN + n];
        cst_lds[0 * 32 + n] = dtar;
        cst_lds[1 * 32 + n] = dtai;
        cst_lds[2 * 32 + n] = dA_r;
        cst_lds[3 * 32 + n] = dA_i;
        cst_lds[4 * 32 + n] = t_r * br - t_i * bi;
        cst_lds[5 * 32 + n] = t_r * bi + t_i * br;
        cst_lds[6 * 32 + n] = 2.0f * C_re[h * NN + n];
        cst_lds[7 * 32 + n] = 2.0f * C_im[h * NN + n];
    }
    __syncthreads();   // S0

    // ---- Phase 1 (MFMA): A3 frags from table
    {
        int nprime = w * 16 + l15;
        const unsigned* a3b = A3t + (size_t)h * 4096 + nprime;
        short8 a3h0, a3l0, a3h1, a3l1;
#pragma unroll
        for (int j = 0; j < 8; j++) {
            unsigned v = a3b[(g * 8 + j) * 64];
            a3h0[j] = (short)(v >> 16); a3l0[j] = (short)(v & 0xffffu);
            unsigned v2 = a3b[(32 + g * 8 + j) * 64];
            a3h1[j] = (short)(v2 >> 16); a3l1[j] = (short)(v2 & 0xffffu);
        }
#pragma unroll
        for (int ni = 0; ni < 4; ni++) {
            int t = ni * 16 + l15;
            short8 uH0 = *(const short8*)(uh + t * 72 + g * 8);
            short8 uL0 = *(const short8*)(ul + t * 72 + g * 8);
            short8 uH1 = *(const short8*)(uh + t * 72 + 32 + g * 8);
            short8 uL1 = *(const short8*)(ul + t * 72 + 32 + g * 8);
            f32x4 a = (f32x4){0.f, 0.f, 0.f, 0.f};
            a = __builtin_amdgcn_mfma_f32_16x16x32_bf16(a3h0, uH0, a, 0, 0, 0);
            a = __builtin_amdgcn_mfma_f32_16x16x32_bf16(a3l0, uH0, a, 0, 0, 0);
            a = __builtin_amdgcn_mfma_f32_16x16x32_bf16(a3h0, uL0, a, 0, 0, 0);
            a = __builtin_amdgcn_mfma_f32_16x16x32_bf16(a3h1, uH1, a, 0, 0, 0);
            a = __builtin_amdgcn_mfma_f32_16x16x32_bf16(a3l1, uH1, a, 0, 0, 0);
            a = __builtin_amdgcn_mfma_f32_16x16x32_bf16(a3h1, uL1, a, 0, 0, 0);
            int nprime2 = w * 16 + g * 4;
#pragma unroll
            for (int r = 0; r < 4; r++) {
                int nn2 = nprime2 + r;
                if (nn2 < 32) XsR[nn2 * 65 + t] = __float_as_uint(a[r]);
                else          XsI[(nn2 - 32) * 65 + t] = __float_as_uint(a[r]);
            }
        }
    }
    // ---- kpart from Et: k[j] = sum_n [rec(e0)*dbr + rec(e1)*dbi]
    {
        int j = tid & 63, nr = tid >> 6;
        float acc = 0.0f;
        if (j == 0) {
#pragma unroll
            for (int q = 0; q < 8; q++) {
                int n = nr * 8 + q;
                acc = fmaf(cst_lds[6 * 32 + n], cst_lds[4 * 32 + n], acc);
                acc = fmaf(-cst_lds[7 * 32 + n], cst_lds[5 * 32 + n], acc);
            }
        } else {
            const unsigned* eb = Et + (size_t)h * 4096 + (j - 1) * 64;
#pragma unroll
            for (int q = 0; q < 8; q++) {
                int n = nr * 8 + q;
                acc = fmaf(reconhl(eb[n]), cst_lds[4 * 32 + n], acc);
                acc = fmaf(reconhl(eb[32 + n]), cst_lds[5 * 32 + n], acc);
            }
        }
        kpart[nr * 64 + j] = acc;
    }
    __syncthreads();   // S1

    // ---- scan (tid<32) | karr finalize (64..127) | zero pad (128..191) — guarded bounds
    if (tid < 32) {
        int n = tid;
        float dtar = cst_lds[0 * 32 + n], dtai = cst_lds[1 * 32 + n];
        float mr = expf(64.0f * dtar);
        float s, c; sincosf(64.0f * dtai, &s, &c);
        float Mr = mr * c, Mi = mr * s;
        float cr = 0.f, ci = 0.f;
        unsigned* pR = XsR + n * 65;
        unsigned* pI = XsI + n * 65;
        float fr = __uint_as_float(pR[0]);
        float fi2 = __uint_as_float(pI[0]);
#pragma unroll 4
        for (int t = 0; t < 64; t++) {
            float frn = 0.f, fin = 0.f;
            if (t < 63) { frn = __uint_as_float(pR[t + 1]); fin = __uint_as_float(pI[t + 1]); }
            pR[t] = packhl(cr);
            pI[t] = packhl(ci);
            float nr = fmaf(Mr, cr, fmaf(-Mi, ci, fr));
            float nic = fmaf(Mr, ci, fmaf(Mi, cr, fi2));
            cr = nr; ci = nic;
            fr = frn; fi2 = fin;
        }
    } else if (tid >= 64 && tid < 128) {
        int j = tid - 64;
        float k = kpart[j] + kpart[64 + j] + kpart[128 + j] + kpart[192 + j];
        karr_pk[64 + j] = packhl(k);
    } else if (tid >= 128 && tid < 192) {
        karr_pk[tid - 128] = 0u;
    }
    __syncthreads();   // S2

    // ---- Phase 3 (MFMA, 12x): K frags from LDS, E frags from table
    {
        int i = w * 16 + l15;
        short8 kh0, kl0, kh1, kl1;
#pragma unroll
        for (int j = 0; j < 8; j++) {
            unsigned v0 = karr_pk[64 + i - (g * 8 + j)];
            kh0[j] = (short)(v0 >> 16); kl0[j] = (short)(v0 & 0xffffu);
            unsigned v1 = karr_pk[64 + i - (32 + g * 8 + j)];
            kh1[j] = (short)(v1 >> 16); kl1[j] = (short)(v1 & 0xffffu);
        }
        short8 e0h, e0l, e1h, e1l;
        {
            const unsigned* eb = Et + (size_t)h * 4096 + i * 64;
#pragma unroll
            for (int j = 0; j < 8; j++) {
                int n = g * 8 + j;
                unsigned v = eb[n];
                e0h[j] = (short)(v >> 16); e0l[j] = (short)(v & 0xffffu);
                unsigned v2 = eb[32 + n];
                e1h[j] = (short)(v2 >> 16); e1l[j] = (short)(v2 & 0xffffu);
            }
        }
        float Dh = D[h];
        unsigned short* orow = yhi + ((size_t)(b * HH + h)) * LL;
#pragma unroll
        for (int ni = 0; ni < 4; ni++) {
            int t = ni * 16 + l15;
            short8 uH0 = *(const short8*)(uh + t * 72 + g * 8);
            short8 uL0 = *(const short8*)(ul + t * 72 + g * 8);
            short8 uH1 = *(const short8*)(uh + t * 72 + 32 + g * 8);
            short8 uL1 = *(const short8*)(ul + t * 72 + 32 + g * 8);
            short8 xrh, xrl, xih, xil;
#pragma unroll
            for (int j = 0; j < 8; j++) {
                unsigned v = XsR[(g * 8 + j) * 65 + t];
                xrh[j] = (short)(v >> 16); xrl[j] = (short)(v & 0xffffu);
                unsigned v2 = XsI[(g * 8 + j) * 65 + t];
                xih[j] = (short)(v2 >> 16); xil[j] = (short)(v2 & 0xffffu);
            }
            f32x4 a = (f32x4){0.f, 0.f, 0.f, 0.f};
            a = __builtin_amdgcn_mfma_f32_16x16x32_bf16(kh0, uH0, a, 0, 0, 0);
            a = __builtin_amdgcn_mfma_f32_16x16x32_bf16(kl0, uH0, a, 0, 0, 0);
            a = __builtin_amdgcn_mfma_f32_16x16x32_bf16(kh0, uL0, a, 0, 0, 0);
            a = __builtin_amdgcn_mfma_f32_16x16x32_bf16(kh1, uH1, a, 0, 0, 0);
            a = __builtin_amdgcn_mfma_f32_16x16x32_bf16(kl1, uH1, a, 0, 0, 0);
            a = __builtin_amdgcn_mfma_f32_16x16x32_bf16(kh1, uL1, a, 0, 0, 0);
            a = __builtin_amdgcn_mfma_f32_16x16x32_bf16(e0h, xrh, a, 0, 0, 0);
            a = __builtin_amdgcn_mfma_f32_16x16x32_bf16(e0h, xrl, a, 0, 0, 0);
            a = __builtin_amdgcn_mfma_f32_16x16x32_bf16(e0l, xrh, a, 0, 0, 0);
            a = __builtin_amdgcn_mfma_f32_16x16x32_bf16(e1h, xih, a, 0, 0, 0);
            a = __builtin_amdgcn_mfma_f32_16x16x32_bf16(e1h, xil, a, 0, 0, 0);
            a = __builtin_amdgcn_mfma_f32_16x16x32_bf16(e1l, xih, a, 0, 0, 0);
            ushort4 ov;
            unsigned short* op = &ov.x;
#pragma unroll
            for (int r = 0; r < 4; r++) {
                int io = w * 16 + g * 4 + r;
                float uv = __uint_as_float(((unsigned)uh[t * 72 + io]) << 16)
                         + __uint_as_float(((unsigned)ul[t * 72 + io]) << 16);
                float y = a[r] + Dh * uv;
                float gl = 0.5f * y * (1.0f + erff(y * 0.70710678118654752f));
                op[r] = (unsigned short)f2bf(gl);
            }
            *(ushort4*)(&orow[t * 64 + w * 16 + g * 4]) = ov;
        }
    }
}

// ---------------- Kernel C: MFMA bf16 GEMM + bias + GLU (W converted in-kernel) ----------------
__global__ __launch_bounds__(256) void gemm_glu_mfma(const unsigned short* __restrict__ yhi,
                                                     const float* __restrict__ W,
                                                     const float* __restrict__ bias,
                                                     float* __restrict__ out) {
    const int b = blockIdx.z;
    const int d0 = blockIdx.y * 64;
    const int l0 = blockIdx.x * 128;
    const int tid = threadIdx.x;
    const int lane = tid & 63;
    const int wid = tid >> 6;
    const int wave_m = wid & 1;
    const int wave_n = wid >> 1;

    __shared__ unsigned short Ysh[32 * 128];
    __shared__ char Wlds[128 * 64];

    f32x4 acc[4][4];
#pragma unroll
    for (int i = 0; i < 4; i++)
#pragma unroll
        for (int j = 0; j < 4; j++) acc[i][j] = (f32x4){0.f, 0.f, 0.f, 0.f};

    for (int kt = 0; kt < 16; kt++) {
        const int h0 = kt * 32;
        __syncthreads();
#pragma unroll
        for (int q = 0; q < 2; q++) {
            int cid = q * 256 + tid;
            int kr = cid >> 4;
            int cc = cid & 15;
            int scol = (cc * 8) ^ ((kr & 8) ? 16 : 0);
            const unsigned short* src = yhi + ((size_t)(b * HH + h0 + kr)) * LL + l0 + scol;
            gload_lds16(src, (char*)Ysh + cid * 16);
        }
        {
            int row = tid >> 1;
            int kb = (tid & 1) * 16;
            int qq = (row >> 1) & 3;
            int grow = (row < 64) ? (d0 + row) : (448 + d0 + row);
            const float* src = W + (size_t)grow * 512 + h0 + kb;
            float4 w0 = *(const float4*)(src);
            float4 w1 = *(const float4*)(src + 4);
            float4 w2 = *(const float4*)(src + 8);
            float4 w3 = *(const float4*)(src + 12);
            short8 v0, v1;
            v0[0] = (short)f2bf(w0.x); v0[1] = (short)f2bf(w0.y);
            v0[2] = (short)f2bf(w0.z); v0[3] = (short)f2bf(w0.w);
            v0[4] = (short)f2bf(w1.x); v0[5] = (short)f2bf(w1.y);
            v0[6] = (short)f2bf(w1.z); v0[7] = (short)f2bf(w1.w);
            v1[0] = (short)f2bf(w2.x); v1[1] = (short)f2bf(w2.y);
            v1[2] = (short)f2bf(w2.z); v1[3] = (short)f2bf(w2.w);
            v1[4] = (short)f2bf(w3.x); v1[5] = (short)f2bf(w3.y);
            v1[6] = (short)f2bf(w3.z); v1[7] = (short)f2bf(w3.w);
            int g0 = kb >> 3;
            *(short8*)(Wlds + row * 64 + ((g0 ^ qq) * 16)) = v0;
            *(short8*)(Wlds + row * 64 + (((g0 + 1) ^ qq) * 16)) = v1;
        }
        __syncthreads();

        short8 af[4];
#pragma unroll
        for (int mi = 0; mi < 4; mi++) {
            int rowb = (mi < 2) ? (wave_m * 32 + mi * 16) : (64 + wave_m * 32 + (mi - 2) * 16);
            int row = rowb + (lane & 15);
            int qq = (row >> 1) & 3;
            int gp = lane >> 4;
            af[mi] = *(const short8*)(Wlds + row * 64 + ((gp ^ qq) * 16));
        }
#pragma unroll
        for (int ni = 0; ni < 4; ni++) {
            int col = wave_n * 64 + ni * 16 + (lane & 15);
            int gq = lane >> 4;
            int cs = col ^ ((gq & 1) << 4);
            const unsigned short* yb = Ysh + (8 * gq) * 128 + cs;
            short8 bh;
            bh[0] = (short)yb[0 * 128];
            bh[1] = (short)yb[1 * 128];
            bh[2] = (short)yb[2 * 128];
            bh[3] = (short)yb[3 * 128];
            bh[4] = (short)yb[4 * 128];
            bh[5] = (short)yb[5 * 128];
            bh[6] = (short)yb[6 * 128];
            bh[7] = (short)yb[7 * 128];
#pragma unroll
            for (int mi = 0; mi < 4; mi++) {
                acc[mi][ni] = __builtin_amdgcn_mfma_f32_16x16x32_bf16(af[mi], bh, acc[mi][ni], 0, 0, 0);
            }
        }
    }

#pragma unroll
    for (int mi = 0; mi < 2; mi++) {
        int dbase = d0 + wave_m * 32 + mi * 16 + ((lane >> 4) << 2);
#pragma unroll
        for (int r = 0; r < 4; r++) {
            int d = dbase + r;
            float b1 = bias[d], b2 = bias[DMOUT + d];
#pragma unroll
            for (int ni = 0; ni < 4; ni++) {
                int l = l0 + wave_n * 64 + ni * 16 + (lane & 15);
                float z1 = acc[mi][ni][r] + b1;
                float z2 = acc[mi + 2][ni][r] + b2;
                out[((size_t)(b * DMOUT + d)) * LL + l] = z1 * (1.0f / (1.0f + expf(-z2)));
            }
        }
    }
}

extern "C" void kernel_launch(void* const* d_in, const int* in_sizes, int n_in,
                              void* d_out, int out_size, void* d_ws, size_t ws_size,
                              hipStream_t stream) {
    const float* u      = (const float*)d_in[0];
    const float* log_dt = (const float*)d_in[1];
    const float* A_re   = (const float*)d_in[2];
    const float* A_im   = (const float*)d_in[3];
    const float* B_re   = (const float*)d_in[4];
    const float* B_im   = (const float*)d_in[5];
    const float* C_re   = (const float*)d_in[6];
    const float* C_im   = (const float*)d_in[7];
    const float* D      = (const float*)d_in[8];
    const float* W      = (const float*)d_in[9];
    const float* bias   = (const float*)d_in[10];
    float* out = (float*)d_out;

    char* ws = (char*)d_ws;
    unsigned short* yhi = (unsigned short*)ws;                  // 16,777,216 B
    unsigned* A3t = (unsigned*)(ws + 16777216);                 //  8,388,608 B
    unsigned* Et  = (unsigned*)(ws + 16777216 + 8388608);       //  8,388,608 B  (total 32 MB)

    prep_kernel<<<HH, 256, 0, stream>>>(log_dt, A_re, A_im, B_re, B_im, C_re, C_im, A3t, Et);
    ssm_kernel<<<dim3(HH, BB), 256, 0, stream>>>(u, log_dt, A_re, A_im, B_re, B_im,
                                                 C_re, C_im, D, A3t, Et, yhi);
    gemm_glu_mfma<<<dim3(32, 8, BB), 256, 0, stream>>>(yhi, W, bias, out);
}

// Round 16
// 93.877 us; speedup vs baseline: 4.7483x; 1.0219x over previous
//
#include <hip/hip_runtime.h>
#include <math.h>

#define BB 4
#define HH 512
#define LL 4096
#define NN 32
#define DMOUT 512

typedef __attribute__((ext_vector_type(8))) short short8;
typedef __attribute__((ext_vector_type(4))) float f32x4;

__device__ __forceinline__ unsigned f2bf(float x) {
    unsigned u = __float_as_uint(x);
    return (u + 0x7fffu + ((u >> 16) & 1u)) >> 16;
}
__device__ __forceinline__ unsigned packhl(float x) {
    unsigned hb = f2bf(x);
    float xh = __uint_as_float(hb << 16);
    return (hb << 16) | f2bf(x - xh);
}
__device__ __forceinline__ float reconhl(unsigned v) {
    return __uint_as_float(v & 0xffff0000u) + __uint_as_float(v << 16);
}
__device__ __forceinline__ void gload_lds16(const void* g, void* l) {
    __builtin_amdgcn_global_load_lds((const __attribute__((address_space(1))) void*)g,
                                     (__attribute__((address_space(3))) void*)l, 16, 0, 0);
}

// ---------------- Kernel A2: W -> bf16 hi split ----------------
__global__ void wsplit_kernel(const float* __restrict__ W, unsigned short* __restrict__ whi) {
    int i = (blockIdx.x * 256 + threadIdx.x) * 4;
    float4 w = *(const float4*)(W + i);
    ushort4 o;
    o.x = (unsigned short)f2bf(w.x);
    o.y = (unsigned short)f2bf(w.y);
    o.z = (unsigned short)f2bf(w.z);
    o.w = (unsigned short)f2bf(w.w);
    *(ushort4*)(whi + i) = o;
}

// ---------------- Kernel P: per-h tables (A3t, Et) ----------------
__global__ __launch_bounds__(256) void prep_kernel(
    const float* __restrict__ log_dt,
    const float* __restrict__ A_re, const float* __restrict__ A_im,
    const float* __restrict__ B_re, const float* __restrict__ B_im,
    const float* __restrict__ C_re, const float* __restrict__ C_im,
    unsigned* __restrict__ A3t, unsigned* __restrict__ Et) {
    const int h = blockIdx.x;
    const int tid = threadIdx.x;
    __shared__ float cst_lds[256];

    if (tid < 32) {
        int n = tid;
        float dt = expf(log_dt[h]);
        float ar = A_re[h * NN + n], ai = A_im[h * NN + n];
        float dtar = dt * ar, dtai = dt * ai;
        float ea = expf(dtar);
        float s, c; sincosf(dtai, &s, &c);
        float dA_r = ea * c, dA_i = ea * s;
        float em_r = dA_r - 1.0f, em_i = dA_i;
        float inv = 1.0f / (ar * ar + ai * ai);
        float t_r = (em_r * ar + em_i * ai) * inv;
        float t_i = (em_i * ar - em_r * ai) * inv;
        float br = B_re[h * NN + n], bi = B_im[h * NN + n];
        cst_lds[0 * 32 + n] = dtar;
        cst_lds[1 * 32 + n] = dtai;
        cst_lds[2 * 32 + n] = dA_r;
        cst_lds[3 * 32 + n] = dA_i;
        cst_lds[4 * 32 + n] = t_r * br - t_i * bi;
        cst_lds[5 * 32 + n] = t_r * bi + t_i * br;
        cst_lds[6 * 32 + n] = 2.0f * C_re[h * NN + n];
        cst_lds[7 * 32 + n] = 2.0f * C_im[h * NN + n];
    }
    __syncthreads();

    const int n = tid & 31, q = tid >> 5;
    const float dtar = cst_lds[0 * 32 + n], dtai = cst_lds[1 * 32 + n];
    const float dAr = cst_lds[2 * 32 + n], dAi = cst_lds[3 * 32 + n];
    const float dbr = cst_lds[4 * 32 + n], dbi = cst_lds[5 * 32 + n];
    const float tcr = cst_lds[6 * 32 + n], tci = cst_lds[7 * 32 + n];

    {
        float p = (float)(56 - q * 8);
        float mr = expf(p * dtar);
        float s, c; sincosf(p * dtai, &s, &c);
        float pr = mr * c, pi = mr * s;
        unsigned* base = A3t + (size_t)h * 4096;
#pragma unroll
        for (int jj = 7; jj >= 0; jj--) {
            int m = q * 8 + jj;
            base[m * 64 + n]      = packhl(dbr * pr - dbi * pi);
            base[m * 64 + 32 + n] = packhl(dbr * pi + dbi * pr);
            float nr2 = pr * dAr - pi * dAi;
            pi = pr * dAi + pi * dAr;
            pr = nr2;
        }
    }
    {
        float p = (float)(q * 8 + 1);
        float mr = expf(p * dtar);
        float s, c; sincosf(p * dtai, &s, &c);
        float pr = mr * c, pi = mr * s;
        unsigned* base = Et + (size_t)h * 4096;
#pragma unroll
        for (int i = q * 8; i <= q * 8 + 7; i++) {
            base[i * 64 + n]      = packhl(tcr * pr - tci * pi);
            base[i * 64 + 32 + n] = packhl(-(tcr * pi + tci * pr));
            float nr2 = pr * dAr - pi * dAi;
            pi = pr * dAi + pi * dAr;
            pr = nr2;
        }
    }
}

// ---------------- Kernel B: SSM conv via MFMA chunked scan + D skip + GELU ----------------
__global__ __launch_bounds__(256, 4) void ssm_kernel(
    const float* __restrict__ u, const float* __restrict__ log_dt,
    const float* __restrict__ A_re, const float* __restrict__ A_im,
    const float* __restrict__ B_re, const float* __restrict__ B_im,
    const float* __restrict__ C_re, const float* __restrict__ C_im,
    const float* __restrict__ D,
    const unsigned* __restrict__ A3t, const unsigned* __restrict__ Et,
    unsigned short* __restrict__ yhi) {
    const int h = blockIdx.x;
    const int b = blockIdx.y;
    const int tid = threadIdx.x;
    const int lane = tid & 63;
    const int w = tid >> 6;
    const int g = lane >> 4;
    const int l15 = lane & 15;

    __shared__ unsigned short uh[64 * 72];
    __shared__ unsigned short ul[64 * 72];
    __shared__ unsigned XsR[32 * 65];
    __shared__ unsigned XsI[32 * 65];
    __shared__ unsigned karr_pk[128];
    __shared__ float kpart[256];
    __shared__ float cst_lds[256];

    {
        const float* urow = u + ((size_t)(b * HH + h)) * LL;
#pragma unroll
        for (int r = 0; r < 4; r++) {
            int f = tid + 256 * r;
            float4 v = *(const float4*)(urow + f * 4);
            int t = f >> 4, mb = (f & 15) << 2;
            unsigned hx = f2bf(v.x), hy = f2bf(v.y), hz = f2bf(v.z), hw = f2bf(v.w);
            uint2 hwv;
            hwv.x = hx | (hy << 16);
            hwv.y = hz | (hw << 16);
            float rx = v.x - __uint_as_float(hx << 16);
            float ry = v.y - __uint_as_float(hy << 16);
            float rz = v.z - __uint_as_float(hz << 16);
            float rw = v.w - __uint_as_float(hw << 16);
            uint2 lwv;
            lwv.x = f2bf(rx) | (f2bf(ry) << 16);
            lwv.y = f2bf(rz) | (f2bf(rw) << 16);
            *(uint2*)(&uh[t * 72 + mb]) = hwv;
            *(uint2*)(&ul[t * 72 + mb]) = lwv;
        }
    }
    if (tid < 32) {
        int n = tid;
        float dt = expf(log_dt[h]);
        float ar = A_re[h * NN + n], ai = A_im[h * NN + n];
        float dtar = dt * ar, dtai = dt * ai;
        float ea = expf(dtar);
        float s, c; sincosf(dtai, &s, &c);
        float dA_r = ea * c, dA_i = ea * s;
        float em_r = dA_r - 1.0f, em_i = dA_i;
        float inv = 1.0f / (ar * ar + ai * ai);
        float t_r = (em_r * ar + em_i * ai) * inv;
        float t_i = (em_i * ar - em_r * ai) * inv;
        float br = B_re[h * NN + n], bi = B_im[h * NN + n];
        cst_lds[0 * 32 + n] = dtar;
        cst_lds[1 * 32 + n] = dtai;
        cst_lds[2 * 32 + n] = dA_r;
        cst_lds[3 * 32 + n] = dA_i;
        cst_lds[4 * 32 + n] = t_r * br - t_i * bi;
        cst_lds[5 * 32 + n] = t_r * bi + t_i * br;
        cst_lds[6 * 32 + n] = 2.0f * C_re[h * NN + n];
        cst_lds[7 * 32 + n] = 2.0f * C_im[h * NN + n];
    }
    __syncthreads();   // S0

    {
        int nprime = w * 16 + l15;
        const unsigned* a3b = A3t + (size_t)h * 4096 + nprime;
        short8 a3h0, a3l0, a3h1, a3l1;
#pragma unroll
        for (int j = 0; j < 8; j++) {
            unsigned v = a3b[(g * 8 + j) * 64];
            a3h0[j] = (short)(v >> 16); a3l0[j] = (short)(v & 0xffffu);
            unsigned v2 = a3b[(32 + g * 8 + j) * 64];
            a3h1[j] = (short)(v2 >> 16); a3l1[j] = (short)(v2 & 0xffffu);
        }
#pragma unroll
        for (int ni = 0; ni < 4; ni++) {
            int t = ni * 16 + l15;
            short8 uH0 = *(const short8*)(uh + t * 72 + g * 8);
            short8 uL0 = *(const short8*)(ul + t * 72 + g * 8);
            short8 uH1 = *(const short8*)(uh + t * 72 + 32 + g * 8);
            short8 uL1 = *(const short8*)(ul + t * 72 + 32 + g * 8);
            f32x4 a = (f32x4){0.f, 0.f, 0.f, 0.f};
            a = __builtin_amdgcn_mfma_f32_16x16x32_bf16(a3h0, uH0, a, 0, 0, 0);
            a = __builtin_amdgcn_mfma_f32_16x16x32_bf16(a3l0, uH0, a, 0, 0, 0);
            a = __builtin_amdgcn_mfma_f32_16x16x32_bf16(a3h0, uL0, a, 0, 0, 0);
            a = __builtin_amdgcn_mfma_f32_16x16x32_bf16(a3h1, uH1, a, 0, 0, 0);
            a = __builtin_amdgcn_mfma_f32_16x16x32_bf16(a3l1, uH1, a, 0, 0, 0);
            a = __builtin_amdgcn_mfma_f32_16x16x32_bf16(a3h1, uL1, a, 0, 0, 0);
            int nprime2 = w * 16 + g * 4;
#pragma unroll
            for (int r = 0; r < 4; r++) {
                int nn2 = nprime2 + r;
                if (nn2 < 32) XsR[nn2 * 65 + t] = __float_as_uint(a[r]);
                else          XsI[(nn2 - 32) * 65 + t] = __float_as_uint(a[r]);
            }
        }
    }
    {
        int j = tid & 63, nr = tid >> 6;
        float acc = 0.0f;
        if (j == 0) {
#pragma unroll
            for (int q = 0; q < 8; q++) {
                int n = nr * 8 + q;
                acc = fmaf(cst_lds[6 * 32 + n], cst_lds[4 * 32 + n], acc);
                acc = fmaf(-cst_lds[7 * 32 + n], cst_lds[5 * 32 + n], acc);
            }
        } else {
            const unsigned* eb = Et + (size_t)h * 4096 + (j - 1) * 64;
#pragma unroll
            for (int q = 0; q < 8; q++) {
                int n = nr * 8 + q;
                acc = fmaf(reconhl(eb[n]), cst_lds[4 * 32 + n], acc);
                acc = fmaf(reconhl(eb[32 + n]), cst_lds[5 * 32 + n], acc);
            }
        }
        kpart[nr * 64 + j] = acc;
    }
    __syncthreads();   // S1

    if (tid < 32) {
        int n = tid;
        float dtar = cst_lds[0 * 32 + n], dtai = cst_lds[1 * 32 + n];
        float mr = expf(64.0f * dtar);
        float s, c; sincosf(64.0f * dtai, &s, &c);
        float Mr = mr * c, Mi = mr * s;
        float cr = 0.f, ci = 0.f;
        unsigned* pR = XsR + n * 65;
        unsigned* pI = XsI + n * 65;
        float fr = __uint_as_float(pR[0]);
        float fi2 = __uint_as_float(pI[0]);
#pragma unroll 4
        for (int t = 0; t < 64; t++) {
            float frn = 0.f, fin = 0.f;
            if (t < 63) { frn = __uint_as_float(pR[t + 1]); fin = __uint_as_float(pI[t + 1]); }
            pR[t] = packhl(cr);
            pI[t] = packhl(ci);
            float nr = fmaf(Mr, cr, fmaf(-Mi, ci, fr));
            float nic = fmaf(Mr, ci, fmaf(Mi, cr, fi2));
            cr = nr; ci = nic;
            fr = frn; fi2 = fin;
        }
    } else if (tid >= 64 && tid < 128) {
        int j = tid - 64;
        float k = kpart[j] + kpart[64 + j] + kpart[128 + j] + kpart[192 + j];
        karr_pk[64 + j] = packhl(k);
    } else if (tid >= 128 && tid < 192) {
        karr_pk[tid - 128] = 0u;
    }
    __syncthreads();   // S2

    {
        int i = w * 16 + l15;
        short8 kh0, kl0, kh1, kl1;
#pragma unroll
        for (int j = 0; j < 8; j++) {
            unsigned v0 = karr_pk[64 + i - (g * 8 + j)];
            kh0[j] = (short)(v0 >> 16); kl0[j] = (short)(v0 & 0xffffu);
            unsigned v1 = karr_pk[64 + i - (32 + g * 8 + j)];
            kh1[j] = (short)(v1 >> 16); kl1[j] = (short)(v1 & 0xffffu);
        }
        short8 e0h, e0l, e1h, e1l;
        {
            const unsigned* eb = Et + (size_t)h * 4096 + i * 64;
#pragma unroll
            for (int j = 0; j < 8; j++) {
                int n = g * 8 + j;
                unsigned v = eb[n];
                e0h[j] = (short)(v >> 16); e0l[j] = (short)(v & 0xffffu);
                unsigned v2 = eb[32 + n];
                e1h[j] = (short)(v2 >> 16); e1l[j] = (short)(v2 & 0xffffu);
            }
        }
        float Dh = D[h];
        unsigned short* orow = yhi + ((size_t)(b * HH + h)) * LL;
#pragma unroll
        for (int ni = 0; ni < 4; ni++) {
            int t = ni * 16 + l15;
            short8 uH0 = *(const short8*)(uh + t * 72 + g * 8);
            short8 uL0 = *(const short8*)(ul + t * 72 + g * 8);
            short8 uH1 = *(const short8*)(uh + t * 72 + 32 + g * 8);
            short8 uL1 = *(const short8*)(ul + t * 72 + 32 + g * 8);
            short8 xrh, xrl, xih, xil;
#pragma unroll
            for (int j = 0; j < 8; j++) {
                unsigned v = XsR[(g * 8 + j) * 65 + t];
                xrh[j] = (short)(v >> 16); xrl[j] = (short)(v & 0xffffu);
                unsigned v2 = XsI[(g * 8 + j) * 65 + t];
                xih[j] = (short)(v2 >> 16); xil[j] = (short)(v2 & 0xffffu);
            }
            f32x4 a = (f32x4){0.f, 0.f, 0.f, 0.f};
            a = __builtin_amdgcn_mfma_f32_16x16x32_bf16(kh0, uH0, a, 0, 0, 0);
            a = __builtin_amdgcn_mfma_f32_16x16x32_bf16(kl0, uH0, a, 0, 0, 0);
            a = __builtin_amdgcn_mfma_f32_16x16x32_bf16(kh0, uL0, a, 0, 0, 0);
            a = __builtin_amdgcn_mfma_f32_16x16x32_bf16(kh1, uH1, a, 0, 0, 0);
            a = __builtin_amdgcn_mfma_f32_16x16x32_bf16(kl1, uH1, a, 0, 0, 0);
            a = __builtin_amdgcn_mfma_f32_16x16x32_bf16(kh1, uL1, a, 0, 0, 0);
            a = __builtin_amdgcn_mfma_f32_16x16x32_bf16(e0h, xrh, a, 0, 0, 0);
            a = __builtin_amdgcn_mfma_f32_16x16x32_bf16(e0h, xrl, a, 0, 0, 0);
            a = __builtin_amdgcn_mfma_f32_16x16x32_bf16(e0l, xrh, a, 0, 0, 0);
            a = __builtin_amdgcn_mfma_f32_16x16x32_bf16(e1h, xih, a, 0, 0, 0);
            a = __builtin_amdgcn_mfma_f32_16x16x32_bf16(e1h, xil, a, 0, 0, 0);
            a = __builtin_amdgcn_mfma_f32_16x16x32_bf16(e1l, xih, a, 0, 0, 0);
            ushort4 ov;
            unsigned short* op = &ov.x;
#pragma unroll
            for (int r = 0; r < 4; r++) {
                int io = w * 16 + g * 4 + r;
                float uv = __uint_as_float(((unsigned)uh[t * 72 + io]) << 16)
                         + __uint_as_float(((unsigned)ul[t * 72 + io]) << 16);
                float y = a[r] + Dh * uv;
                float gl = 0.5f * y * (1.0f + erff(y * 0.70710678118654752f));
                op[r] = (unsigned short)f2bf(gl);
            }
            *(ushort4*)(&orow[t * 64 + w * 16 + g * 4]) = ov;
        }
    }
}

// ---------------- Kernel C: MFMA bf16 GEMM + bias + GLU ----------------
__global__ __launch_bounds__(256) void gemm_glu_mfma(const unsigned short* __restrict__ yhi,
                                                     const float* __restrict__ W,
                                                     const unsigned short* __restrict__ whi,
                                                     const float* __restrict__ bias,
                                                     float* __restrict__ out, int preW) {
    const int b = blockIdx.z;
    const int d0 = blockIdx.y * 64;
    const int l0 = blockIdx.x * 128;
    const int tid = threadIdx.x;
    const int lane = tid & 63;
    const int wid = tid >> 6;
    const int wave_m = wid & 1;
    const int wave_n = wid >> 1;

    __shared__ unsigned short Ysh[32 * 128];
    __shared__ char Wlds[128 * 64];

    f32x4 acc[4][4];
#pragma unroll
    for (int i = 0; i < 4; i++)
#pragma unroll
        for (int j = 0; j < 4; j++) acc[i][j] = (f32x4){0.f, 0.f, 0.f, 0.f};

    for (int kt = 0; kt < 16; kt++) {
        const int h0 = kt * 32;
        __syncthreads();
#pragma unroll
        for (int q = 0; q < 2; q++) {
            int cid = q * 256 + tid;
            int kr = cid >> 4;
            int cc = cid & 15;
            int scol = (cc * 8) ^ ((kr & 8) ? 16 : 0);
            const unsigned short* src = yhi + ((size_t)(b * HH + h0 + kr)) * LL + l0 + scol;
            gload_lds16(src, (char*)Ysh + cid * 16);
        }
        if (preW) {
#pragma unroll
            for (int e = 0; e < 2; e++) {
                int c = e * 256 + tid;
                int row = c >> 2;
                int gx = c & 3;
                int qq = (row >> 1) & 3;
                int grow = (row < 64) ? (d0 + row) : (448 + d0 + row);
                const unsigned short* src = whi + (size_t)grow * 512 + h0 + ((gx ^ qq) * 8);
                gload_lds16(src, Wlds + c * 16);
            }
        } else {
            int row = tid >> 1;
            int kb = (tid & 1) * 16;
            int qq = (row >> 1) & 3;
            int grow = (row < 64) ? (d0 + row) : (448 + d0 + row);
            const float* src = W + (size_t)grow * 512 + h0 + kb;
            float4 w0 = *(const float4*)(src);
            float4 w1 = *(const float4*)(src + 4);
            float4 w2 = *(const float4*)(src + 8);
            float4 w3 = *(const float4*)(src + 12);
            short8 v0, v1;
            v0[0] = (short)f2bf(w0.x); v0[1] = (short)f2bf(w0.y);
            v0[2] = (short)f2bf(w0.z); v0[3] = (short)f2bf(w0.w);
            v0[4] = (short)f2bf(w1.x); v0[5] = (short)f2bf(w1.y);
            v0[6] = (short)f2bf(w1.z); v0[7] = (short)f2bf(w1.w);
            v1[0] = (short)f2bf(w2.x); v1[1] = (short)f2bf(w2.y);
            v1[2] = (short)f2bf(w2.z); v1[3] = (short)f2bf(w2.w);
            v1[4] = (short)f2bf(w3.x); v1[5] = (short)f2bf(w3.y);
            v1[6] = (short)f2bf(w3.z); v1[7] = (short)f2bf(w3.w);
            int g0 = kb >> 3;
            *(short8*)(Wlds + row * 64 + ((g0 ^ qq) * 16)) = v0;
            *(short8*)(Wlds + row * 64 + (((g0 + 1) ^ qq) * 16)) = v1;
        }
        __syncthreads();

        short8 af[4];
#pragma unroll
        for (int mi = 0; mi < 4; mi++) {
            int rowb = (mi < 2) ? (wave_m * 32 + mi * 16) : (64 + wave_m * 32 + (mi - 2) * 16);
            int row = rowb + (lane & 15);
            int qq = (row >> 1) & 3;
            int gp = lane >> 4;
            af[mi] = *(const short8*)(Wlds + row * 64 + ((gp ^ qq) * 16));
        }
#pragma unroll
        for (int ni = 0; ni < 4; ni++) {
            int col = wave_n * 64 + ni * 16 + (lane & 15);
            int gq = lane >> 4;
            int cs = col ^ ((gq & 1) << 4);
            const unsigned short* yb = Ysh + (8 * gq) * 128 + cs;
            short8 bh;
            bh[0] = (short)yb[0 * 128];
            bh[1] = (short)yb[1 * 128];
            bh[2] = (short)yb[2 * 128];
            bh[3] = (short)yb[3 * 128];
            bh[4] = (short)yb[4 * 128];
            bh[5] = (short)yb[5 * 128];
            bh[6] = (short)yb[6 * 128];
            bh[7] = (short)yb[7 * 128];
#pragma unroll
            for (int mi = 0; mi < 4; mi++) {
                acc[mi][ni] = __builtin_amdgcn_mfma_f32_16x16x32_bf16(af[mi], bh, acc[mi][ni], 0, 0, 0);
            }
        }
    }

#pragma unroll
    for (int mi = 0; mi < 2; mi++) {
        int dbase = d0 + wave_m * 32 + mi * 16 + ((lane >> 4) << 2);
#pragma unroll
        for (int r = 0; r < 4; r++) {
            int d = dbase + r;
            float b1 = bias[d], b2 = bias[DMOUT + d];
#pragma unroll
            for (int ni = 0; ni < 4; ni++) {
                int l = l0 + wave_n * 64 + ni * 16 + (lane & 15);
                float z1 = acc[mi][ni][r] + b1;
                float z2 = acc[mi + 2][ni][r] + b2;
                out[((size_t)(b * DMOUT + d)) * LL + l] = z1 * (1.0f / (1.0f + expf(-z2)));
            }
        }
    }
}

extern "C" void kernel_launch(void* const* d_in, const int* in_sizes, int n_in,
                              void* d_out, int out_size, void* d_ws, size_t ws_size,
                              hipStream_t stream) {
    const float* u      = (const float*)d_in[0];
    const float* log_dt = (const float*)d_in[1];
    const float* A_re   = (const float*)d_in[2];
    const float* A_im   = (const float*)d_in[3];
    const float* B_re   = (const float*)d_in[4];
    const float* B_im   = (const float*)d_in[5];
    const float* C_re   = (const float*)d_in[6];
    const float* C_im   = (const float*)d_in[7];
    const float* D      = (const float*)d_in[8];
    const float* W      = (const float*)d_in[9];
    const float* bias   = (const float*)d_in[10];
    float* out = (float*)d_out;

    char* ws = (char*)d_ws;
    unsigned short* yhi = (unsigned short*)ws;                     // 16,777,216 B
    unsigned* A3t = (unsigned*)(ws + 16777216);                    //  8,388,608 B
    unsigned* Et  = (unsigned*)(ws + 16777216 + 8388608);          //  8,388,608 B
    unsigned short* whi = (unsigned short*)(ws + 33554432);        //  1,048,576 B (total 34.6 MB)
    int preW = (ws_size >= (size_t)(33554432 + 1048576)) ? 1 : 0;

    if (preW) wsplit_kernel<<<512, 256, 0, stream>>>(W, whi);
    prep_kernel<<<HH, 256, 0, stream>>>(log_dt, A_re, A_im, B_re, B_im, C_re, C_im, A3t, Et);
    ssm_kernel<<<dim3(HH, BB), 256, 0, stream>>>(u, log_dt, A_re, A_im, B_re, B_im,
                                                 C_re, C_im, D, A3t, Et, yhi);
    gemm_glu_mfma<<<dim3(32, 8, BB), 256, 0, stream>>>(yhi, W, whi, bias, out, preW);
}

// Round 17
// 92.323 us; speedup vs baseline: 4.8282x; 1.0168x over previous
//
#include <hip/hip_runtime.h>
#include <math.h>

#define BB 4
#define HH 512
#define LL 4096
#define NN 32
#define DMOUT 512

typedef __attribute__((ext_vector_type(8))) short short8;
typedef __attribute__((ext_vector_type(4))) float f32x4;

__device__ __forceinline__ unsigned f2bf(float x) {
    unsigned u = __float_as_uint(x);
    return (u + 0x7fffu + ((u >> 16) & 1u)) >> 16;
}
__device__ __forceinline__ unsigned packhl(float x) {
    unsigned hb = f2bf(x);
    float xh = __uint_as_float(hb << 16);
    return (hb << 16) | f2bf(x - xh);
}
__device__ __forceinline__ float reconhl(unsigned v) {
    return __uint_as_float(v & 0xffff0000u) + __uint_as_float(v << 16);
}
__device__ __forceinline__ void gload_lds16(const void* g, void* l) {
    __builtin_amdgcn_global_load_lds((const __attribute__((address_space(1))) void*)g,
                                     (__attribute__((address_space(3))) void*)l, 16, 0, 0);
}

// ---------------- Kernel A2: W -> bf16 hi split ----------------
__global__ void wsplit_kernel(const float* __restrict__ W, unsigned short* __restrict__ whi) {
    int i = (blockIdx.x * 256 + threadIdx.x) * 4;
    float4 w = *(const float4*)(W + i);
    ushort4 o;
    o.x = (unsigned short)f2bf(w.x);
    o.y = (unsigned short)f2bf(w.y);
    o.z = (unsigned short)f2bf(w.z);
    o.w = (unsigned short)f2bf(w.w);
    *(ushort4*)(whi + i) = o;
}

// ---------------- Kernel P: per-h tables (A3t, Et) ----------------
__global__ __launch_bounds__(256) void prep_kernel(
    const float* __restrict__ log_dt,
    const float* __restrict__ A_re, const float* __restrict__ A_im,
    const float* __restrict__ B_re, const float* __restrict__ B_im,
    const float* __restrict__ C_re, const float* __restrict__ C_im,
    unsigned* __restrict__ A3t, unsigned* __restrict__ Et) {
    const int h = blockIdx.x;
    const int tid = threadIdx.x;
    __shared__ float cst_lds[256];

    if (tid < 32) {
        int n = tid;
        float dt = expf(log_dt[h]);
        float ar = A_re[h * NN + n], ai = A_im[h * NN + n];
        float dtar = dt * ar, dtai = dt * ai;
        float ea = expf(dtar);
        float s, c; sincosf(dtai, &s, &c);
        float dA_r = ea * c, dA_i = ea * s;
        float em_r = dA_r - 1.0f, em_i = dA_i;
        float inv = 1.0f / (ar * ar + ai * ai);
        float t_r = (em_r * ar + em_i * ai) * inv;
        float t_i = (em_i * ar - em_r * ai) * inv;
        float br = B_re[h * NN + n], bi = B_im[h * NN + n];
        cst_lds[0 * 32 + n] = dtar;
        cst_lds[1 * 32 + n] = dtai;
        cst_lds[2 * 32 + n] = dA_r;
        cst_lds[3 * 32 + n] = dA_i;
        cst_lds[4 * 32 + n] = t_r * br - t_i * bi;
        cst_lds[5 * 32 + n] = t_r * bi + t_i * br;
        cst_lds[6 * 32 + n] = 2.0f * C_re[h * NN + n];
        cst_lds[7 * 32 + n] = 2.0f * C_im[h * NN + n];
    }
    __syncthreads();

    const int n = tid & 31, q = tid >> 5;
    const float dtar = cst_lds[0 * 32 + n], dtai = cst_lds[1 * 32 + n];
    const float dAr = cst_lds[2 * 32 + n], dAi = cst_lds[3 * 32 + n];
    const float dbr = cst_lds[4 * 32 + n], dbi = cst_lds[5 * 32 + n];
    const float tcr = cst_lds[6 * 32 + n], tci = cst_lds[7 * 32 + n];

    {
        float p = (float)(56 - q * 8);
        float mr = expf(p * dtar);
        float s, c; sincosf(p * dtai, &s, &c);
        float pr = mr * c, pi = mr * s;
        unsigned* base = A3t + (size_t)h * 4096;
#pragma unroll
        for (int jj = 7; jj >= 0; jj--) {
            int m = q * 8 + jj;
            base[m * 64 + n]      = packhl(dbr * pr - dbi * pi);
            base[m * 64 + 32 + n] = packhl(dbr * pi + dbi * pr);
            float nr2 = pr * dAr - pi * dAi;
            pi = pr * dAi + pi * dAr;
            pr = nr2;
        }
    }
    {
        float p = (float)(q * 8 + 1);
        float mr = expf(p * dtar);
        float s, c; sincosf(p * dtai, &s, &c);
        float pr = mr * c, pi = mr * s;
        unsigned* base = Et + (size_t)h * 4096;
#pragma unroll
        for (int i = q * 8; i <= q * 8 + 7; i++) {
            base[i * 64 + n]      = packhl(tcr * pr - tci * pi);
            base[i * 64 + 32 + n] = packhl(-(tcr * pi + tci * pr));
            float nr2 = pr * dAr - pi * dAi;
            pi = pr * dAi + pi * dAr;
            pr = nr2;
        }
    }
}

// ---------------- Kernel B: SSM conv via MFMA chunked scan + D skip + GELU ----------------
__global__ __launch_bounds__(256, 4) void ssm_kernel(
    const float* __restrict__ u, const float* __restrict__ log_dt,
    const float* __restrict__ A_re, const float* __restrict__ A_im,
    const float* __restrict__ B_re, const float* __restrict__ B_im,
    const float* __restrict__ C_re, const float* __restrict__ C_im,
    const float* __restrict__ D,
    const unsigned* __restrict__ A3t, const unsigned* __restrict__ Et,
    unsigned short* __restrict__ yhi) {
    const int h = blockIdx.x;
    const int b = blockIdx.y;
    const int tid = threadIdx.x;
    const int lane = tid & 63;
    const int w = tid >> 6;
    const int g = lane >> 4;
    const int l15 = lane & 15;

    __shared__ unsigned short uh[64 * 72];
    __shared__ unsigned short ul[64 * 72];
    __shared__ unsigned XsR[32 * 65];
    __shared__ unsigned XsI[32 * 65];
    __shared__ unsigned karr_pk[128];
    __shared__ float kpart[256];
    __shared__ float cst_lds[256];

    {
        const float* urow = u + ((size_t)(b * HH + h)) * LL;
#pragma unroll
        for (int r = 0; r < 4; r++) {
            int f = tid + 256 * r;
            float4 v = *(const float4*)(urow + f * 4);
            int t = f >> 4, mb = (f & 15) << 2;
            unsigned hx = f2bf(v.x), hy = f2bf(v.y), hz = f2bf(v.z), hw = f2bf(v.w);
            uint2 hwv;
            hwv.x = hx | (hy << 16);
            hwv.y = hz | (hw << 16);
            float rx = v.x - __uint_as_float(hx << 16);
            float ry = v.y - __uint_as_float(hy << 16);
            float rz = v.z - __uint_as_float(hz << 16);
            float rw = v.w - __uint_as_float(hw << 16);
            uint2 lwv;
            lwv.x = f2bf(rx) | (f2bf(ry) << 16);
            lwv.y = f2bf(rz) | (f2bf(rw) << 16);
            *(uint2*)(&uh[t * 72 + mb]) = hwv;
            *(uint2*)(&ul[t * 72 + mb]) = lwv;
        }
    }
    if (tid < 32) {
        int n = tid;
        float dt = expf(log_dt[h]);
        float ar = A_re[h * NN + n], ai = A_im[h * NN + n];
        float dtar = dt * ar, dtai = dt * ai;
        float ea = expf(dtar);
        float s, c; sincosf(dtai, &s, &c);
        float dA_r = ea * c, dA_i = ea * s;
        float em_r = dA_r - 1.0f, em_i = dA_i;
        float inv = 1.0f / (ar * ar + ai * ai);
        float t_r = (em_r * ar + em_i * ai) * inv;
        float t_i = (em_i * ar - em_r * ai) * inv;
        float br = B_re[h * NN + n], bi = B_im[h * NN + n];
        cst_lds[0 * 32 + n] = dtar;
        cst_lds[1 * 32 + n] = dtai;
        cst_lds[2 * 32 + n] = dA_r;
        cst_lds[3 * 32 + n] = dA_i;
        cst_lds[4 * 32 + n] = t_r * br - t_i * bi;
        cst_lds[5 * 32 + n] = t_r * bi + t_i * br;
        cst_lds[6 * 32 + n] = 2.0f * C_re[h * NN + n];
        cst_lds[7 * 32 + n] = 2.0f * C_im[h * NN + n];
    }
    __syncthreads();   // S0

    {
        int nprime = w * 16 + l15;
        const unsigned* a3b = A3t + (size_t)h * 4096 + nprime;
        short8 a3h0, a3l0, a3h1, a3l1;
#pragma unroll
        for (int j = 0; j < 8; j++) {
            unsigned v = a3b[(g * 8 + j) * 64];
            a3h0[j] = (short)(v >> 16); a3l0[j] = (short)(v & 0xffffu);
            unsigned v2 = a3b[(32 + g * 8 + j) * 64];
            a3h1[j] = (short)(v2 >> 16); a3l1[j] = (short)(v2 & 0xffffu);
        }
#pragma unroll
        for (int ni = 0; ni < 4; ni++) {
            int t = ni * 16 + l15;
            short8 uH0 = *(const short8*)(uh + t * 72 + g * 8);
            short8 uL0 = *(const short8*)(ul + t * 72 + g * 8);
            short8 uH1 = *(const short8*)(uh + t * 72 + 32 + g * 8);
            short8 uL1 = *(const short8*)(ul + t * 72 + 32 + g * 8);
            f32x4 a = (f32x4){0.f, 0.f, 0.f, 0.f};
            a = __builtin_amdgcn_mfma_f32_16x16x32_bf16(a3h0, uH0, a, 0, 0, 0);
            a = __builtin_amdgcn_mfma_f32_16x16x32_bf16(a3l0, uH0, a, 0, 0, 0);
            a = __builtin_amdgcn_mfma_f32_16x16x32_bf16(a3h0, uL0, a, 0, 0, 0);
            a = __builtin_amdgcn_mfma_f32_16x16x32_bf16(a3h1, uH1, a, 0, 0, 0);
            a = __builtin_amdgcn_mfma_f32_16x16x32_bf16(a3l1, uH1, a, 0, 0, 0);
            a = __builtin_amdgcn_mfma_f32_16x16x32_bf16(a3h1, uL1, a, 0, 0, 0);
            int nprime2 = w * 16 + g * 4;
#pragma unroll
            for (int r = 0; r < 4; r++) {
                int nn2 = nprime2 + r;
                if (nn2 < 32) XsR[nn2 * 65 + t] = __float_as_uint(a[r]);
                else          XsI[(nn2 - 32) * 65 + t] = __float_as_uint(a[r]);
            }
        }
    }
    {
        int j = tid & 63, nr = tid >> 6;
        float acc = 0.0f;
        if (j == 0) {
#pragma unroll
            for (int q = 0; q < 8; q++) {
                int n = nr * 8 + q;
                acc = fmaf(cst_lds[6 * 32 + n], cst_lds[4 * 32 + n], acc);
                acc = fmaf(-cst_lds[7 * 32 + n], cst_lds[5 * 32 + n], acc);
            }
        } else {
            const unsigned* eb = Et + (size_t)h * 4096 + (j - 1) * 64;
#pragma unroll
            for (int q = 0; q < 8; q++) {
                int n = nr * 8 + q;
                acc = fmaf(reconhl(eb[n]), cst_lds[4 * 32 + n], acc);
                acc = fmaf(reconhl(eb[32 + n]), cst_lds[5 * 32 + n], acc);
            }
        }
        kpart[nr * 64 + j] = acc;
    }
    __syncthreads();   // S1

    if (tid < 32) {
        int n = tid;
        float dtar = cst_lds[0 * 32 + n], dtai = cst_lds[1 * 32 + n];
        float mr = expf(64.0f * dtar);
        float s, c; sincosf(64.0f * dtai, &s, &c);
        float Mr = mr * c, Mi = mr * s;
        float cr = 0.f, ci = 0.f;
        unsigned* pR = XsR + n * 65;
        unsigned* pI = XsI + n * 65;
        float fr = __uint_as_float(pR[0]);
        float fi2 = __uint_as_float(pI[0]);
#pragma unroll 4
        for (int t = 0; t < 64; t++) {
            float frn = 0.f, fin = 0.f;
            if (t < 63) { frn = __uint_as_float(pR[t + 1]); fin = __uint_as_float(pI[t + 1]); }
            pR[t] = packhl(cr);
            pI[t] = packhl(ci);
            float nr = fmaf(Mr, cr, fmaf(-Mi, ci, fr));
            float nic = fmaf(Mr, ci, fmaf(Mi, cr, fi2));
            cr = nr; ci = nic;
            fr = frn; fi2 = fin;
        }
    } else if (tid >= 64 && tid < 128) {
        int j = tid - 64;
        float k = kpart[j] + kpart[64 + j] + kpart[128 + j] + kpart[192 + j];
        karr_pk[64 + j] = packhl(k);
    } else if (tid >= 128 && tid < 192) {
        karr_pk[tid - 128] = 0u;
    }
    __syncthreads();   // S2

    {
        int i = w * 16 + l15;
        short8 kh0, kl0, kh1, kl1;
#pragma unroll
        for (int j = 0; j < 8; j++) {
            unsigned v0 = karr_pk[64 + i - (g * 8 + j)];
            kh0[j] = (short)(v0 >> 16); kl0[j] = (short)(v0 & 0xffffu);
            unsigned v1 = karr_pk[64 + i - (32 + g * 8 + j)];
            kh1[j] = (short)(v1 >> 16); kl1[j] = (short)(v1 & 0xffffu);
        }
        short8 e0h, e0l, e1h, e1l;
        {
            const unsigned* eb = Et + (size_t)h * 4096 + i * 64;
#pragma unroll
            for (int j = 0; j < 8; j++) {
                int n = g * 8 + j;
                unsigned v = eb[n];
                e0h[j] = (short)(v >> 16); e0l[j] = (short)(v & 0xffffu);
                unsigned v2 = eb[32 + n];
                e1h[j] = (short)(v2 >> 16); e1l[j] = (short)(v2 & 0xffffu);
            }
        }
        float Dh = D[h];
        unsigned short* orow = yhi + ((size_t)(b * HH + h)) * LL;
#pragma unroll
        for (int ni = 0; ni < 4; ni++) {
            int t = ni * 16 + l15;
            short8 uH0 = *(const short8*)(uh + t * 72 + g * 8);
            short8 uL0 = *(const short8*)(ul + t * 72 + g * 8);
            short8 uH1 = *(const short8*)(uh + t * 72 + 32 + g * 8);
            short8 uL1 = *(const short8*)(ul + t * 72 + 32 + g * 8);
            short8 xrh, xrl, xih, xil;
#pragma unroll
            for (int j = 0; j < 8; j++) {
                unsigned v = XsR[(g * 8 + j) * 65 + t];
                xrh[j] = (short)(v >> 16); xrl[j] = (short)(v & 0xffffu);
                unsigned v2 = XsI[(g * 8 + j) * 65 + t];
                xih[j] = (short)(v2 >> 16); xil[j] = (short)(v2 & 0xffffu);
            }
            f32x4 a = (f32x4){0.f, 0.f, 0.f, 0.f};
            a = __builtin_amdgcn_mfma_f32_16x16x32_bf16(kh0, uH0, a, 0, 0, 0);
            a = __builtin_amdgcn_mfma_f32_16x16x32_bf16(kl0, uH0, a, 0, 0, 0);
            a = __builtin_amdgcn_mfma_f32_16x16x32_bf16(kh0, uL0, a, 0, 0, 0);
            a = __builtin_amdgcn_mfma_f32_16x16x32_bf16(kh1, uH1, a, 0, 0, 0);
            a = __builtin_amdgcn_mfma_f32_16x16x32_bf16(kl1, uH1, a, 0, 0, 0);
            a = __builtin_amdgcn_mfma_f32_16x16x32_bf16(kh1, uL1, a, 0, 0, 0);
            a = __builtin_amdgcn_mfma_f32_16x16x32_bf16(e0h, xrh, a, 0, 0, 0);
            a = __builtin_amdgcn_mfma_f32_16x16x32_bf16(e0h, xrl, a, 0, 0, 0);
            a = __builtin_amdgcn_mfma_f32_16x16x32_bf16(e0l, xrh, a, 0, 0, 0);
            a = __builtin_amdgcn_mfma_f32_16x16x32_bf16(e1h, xih, a, 0, 0, 0);
            a = __builtin_amdgcn_mfma_f32_16x16x32_bf16(e1h, xil, a, 0, 0, 0);
            a = __builtin_amdgcn_mfma_f32_16x16x32_bf16(e1l, xih, a, 0, 0, 0);
            ushort4 ov;
            unsigned short* op = &ov.x;
#pragma unroll
            for (int r = 0; r < 4; r++) {
                int io = w * 16 + g * 4 + r;
                float uv = __uint_as_float(((unsigned)uh[t * 72 + io]) << 16)
                         + __uint_as_float(((unsigned)ul[t * 72 + io]) << 16);
                float y = a[r] + Dh * uv;
                float gl = 0.5f * y * (1.0f + erff(y * 0.70710678118654752f));
                op[r] = (unsigned short)f2bf(gl);
            }
            *(ushort4*)(&orow[t * 64 + w * 16 + g * 4]) = ov;
        }
    }
}

// ---------------- Kernel C: MFMA bf16 GEMM 64x64 tiles + bias + GLU ----------------
// grid = dim3(64 l-tiles, 8 d-tiles, B); 2048 blocks -> 8 blocks/CU for latency hiding.
__global__ __launch_bounds__(256) void gemm_glu_mfma(const unsigned short* __restrict__ yhi,
                                                     const float* __restrict__ W,
                                                     const unsigned short* __restrict__ whi,
                                                     const float* __restrict__ bias,
                                                     float* __restrict__ out, int preW) {
    const int b = blockIdx.z;
    const int d0 = blockIdx.y * 64;
    const int l0 = blockIdx.x * 64;
    const int tid = threadIdx.x;
    const int lane = tid & 63;
    const int wid = tid >> 6;
    const int wave_m = wid & 1;
    const int wave_n = wid >> 1;
    const int l15 = lane & 15;
    const int g = lane >> 4;

    __shared__ unsigned short Ysh[32 * 64];   // 4 KB, col-xor-8 swizzle by row-bit3
    __shared__ char Wlds[128 * 64];           // 8 KB bf16-hi, group-xor-swizzled

    f32x4 acc[4][2];
#pragma unroll
    for (int i = 0; i < 4; i++)
#pragma unroll
        for (int j = 0; j < 2; j++) acc[i][j] = (f32x4){0.f, 0.f, 0.f, 0.f};

    for (int kt = 0; kt < 16; kt++) {
        const int h0 = kt * 32;
        __syncthreads();
        // stage Y tile [32 k][64 l] ushort: 256 16B chunks, one per thread
        {
            int kr = tid >> 3;                // row 0..31
            int cc = tid & 7;                 // 16B chunk in row (8 ushorts)
            int scol = (cc * 8) ^ ((kr & 8) ? 8 : 0);
            const unsigned short* src = yhi + ((size_t)(b * HH + h0 + kr)) * LL + l0 + scol;
            gload_lds16(src, (char*)Ysh + tid * 16);
        }
        if (preW) {
#pragma unroll
            for (int e = 0; e < 2; e++) {
                int c = e * 256 + tid;
                int row = c >> 2;
                int gx = c & 3;
                int qq = (row >> 1) & 3;
                int grow = (row < 64) ? (d0 + row) : (448 + d0 + row);
                const unsigned short* src = whi + (size_t)grow * 512 + h0 + ((gx ^ qq) * 8);
                gload_lds16(src, Wlds + c * 16);
            }
        } else {
            int row = tid >> 1;
            int kb = (tid & 1) * 16;
            int qq = (row >> 1) & 3;
            int grow = (row < 64) ? (d0 + row) : (448 + d0 + row);
            const float* src = W + (size_t)grow * 512 + h0 + kb;
            float4 w0 = *(const float4*)(src);
            float4 w1 = *(const float4*)(src + 4);
            float4 w2 = *(const float4*)(src + 8);
            float4 w3 = *(const float4*)(src + 12);
            short8 v0, v1;
            v0[0] = (short)f2bf(w0.x); v0[1] = (short)f2bf(w0.y);
            v0[2] = (short)f2bf(w0.z); v0[3] = (short)f2bf(w0.w);
            v0[4] = (short)f2bf(w1.x); v0[5] = (short)f2bf(w1.y);
            v0[6] = (short)f2bf(w1.z); v0[7] = (short)f2bf(w1.w);
            v1[0] = (short)f2bf(w2.x); v1[1] = (short)f2bf(w2.y);
            v1[2] = (short)f2bf(w2.z); v1[3] = (short)f2bf(w2.w);
            v1[4] = (short)f2bf(w3.x); v1[5] = (short)f2bf(w3.y);
            v1[6] = (short)f2bf(w3.z); v1[7] = (short)f2bf(w3.w);
            int g0 = kb >> 3;
            *(short8*)(Wlds + row * 64 + ((g0 ^ qq) * 16)) = v0;
            *(short8*)(Wlds + row * 64 + (((g0 + 1) ^ qq) * 16)) = v1;
        }
        __syncthreads();

        short8 af[4];
#pragma unroll
        for (int mi = 0; mi < 4; mi++) {
            int rowb = (mi < 2) ? (wave_m * 32 + mi * 16) : (64 + wave_m * 32 + (mi - 2) * 16);
            int row = rowb + l15;
            int qq = (row >> 1) & 3;
            af[mi] = *(const short8*)(Wlds + row * 64 + ((g ^ qq) * 16));
        }
#pragma unroll
        for (int ni = 0; ni < 2; ni++) {
            int col = wave_n * 32 + ni * 16 + l15;
            int cs = col ^ ((g & 1) << 3);
            const unsigned short* yb = Ysh + (8 * g) * 64 + cs;
            short8 bh;
            bh[0] = (short)yb[0 * 64];
            bh[1] = (short)yb[1 * 64];
            bh[2] = (short)yb[2 * 64];
            bh[3] = (short)yb[3 * 64];
            bh[4] = (short)yb[4 * 64];
            bh[5] = (short)yb[5 * 64];
            bh[6] = (short)yb[6 * 64];
            bh[7] = (short)yb[7 * 64];
#pragma unroll
            for (int mi = 0; mi < 4; mi++) {
                acc[mi][ni] = __builtin_amdgcn_mfma_f32_16x16x32_bf16(af[mi], bh, acc[mi][ni], 0, 0, 0);
            }
        }
    }

#pragma unroll
    for (int mi = 0; mi < 2; mi++) {
        int dbase = d0 + wave_m * 32 + mi * 16 + (g << 2);
#pragma unroll
        for (int r = 0; r < 4; r++) {
            int d = dbase + r;
            float b1 = bias[d], b2 = bias[DMOUT + d];
#pragma unroll
            for (int ni = 0; ni < 2; ni++) {
                int l = l0 + wave_n * 32 + ni * 16 + l15;
                float z1 = acc[mi][ni][r] + b1;
                float z2 = acc[mi + 2][ni][r] + b2;
                out[((size_t)(b * DMOUT + d)) * LL + l] = z1 * (1.0f / (1.0f + expf(-z2)));
            }
        }
    }
}

extern "C" void kernel_launch(void* const* d_in, const int* in_sizes, int n_in,
                              void* d_out, int out_size, void* d_ws, size_t ws_size,
                              hipStream_t stream) {
    const float* u      = (const float*)d_in[0];
    const float* log_dt = (const float*)d_in[1];
    const float* A_re   = (const float*)d_in[2];
    const float* A_im   = (const float*)d_in[3];
    const float* B_re   = (const float*)d_in[4];
    const float* B_im   = (const float*)d_in[5];
    const float* C_re   = (const float*)d_in[6];
    const float* C_im   = (const float*)d_in[7];
    const float* D      = (const float*)d_in[8];
    const float* W      = (const float*)d_in[9];
    const float* bias   = (const float*)d_in[10];
    float* out = (float*)d_out;

    char* ws = (char*)d_ws;
    unsigned short* yhi = (unsigned short*)ws;                     // 16,777,216 B
    unsigned* A3t = (unsigned*)(ws + 16777216);                    //  8,388,608 B
    unsigned* Et  = (unsigned*)(ws + 16777216 + 8388608);          //  8,388,608 B
    unsigned short* whi = (unsigned short*)(ws + 33554432);        //  1,048,576 B (total 34.6 MB)
    int preW = (ws_size >= (size_t)(33554432 + 1048576)) ? 1 : 0;

    if (preW) wsplit_kernel<<<512, 256, 0, stream>>>(W, whi);
    prep_kernel<<<HH, 256, 0, stream>>>(log_dt, A_re, A_im, B_re, B_im, C_re, C_im, A3t, Et);
    ssm_kernel<<<dim3(HH, BB), 256, 0, stream>>>(u, log_dt, A_re, A_im, B_re, B_im,
                                                 C_re, C_im, D, A3t, Et, yhi);
    gemm_glu_mfma<<<dim3(64, 8, BB), 256, 0, stream>>>(yhi, W, whi, bias, out, preW);
}

// Round 18
// 88.530 us; speedup vs baseline: 5.0351x; 1.0428x over previous
//
#include <hip/hip_runtime.h>
#include <math.h>

#define BB 4
#define HH 512
#define LL 4096
#define NN 32
#define DMOUT 512

typedef __attribute__((ext_vector_type(8))) short short8;
typedef __attribute__((ext_vector_type(4))) float f32x4;

__device__ __forceinline__ unsigned f2bf(float x) {
    unsigned u = __float_as_uint(x);
    return (u + 0x7fffu + ((u >> 16) & 1u)) >> 16;
}
__device__ __forceinline__ unsigned packhl(float x) {
    unsigned hb = f2bf(x);
    float xh = __uint_as_float(hb << 16);
    return (hb << 16) | f2bf(x - xh);
}
__device__ __forceinline__ float reconhl(unsigned v) {
    return __uint_as_float(v & 0xffff0000u) + __uint_as_float(v << 16);
}
__device__ __forceinline__ void gload_lds16(const void* g, void* l) {
    __builtin_amdgcn_global_load_lds((const __attribute__((address_space(1))) void*)g,
                                     (__attribute__((address_space(3))) void*)l, 16, 0, 0);
}

// ---------------- Kernel P: per-h tables (A3t, Et) + W->bf16 (fused wsplit) ----------------
__global__ __launch_bounds__(256) void prep_kernel(
    const float* __restrict__ log_dt,
    const float* __restrict__ A_re, const float* __restrict__ A_im,
    const float* __restrict__ B_re, const float* __restrict__ B_im,
    const float* __restrict__ C_re, const float* __restrict__ C_im,
    const float* __restrict__ W,
    unsigned* __restrict__ A3t, unsigned* __restrict__ Et,
    unsigned short* __restrict__ whi, int preW) {
    const int h = blockIdx.x;
    const int tid = threadIdx.x;
    __shared__ float cst_lds[256];

    // fused W split (independent work, same grid as old wsplit)
    if (preW) {
        int i = (h * 256 + tid) * 4;
        float4 wv = *(const float4*)(W + i);
        ushort4 o;
        o.x = (unsigned short)f2bf(wv.x);
        o.y = (unsigned short)f2bf(wv.y);
        o.z = (unsigned short)f2bf(wv.z);
        o.w = (unsigned short)f2bf(wv.w);
        *(ushort4*)(whi + i) = o;
    }

    if (tid < 32) {
        int n = tid;
        float dt = expf(log_dt[h]);
        float ar = A_re[h * NN + n], ai = A_im[h * NN + n];
        float dtar = dt * ar, dtai = dt * ai;
        float ea = expf(dtar);
        float s, c; sincosf(dtai, &s, &c);
        float dA_r = ea * c, dA_i = ea * s;
        float em_r = dA_r - 1.0f, em_i = dA_i;
        float inv = 1.0f / (ar * ar + ai * ai);
        float t_r = (em_r * ar + em_i * ai) * inv;
        float t_i = (em_i * ar - em_r * ai) * inv;
        float br = B_re[h * NN + n], bi = B_im[h * NN + n];
        cst_lds[0 * 32 + n] = dtar;
        cst_lds[1 * 32 + n] = dtai;
        cst_lds[2 * 32 + n] = dA_r;
        cst_lds[3 * 32 + n] = dA_i;
        cst_lds[4 * 32 + n] = t_r * br - t_i * bi;
        cst_lds[5 * 32 + n] = t_r * bi + t_i * br;
        cst_lds[6 * 32 + n] = 2.0f * C_re[h * NN + n];
        cst_lds[7 * 32 + n] = 2.0f * C_im[h * NN + n];
    }
    __syncthreads();

    const int n = tid & 31, q = tid >> 5;
    const float dtar = cst_lds[0 * 32 + n], dtai = cst_lds[1 * 32 + n];
    const float dAr = cst_lds[2 * 32 + n], dAi = cst_lds[3 * 32 + n];
    const float dbr = cst_lds[4 * 32 + n], dbi = cst_lds[5 * 32 + n];
    const float tcr = cst_lds[6 * 32 + n], tci = cst_lds[7 * 32 + n];

    {
        float p = (float)(56 - q * 8);
        float mr = expf(p * dtar);
        float s, c; sincosf(p * dtai, &s, &c);
        float pr = mr * c, pi = mr * s;
        unsigned* base = A3t + (size_t)h * 4096;
#pragma unroll
        for (int jj = 7; jj >= 0; jj--) {
            int m = q * 8 + jj;
            base[m * 64 + n]      = packhl(dbr * pr - dbi * pi);
            base[m * 64 + 32 + n] = packhl(dbr * pi + dbi * pr);
            float nr2 = pr * dAr - pi * dAi;
            pi = pr * dAi + pi * dAr;
            pr = nr2;
        }
    }
    {
        float p = (float)(q * 8 + 1);
        float mr = expf(p * dtar);
        float s, c; sincosf(p * dtai, &s, &c);
        float pr = mr * c, pi = mr * s;
        unsigned* base = Et + (size_t)h * 4096;
#pragma unroll
        for (int i = q * 8; i <= q * 8 + 7; i++) {
            base[i * 64 + n]      = packhl(tcr * pr - tci * pi);
            base[i * 64 + 32 + n] = packhl(-(tcr * pi + tci * pr));
            float nr2 = pr * dAr - pi * dAi;
            pi = pr * dAi + pi * dAr;
            pr = nr2;
        }
    }
}

// ---------------- Kernel B: SSM conv via MFMA chunked scan + D skip + GELU ----------------
__global__ __launch_bounds__(256, 4) void ssm_kernel(
    const float* __restrict__ u, const float* __restrict__ log_dt,
    const float* __restrict__ A_re, const float* __restrict__ A_im,
    const float* __restrict__ B_re, const float* __restrict__ B_im,
    const float* __restrict__ C_re, const float* __restrict__ C_im,
    const float* __restrict__ D,
    const unsigned* __restrict__ A3t, const unsigned* __restrict__ Et,
    unsigned short* __restrict__ yhi) {
    const int h = blockIdx.x;
    const int b = blockIdx.y;
    const int tid = threadIdx.x;
    const int lane = tid & 63;
    const int w = tid >> 6;
    const int g = lane >> 4;
    const int l15 = lane & 15;

    __shared__ unsigned short uh[64 * 72];
    __shared__ unsigned short ul[64 * 72];
    __shared__ unsigned XsR[32 * 65];
    __shared__ unsigned XsI[32 * 65];
    __shared__ unsigned karr_pk[128];
    __shared__ float kpart[256];
    __shared__ float cst_lds[256];

    {
        const float* urow = u + ((size_t)(b * HH + h)) * LL;
#pragma unroll
        for (int r = 0; r < 4; r++) {
            int f = tid + 256 * r;
            float4 v = *(const float4*)(urow + f * 4);
            int t = f >> 4, mb = (f & 15) << 2;
            unsigned hx = f2bf(v.x), hy = f2bf(v.y), hz = f2bf(v.z), hw = f2bf(v.w);
            uint2 hwv;
            hwv.x = hx | (hy << 16);
            hwv.y = hz | (hw << 16);
            float rx = v.x - __uint_as_float(hx << 16);
            float ry = v.y - __uint_as_float(hy << 16);
            float rz = v.z - __uint_as_float(hz << 16);
            float rw = v.w - __uint_as_float(hw << 16);
            uint2 lwv;
            lwv.x = f2bf(rx) | (f2bf(ry) << 16);
            lwv.y = f2bf(rz) | (f2bf(rw) << 16);
            *(uint2*)(&uh[t * 72 + mb]) = hwv;
            *(uint2*)(&ul[t * 72 + mb]) = lwv;
        }
    }
    if (tid < 32) {
        int n = tid;
        float dt = expf(log_dt[h]);
        float ar = A_re[h * NN + n], ai = A_im[h * NN + n];
        float dtar = dt * ar, dtai = dt * ai;
        float ea = expf(dtar);
        float s, c; sincosf(dtai, &s, &c);
        float dA_r = ea * c, dA_i = ea * s;
        float em_r = dA_r - 1.0f, em_i = dA_i;
        float inv = 1.0f / (ar * ar + ai * ai);
        float t_r = (em_r * ar + em_i * ai) * inv;
        float t_i = (em_i * ar - em_r * ai) * inv;
        float br = B_re[h * NN + n], bi = B_im[h * NN + n];
        cst_lds[0 * 32 + n] = dtar;
        cst_lds[1 * 32 + n] = dtai;
        cst_lds[2 * 32 + n] = dA_r;
        cst_lds[3 * 32 + n] = dA_i;
        cst_lds[4 * 32 + n] = t_r * br - t_i * bi;
        cst_lds[5 * 32 + n] = t_r * bi + t_i * br;
        cst_lds[6 * 32 + n] = 2.0f * C_re[h * NN + n];
        cst_lds[7 * 32 + n] = 2.0f * C_im[h * NN + n];
    }
    __syncthreads();   // S0

    {
        int nprime = w * 16 + l15;
        const unsigned* a3b = A3t + (size_t)h * 4096 + nprime;
        short8 a3h0, a3l0, a3h1, a3l1;
#pragma unroll
        for (int j = 0; j < 8; j++) {
            unsigned v = a3b[(g * 8 + j) * 64];
            a3h0[j] = (short)(v >> 16); a3l0[j] = (short)(v & 0xffffu);
            unsigned v2 = a3b[(32 + g * 8 + j) * 64];
            a3h1[j] = (short)(v2 >> 16); a3l1[j] = (short)(v2 & 0xffffu);
        }
#pragma unroll
        for (int ni = 0; ni < 4; ni++) {
            int t = ni * 16 + l15;
            short8 uH0 = *(const short8*)(uh + t * 72 + g * 8);
            short8 uL0 = *(const short8*)(ul + t * 72 + g * 8);
            short8 uH1 = *(const short8*)(uh + t * 72 + 32 + g * 8);
            short8 uL1 = *(const short8*)(ul + t * 72 + 32 + g * 8);
            f32x4 a = (f32x4){0.f, 0.f, 0.f, 0.f};
            a = __builtin_amdgcn_mfma_f32_16x16x32_bf16(a3h0, uH0, a, 0, 0, 0);
            a = __builtin_amdgcn_mfma_f32_16x16x32_bf16(a3l0, uH0, a, 0, 0, 0);
            a = __builtin_amdgcn_mfma_f32_16x16x32_bf16(a3h0, uL0, a, 0, 0, 0);
            a = __builtin_amdgcn_mfma_f32_16x16x32_bf16(a3h1, uH1, a, 0, 0, 0);
            a = __builtin_amdgcn_mfma_f32_16x16x32_bf16(a3l1, uH1, a, 0, 0, 0);
            a = __builtin_amdgcn_mfma_f32_16x16x32_bf16(a3h1, uL1, a, 0, 0, 0);
            int nprime2 = w * 16 + g * 4;
#pragma unroll
            for (int r = 0; r < 4; r++) {
                int nn2 = nprime2 + r;
                if (nn2 < 32) XsR[nn2 * 65 + t] = __float_as_uint(a[r]);
                else          XsI[(nn2 - 32) * 65 + t] = __float_as_uint(a[r]);
            }
        }
    }
    {
        int j = tid & 63, nr = tid >> 6;
        float acc = 0.0f;
        if (j == 0) {
#pragma unroll
            for (int q = 0; q < 8; q++) {
                int n = nr * 8 + q;
                acc = fmaf(cst_lds[6 * 32 + n], cst_lds[4 * 32 + n], acc);
                acc = fmaf(-cst_lds[7 * 32 + n], cst_lds[5 * 32 + n], acc);
            }
        } else {
            const unsigned* eb = Et + (size_t)h * 4096 + (j - 1) * 64;
#pragma unroll
            for (int q = 0; q < 8; q++) {
                int n = nr * 8 + q;
                acc = fmaf(reconhl(eb[n]), cst_lds[4 * 32 + n], acc);
                acc = fmaf(reconhl(eb[32 + n]), cst_lds[5 * 32 + n], acc);
            }
        }
        kpart[nr * 64 + j] = acc;
    }
    // ---- E-frags hoisted BEFORE S1: pure global (Et) loads, latency hides under scan
    short8 e0h, e0l, e1h, e1l;
    {
        int i = w * 16 + l15;
        const unsigned* eb = Et + (size_t)h * 4096 + i * 64;
#pragma unroll
        for (int j = 0; j < 8; j++) {
            int n = g * 8 + j;
            unsigned v = eb[n];
            e0h[j] = (short)(v >> 16); e0l[j] = (short)(v & 0xffffu);
            unsigned v2 = eb[32 + n];
            e1h[j] = (short)(v2 >> 16); e1l[j] = (short)(v2 & 0xffffu);
        }
    }
    __syncthreads();   // S1

    if (tid < 32) {
        int n = tid;
        float dtar = cst_lds[0 * 32 + n], dtai = cst_lds[1 * 32 + n];
        float mr = expf(64.0f * dtar);
        float s, c; sincosf(64.0f * dtai, &s, &c);
        float Mr = mr * c, Mi = mr * s;
        float cr = 0.f, ci = 0.f;
        unsigned* pR = XsR + n * 65;
        unsigned* pI = XsI + n * 65;
        float fr = __uint_as_float(pR[0]);
        float fi2 = __uint_as_float(pI[0]);
#pragma unroll 4
        for (int t = 0; t < 64; t++) {
            float frn = 0.f, fin = 0.f;
            if (t < 63) { frn = __uint_as_float(pR[t + 1]); fin = __uint_as_float(pI[t + 1]); }
            pR[t] = packhl(cr);
            pI[t] = packhl(ci);
            float nr = fmaf(Mr, cr, fmaf(-Mi, ci, fr));
            float nic = fmaf(Mr, ci, fmaf(Mi, cr, fi2));
            cr = nr; ci = nic;
            fr = frn; fi2 = fin;
        }
    } else if (tid >= 64 && tid < 128) {
        int j = tid - 64;
        float k = kpart[j] + kpart[64 + j] + kpart[128 + j] + kpart[192 + j];
        karr_pk[64 + j] = packhl(k);
    } else if (tid >= 128 && tid < 192) {
        karr_pk[tid - 128] = 0u;
    }
    __syncthreads();   // S2

    {
        int i = w * 16 + l15;
        short8 kh0, kl0, kh1, kl1;
#pragma unroll
        for (int j = 0; j < 8; j++) {
            unsigned v0 = karr_pk[64 + i - (g * 8 + j)];
            kh0[j] = (short)(v0 >> 16); kl0[j] = (short)(v0 & 0xffffu);
            unsigned v1 = karr_pk[64 + i - (32 + g * 8 + j)];
            kh1[j] = (short)(v1 >> 16); kl1[j] = (short)(v1 & 0xffffu);
        }
        float Dh = D[h];
        unsigned short* orow = yhi + ((size_t)(b * HH + h)) * LL;
#pragma unroll
        for (int ni = 0; ni < 4; ni++) {
            int t = ni * 16 + l15;
            short8 uH0 = *(const short8*)(uh + t * 72 + g * 8);
            short8 uL0 = *(const short8*)(ul + t * 72 + g * 8);
            short8 uH1 = *(const short8*)(uh + t * 72 + 32 + g * 8);
            short8 uL1 = *(const short8*)(ul + t * 72 + 32 + g * 8);
            short8 xrh, xrl, xih, xil;
#pragma unroll
            for (int j = 0; j < 8; j++) {
                unsigned v = XsR[(g * 8 + j) * 65 + t];
                xrh[j] = (short)(v >> 16); xrl[j] = (short)(v & 0xffffu);
                unsigned v2 = XsI[(g * 8 + j) * 65 + t];
                xih[j] = (short)(v2 >> 16); xil[j] = (short)(v2 & 0xffffu);
            }
            f32x4 a = (f32x4){0.f, 0.f, 0.f, 0.f};
            a = __builtin_amdgcn_mfma_f32_16x16x32_bf16(kh0, uH0, a, 0, 0, 0);
            a = __builtin_amdgcn_mfma_f32_16x16x32_bf16(kl0, uH0, a, 0, 0, 0);
            a = __builtin_amdgcn_mfma_f32_16x16x32_bf16(kh0, uL0, a, 0, 0, 0);
            a = __builtin_amdgcn_mfma_f32_16x16x32_bf16(kh1, uH1, a, 0, 0, 0);
            a = __builtin_amdgcn_mfma_f32_16x16x32_bf16(kl1, uH1, a, 0, 0, 0);
            a = __builtin_amdgcn_mfma_f32_16x16x32_bf16(kh1, uL1, a, 0, 0, 0);
            a = __builtin_amdgcn_mfma_f32_16x16x32_bf16(e0h, xrh, a, 0, 0, 0);
            a = __builtin_amdgcn_mfma_f32_16x16x32_bf16(e0h, xrl, a, 0, 0, 0);
            a = __builtin_amdgcn_mfma_f32_16x16x32_bf16(e0l, xrh, a, 0, 0, 0);
            a = __builtin_amdgcn_mfma_f32_16x16x32_bf16(e1h, xih, a, 0, 0, 0);
            a = __builtin_amdgcn_mfma_f32_16x16x32_bf16(e1h, xil, a, 0, 0, 0);
            a = __builtin_amdgcn_mfma_f32_16x16x32_bf16(e1l, xih, a, 0, 0, 0);
            ushort4 ov;
            unsigned short* op = &ov.x;
#pragma unroll
            for (int r = 0; r < 4; r++) {
                int io = w * 16 + g * 4 + r;
                float uv = __uint_as_float(((unsigned)uh[t * 72 + io]) << 16)
                         + __uint_as_float(((unsigned)ul[t * 72 + io]) << 16);
                float y = a[r] + Dh * uv;
                float gl = 0.5f * y * (1.0f + erff(y * 0.70710678118654752f));
                op[r] = (unsigned short)f2bf(gl);
            }
            *(ushort4*)(&orow[t * 64 + w * 16 + g * 4]) = ov;
        }
    }
}

// ---------------- Kernel C: MFMA bf16 GEMM 64x64, double-buffered staging ----------------
__global__ __launch_bounds__(256) void gemm_glu_mfma(const unsigned short* __restrict__ yhi,
                                                     const float* __restrict__ W,
                                                     const unsigned short* __restrict__ whi,
                                                     const float* __restrict__ bias,
                                                     float* __restrict__ out, int preW) {
    const int b = blockIdx.z;
    const int d0 = blockIdx.y * 64;
    const int l0 = blockIdx.x * 64;
    const int tid = threadIdx.x;
    const int lane = tid & 63;
    const int wid = tid >> 6;
    const int wave_m = wid & 1;
    const int wave_n = wid >> 1;
    const int l15 = lane & 15;
    const int g = lane >> 4;

    __shared__ unsigned short Ysh[2][32 * 64];   // 2 x 4 KB
    __shared__ char Wlds[2][128 * 64];           // 2 x 8 KB

    f32x4 acc[4][2];
#pragma unroll
    for (int i = 0; i < 4; i++)
#pragma unroll
        for (int j = 0; j < 2; j++) acc[i][j] = (f32x4){0.f, 0.f, 0.f, 0.f};

    // staging helper (inlined twice below via lambda-free macro style)
#define STAGE(BUF, KT)                                                                   \
    {                                                                                    \
        const int h0s = (KT) * 32;                                                       \
        {                                                                                \
            int kr = tid >> 3;                                                           \
            int cc = tid & 7;                                                            \
            int scol = (cc * 8) ^ ((kr & 8) ? 8 : 0);                                    \
            const unsigned short* srcY = yhi + ((size_t)(b * HH + h0s + kr)) * LL + l0 + scol; \
            gload_lds16(srcY, (char*)Ysh[BUF] + tid * 16);                               \
        }                                                                                \
        if (preW) {                                                                      \
            _Pragma("unroll")                                                            \
            for (int e = 0; e < 2; e++) {                                                \
                int c = e * 256 + tid;                                                   \
                int row = c >> 2;                                                        \
                int gx = c & 3;                                                          \
                int qq = (row >> 1) & 3;                                                 \
                int grow = (row < 64) ? (d0 + row) : (448 + d0 + row);                   \
                const unsigned short* srcW = whi + (size_t)grow * 512 + h0s + ((gx ^ qq) * 8); \
                gload_lds16(srcW, Wlds[BUF] + c * 16);                                   \
            }                                                                            \
        } else {                                                                         \
            int row = tid >> 1;                                                          \
            int kb = (tid & 1) * 16;                                                     \
            int qq = (row >> 1) & 3;                                                     \
            int grow = (row < 64) ? (d0 + row) : (448 + d0 + row);                       \
            const float* srcW = W + (size_t)grow * 512 + h0s + kb;                       \
            float4 w0 = *(const float4*)(srcW);                                          \
            float4 w1 = *(const float4*)(srcW + 4);                                      \
            float4 w2 = *(const float4*)(srcW + 8);                                      \
            float4 w3 = *(const float4*)(srcW + 12);                                     \
            short8 v0, v1;                                                               \
            v0[0] = (short)f2bf(w0.x); v0[1] = (short)f2bf(w0.y);                        \
            v0[2] = (short)f2bf(w0.z); v0[3] = (short)f2bf(w0.w);                        \
            v0[4] = (short)f2bf(w1.x); v0[5] = (short)f2bf(w1.y);                        \
            v0[6] = (short)f2bf(w1.z); v0[7] = (short)f2bf(w1.w);                        \
            v1[0] = (short)f2bf(w2.x); v1[1] = (short)f2bf(w2.y);                        \
            v1[2] = (short)f2bf(w2.z); v1[3] = (short)f2bf(w2.w);                        \
            v1[4] = (short)f2bf(w3.x); v1[5] = (short)f2bf(w3.y);                        \
            v1[6] = (short)f2bf(w3.z); v1[7] = (short)f2bf(w3.w);                        \
            int g0 = kb >> 3;                                                            \
            *(short8*)(Wlds[BUF] + row * 64 + ((g0 ^ qq) * 16)) = v0;                    \
            *(short8*)(Wlds[BUF] + row * 64 + (((g0 + 1) ^ qq) * 16)) = v1;              \
        }                                                                                \
    }

    STAGE(0, 0)
    __syncthreads();

    int cur = 0;
    for (int kt = 0; kt < 16; kt++) {
        if (kt < 15) STAGE(cur ^ 1, kt + 1)   // issue next tile into other buffer

        short8 af[4];
#pragma unroll
        for (int mi = 0; mi < 4; mi++) {
            int rowb = (mi < 2) ? (wave_m * 32 + mi * 16) : (64 + wave_m * 32 + (mi - 2) * 16);
            int row = rowb + l15;
            int qq = (row >> 1) & 3;
            af[mi] = *(const short8*)(Wlds[cur] + row * 64 + ((g ^ qq) * 16));
        }
#pragma unroll
        for (int ni = 0; ni < 2; ni++) {
            int col = wave_n * 32 + ni * 16 + l15;
            int cs = col ^ ((g & 1) << 3);
            const unsigned short* yb = Ysh[cur] + (8 * g) * 64 + cs;
            short8 bh;
            bh[0] = (short)yb[0 * 64];
            bh[1] = (short)yb[1 * 64];
            bh[2] = (short)yb[2 * 64];
            bh[3] = (short)yb[3 * 64];
            bh[4] = (short)yb[4 * 64];
            bh[5] = (short)yb[5 * 64];
            bh[6] = (short)yb[6 * 64];
            bh[7] = (short)yb[7 * 64];
#pragma unroll
            for (int mi = 0; mi < 4; mi++) {
                acc[mi][ni] = __builtin_amdgcn_mfma_f32_16x16x32_bf16(af[mi], bh, acc[mi][ni], 0, 0, 0);
            }
        }
        __syncthreads();   // drains staging; buf[cur] reads done; swap safe
        cur ^= 1;
    }
#undef STAGE

#pragma unroll
    for (int mi = 0; mi < 2; mi++) {
        int dbase = d0 + wave_m * 32 + mi * 16 + (g << 2);
#pragma unroll
        for (int r = 0; r < 4; r++) {
            int d = dbase + r;
            float b1 = bias[d], b2 = bias[DMOUT + d];
#pragma unroll
            for (int ni = 0; ni < 2; ni++) {
                int l = l0 + wave_n * 32 + ni * 16 + l15;
                float z1 = acc[mi][ni][r] + b1;
                float z2 = acc[mi + 2][ni][r] + b2;
                out[((size_t)(b * DMOUT + d)) * LL + l] = z1 * (1.0f / (1.0f + expf(-z2)));
            }
        }
    }
}

extern "C" void kernel_launch(void* const* d_in, const int* in_sizes, int n_in,
                              void* d_out, int out_size, void* d_ws, size_t ws_size,
                              hipStream_t stream) {
    const float* u      = (const float*)d_in[0];
    const float* log_dt = (const float*)d_in[1];
    const float* A_re   = (const float*)d_in[2];
    const float* A_im   = (const float*)d_in[3];
    const float* B_re   = (const float*)d_in[4];
    const float* B_im   = (const float*)d_in[5];
    const float* C_re   = (const float*)d_in[6];
    const float* C_im   = (const float*)d_in[7];
    const float* D      = (const float*)d_in[8];
    const float* W      = (const float*)d_in[9];
    const float* bias   = (const float*)d_in[10];
    float* out = (float*)d_out;

    char* ws = (char*)d_ws;
    unsigned short* yhi = (unsigned short*)ws;                     // 16,777,216 B
    unsigned* A3t = (unsigned*)(ws + 16777216);                    //  8,388,608 B
    unsigned* Et  = (unsigned*)(ws + 16777216 + 8388608);          //  8,388,608 B
    unsigned short* whi = (unsigned short*)(ws + 33554432);        //  1,048,576 B (total 34.6 MB)
    int preW = (ws_size >= (size_t)(33554432 + 1048576)) ? 1 : 0;

    prep_kernel<<<HH, 256, 0, stream>>>(log_dt, A_re, A_im, B_re, B_im, C_re, C_im,
                                        W, A3t, Et, whi, preW);
    ssm_kernel<<<dim3(HH, BB), 256, 0, stream>>>(u, log_dt, A_re, A_im, B_re, B_im,
                                                 C_re, C_im, D, A3t, Et, yhi);
    gemm_glu_mfma<<<dim3(64, 8, BB), 256, 0, stream>>>(yhi, W, whi, bias, out, preW);
}

// Round 19
// 77.635 us; speedup vs baseline: 5.7417x; 1.1403x over previous
//
#include <hip/hip_runtime.h>
#include <math.h>

#define BB 4
#define HH 512
#define LL 4096
#define NN 32
#define DMOUT 512

typedef __attribute__((ext_vector_type(8))) short short8;
typedef __attribute__((ext_vector_type(4))) float f32x4;

__device__ __forceinline__ unsigned f2bf(float x) {
    unsigned u = __float_as_uint(x);
    return (u + 0x7fffu + ((u >> 16) & 1u)) >> 16;
}
__device__ __forceinline__ unsigned packhl(float x) {
    unsigned hb = f2bf(x);
    float xh = __uint_as_float(hb << 16);
    return (hb << 16) | f2bf(x - xh);
}
__device__ __forceinline__ float reconhl(unsigned v) {
    return __uint_as_float(v & 0xffff0000u) + __uint_as_float(v << 16);
}
__device__ __forceinline__ float gelu_fast(float y) {
    float s2 = y * fmaf(y * y, 0.044715f, 1.0f) * 1.5957691216057308f;
    return y * (1.0f / (1.0f + __expf(-s2)));
}
__device__ __forceinline__ void gload_lds16(const void* g, void* l) {
    __builtin_amdgcn_global_load_lds((const __attribute__((address_space(1))) void*)g,
                                     (__attribute__((address_space(3))) void*)l, 16, 0, 0);
}

// ---------------- Kernel P: per-h tables (A3t, Et) + W->bf16 (fused wsplit) ----------------
__global__ __launch_bounds__(256) void prep_kernel(
    const float* __restrict__ log_dt,
    const float* __restrict__ A_re, const float* __restrict__ A_im,
    const float* __restrict__ B_re, const float* __restrict__ B_im,
    const float* __restrict__ C_re, const float* __restrict__ C_im,
    const float* __restrict__ W,
    unsigned* __restrict__ A3t, unsigned* __restrict__ Et,
    unsigned short* __restrict__ whi, int preW) {
    const int h = blockIdx.x;
    const int tid = threadIdx.x;
    __shared__ float cst_lds[256];

    if (preW) {
        int i = (h * 256 + tid) * 4;
        float4 wv = *(const float4*)(W + i);
        ushort4 o;
        o.x = (unsigned short)f2bf(wv.x);
        o.y = (unsigned short)f2bf(wv.y);
        o.z = (unsigned short)f2bf(wv.z);
        o.w = (unsigned short)f2bf(wv.w);
        *(ushort4*)(whi + i) = o;
    }

    if (tid < 32) {
        int n = tid;
        float dt = expf(log_dt[h]);
        float ar = A_re[h * NN + n], ai = A_im[h * NN + n];
        float dtar = dt * ar, dtai = dt * ai;
        float ea = expf(dtar);
        float s, c; sincosf(dtai, &s, &c);
        float dA_r = ea * c, dA_i = ea * s;
        float em_r = dA_r - 1.0f, em_i = dA_i;
        float inv = 1.0f / (ar * ar + ai * ai);
        float t_r = (em_r * ar + em_i * ai) * inv;
        float t_i = (em_i * ar - em_r * ai) * inv;
        float br = B_re[h * NN + n], bi = B_im[h * NN + n];
        cst_lds[0 * 32 + n] = dtar;
        cst_lds[1 * 32 + n] = dtai;
        cst_lds[2 * 32 + n] = dA_r;
        cst_lds[3 * 32 + n] = dA_i;
        cst_lds[4 * 32 + n] = t_r * br - t_i * bi;
        cst_lds[5 * 32 + n] = t_r * bi + t_i * br;
        cst_lds[6 * 32 + n] = 2.0f * C_re[h * NN + n];
        cst_lds[7 * 32 + n] = 2.0f * C_im[h * NN + n];
    }
    __syncthreads();

    const int n = tid & 31, q = tid >> 5;
    const float dtar = cst_lds[0 * 32 + n], dtai = cst_lds[1 * 32 + n];
    const float dAr = cst_lds[2 * 32 + n], dAi = cst_lds[3 * 32 + n];
    const float dbr = cst_lds[4 * 32 + n], dbi = cst_lds[5 * 32 + n];
    const float tcr = cst_lds[6 * 32 + n], tci = cst_lds[7 * 32 + n];

    {
        float p = (float)(56 - q * 8);
        float mr = expf(p * dtar);
        float s, c; sincosf(p * dtai, &s, &c);
        float pr = mr * c, pi = mr * s;
        unsigned* base = A3t + (size_t)h * 4096;
#pragma unroll
        for (int jj = 7; jj >= 0; jj--) {
            int m = q * 8 + jj;
            base[m * 64 + n]      = packhl(dbr * pr - dbi * pi);
            base[m * 64 + 32 + n] = packhl(dbr * pi + dbi * pr);
            float nr2 = pr * dAr - pi * dAi;
            pi = pr * dAi + pi * dAr;
            pr = nr2;
        }
    }
    {
        float p = (float)(q * 8 + 1);
        float mr = expf(p * dtar);
        float s, c; sincosf(p * dtai, &s, &c);
        float pr = mr * c, pi = mr * s;
        unsigned* base = Et + (size_t)h * 4096;
#pragma unroll
        for (int i = q * 8; i <= q * 8 + 7; i++) {
            base[i * 64 + n]      = packhl(tcr * pr - tci * pi);
            base[i * 64 + 32 + n] = packhl(-(tcr * pi + tci * pr));
            float nr2 = pr * dAr - pi * dAi;
            pi = pr * dAi + pi * dAr;
            pr = nr2;
        }
    }
}

// ---------------- Kernel B: SSM conv via MFMA chunked scan + D skip + GELU ----------------
__global__ __launch_bounds__(256, 4) void ssm_kernel(
    const float* __restrict__ u, const float* __restrict__ log_dt,
    const float* __restrict__ A_re, const float* __restrict__ A_im,
    const float* __restrict__ B_re, const float* __restrict__ B_im,
    const float* __restrict__ C_re, const float* __restrict__ C_im,
    const float* __restrict__ D,
    const unsigned* __restrict__ A3t, const unsigned* __restrict__ Et,
    unsigned short* __restrict__ yhi) {
    const int h = blockIdx.x;
    const int b = blockIdx.y;
    const int tid = threadIdx.x;
    const int lane = tid & 63;
    const int w = tid >> 6;
    const int g = lane >> 4;
    const int l15 = lane & 15;

    __shared__ unsigned short uh[64 * 72];   // 9.2 KB
    __shared__ unsigned short ul[64 * 72];   // 9.2 KB
    __shared__ unsigned XsR[64 * 36];        // 9.2 KB  [t][n] packed hi|lo (transposed)
    __shared__ unsigned XsI[64 * 36];        // 9.2 KB
    __shared__ unsigned karr_pk[128];
    __shared__ float kpart[256];
    __shared__ float cst_lds[256];

    {
        const float* urow = u + ((size_t)(b * HH + h)) * LL;
#pragma unroll
        for (int r = 0; r < 4; r++) {
            int f = tid + 256 * r;
            float4 v = *(const float4*)(urow + f * 4);
            int t = f >> 4, mb = (f & 15) << 2;
            unsigned hx = f2bf(v.x), hy = f2bf(v.y), hz = f2bf(v.z), hw = f2bf(v.w);
            uint2 hwv;
            hwv.x = hx | (hy << 16);
            hwv.y = hz | (hw << 16);
            float rx = v.x - __uint_as_float(hx << 16);
            float ry = v.y - __uint_as_float(hy << 16);
            float rz = v.z - __uint_as_float(hz << 16);
            float rw = v.w - __uint_as_float(hw << 16);
            uint2 lwv;
            lwv.x = f2bf(rx) | (f2bf(ry) << 16);
            lwv.y = f2bf(rz) | (f2bf(rw) << 16);
            *(uint2*)(&uh[t * 72 + mb]) = hwv;
            *(uint2*)(&ul[t * 72 + mb]) = lwv;
        }
    }
    if (tid < 32) {
        int n = tid;
        float dt = expf(log_dt[h]);
        float ar = A_re[h * NN + n], ai = A_im[h * NN + n];
        float dtar = dt * ar, dtai = dt * ai;
        float ea = expf(dtar);
        float s, c; sincosf(dtai, &s, &c);
        float dA_r = ea * c, dA_i = ea * s;
        float em_r = dA_r - 1.0f, em_i = dA_i;
        float inv = 1.0f / (ar * ar + ai * ai);
        float t_r = (em_r * ar + em_i * ai) * inv;
        float t_i = (em_i * ar - em_r * ai) * inv;
        float br = B_re[h * NN + n], bi = B_im[h * NN + n];
        cst_lds[0 * 32 + n] = dtar;
        cst_lds[1 * 32 + n] = dtai;
        cst_lds[2 * 32 + n] = dA_r;
        cst_lds[3 * 32 + n] = dA_i;
        cst_lds[4 * 32 + n] = t_r * br - t_i * bi;
        cst_lds[5 * 32 + n] = t_r * bi + t_i * br;
        cst_lds[6 * 32 + n] = 2.0f * C_re[h * NN + n];
        cst_lds[7 * 32 + n] = 2.0f * C_im[h * NN + n];
    }
    __syncthreads();   // S0

    // ---- Phase 1 (MFMA): F[n'][t]; store transposed [t][n'] via uint4
    {
        int nprime = w * 16 + l15;
        const unsigned* a3b = A3t + (size_t)h * 4096 + nprime;
        short8 a3h0, a3l0, a3h1, a3l1;
#pragma unroll
        for (int j = 0; j < 8; j++) {
            unsigned v = a3b[(g * 8 + j) * 64];
            a3h0[j] = (short)(v >> 16); a3l0[j] = (short)(v & 0xffffu);
            unsigned v2 = a3b[(32 + g * 8 + j) * 64];
            a3h1[j] = (short)(v2 >> 16); a3l1[j] = (short)(v2 & 0xffffu);
        }
        int nprime2 = w * 16 + g * 4;   // multiple of 4; <32 -> real, >=32 -> imag
#pragma unroll
        for (int ni = 0; ni < 4; ni++) {
            int t = ni * 16 + l15;
            short8 uH0 = *(const short8*)(uh + t * 72 + g * 8);
            short8 uL0 = *(const short8*)(ul + t * 72 + g * 8);
            short8 uH1 = *(const short8*)(uh + t * 72 + 32 + g * 8);
            short8 uL1 = *(const short8*)(ul + t * 72 + 32 + g * 8);
            f32x4 a = (f32x4){0.f, 0.f, 0.f, 0.f};
            a = __builtin_amdgcn_mfma_f32_16x16x32_bf16(a3h0, uH0, a, 0, 0, 0);
            a = __builtin_amdgcn_mfma_f32_16x16x32_bf16(a3l0, uH0, a, 0, 0, 0);
            a = __builtin_amdgcn_mfma_f32_16x16x32_bf16(a3h0, uL0, a, 0, 0, 0);
            a = __builtin_amdgcn_mfma_f32_16x16x32_bf16(a3h1, uH1, a, 0, 0, 0);
            a = __builtin_amdgcn_mfma_f32_16x16x32_bf16(a3l1, uH1, a, 0, 0, 0);
            a = __builtin_amdgcn_mfma_f32_16x16x32_bf16(a3h1, uL1, a, 0, 0, 0);
            uint4 wv;
            wv.x = __float_as_uint(a[0]); wv.y = __float_as_uint(a[1]);
            wv.z = __float_as_uint(a[2]); wv.w = __float_as_uint(a[3]);
            if (nprime2 < 32) *(uint4*)(&XsR[t * 36 + nprime2]) = wv;
            else              *(uint4*)(&XsI[t * 36 + (nprime2 - 32)]) = wv;
        }
    }
    {
        int j = tid & 63, nr = tid >> 6;
        float acc = 0.0f;
        if (j == 0) {
#pragma unroll
            for (int q = 0; q < 8; q++) {
                int n = nr * 8 + q;
                acc = fmaf(cst_lds[6 * 32 + n], cst_lds[4 * 32 + n], acc);
                acc = fmaf(-cst_lds[7 * 32 + n], cst_lds[5 * 32 + n], acc);
            }
        } else {
            const unsigned* eb = Et + (size_t)h * 4096 + (j - 1) * 64;
#pragma unroll
            for (int q = 0; q < 8; q++) {
                int n = nr * 8 + q;
                acc = fmaf(reconhl(eb[n]), cst_lds[4 * 32 + n], acc);
                acc = fmaf(reconhl(eb[32 + n]), cst_lds[5 * 32 + n], acc);
            }
        }
        kpart[nr * 64 + j] = acc;
    }
    // ---- E-frags hoisted BEFORE S1 (global Et loads hide under scan)
    short8 e0h, e0l, e1h, e1l;
    {
        int i = w * 16 + l15;
        const unsigned* eb = Et + (size_t)h * 4096 + i * 64;
#pragma unroll
        for (int j = 0; j < 8; j++) {
            int n = g * 8 + j;
            unsigned v = eb[n];
            e0h[j] = (short)(v >> 16); e0l[j] = (short)(v & 0xffffu);
            unsigned v2 = eb[32 + n];
            e1h[j] = (short)(v2 >> 16); e1l[j] = (short)(v2 & 0xffffu);
        }
    }
    __syncthreads();   // S1

    if (tid < 32) {
        int n = tid;
        float dtar = cst_lds[0 * 32 + n], dtai = cst_lds[1 * 32 + n];
        float mr = expf(64.0f * dtar);
        float s, c; sincosf(64.0f * dtai, &s, &c);
        float Mr = mr * c, Mi = mr * s;
        float cr = 0.f, ci = 0.f;
        unsigned* pR = XsR + n;
        unsigned* pI = XsI + n;
        float fr = __uint_as_float(pR[0]);
        float fi2 = __uint_as_float(pI[0]);
#pragma unroll 4
        for (int t = 0; t < 64; t++) {
            float frn = 0.f, fin = 0.f;
            if (t < 63) { frn = __uint_as_float(pR[(t + 1) * 36]); fin = __uint_as_float(pI[(t + 1) * 36]); }
            pR[t * 36] = packhl(cr);
            pI[t * 36] = packhl(ci);
            float nr = fmaf(Mr, cr, fmaf(-Mi, ci, fr));
            float nic = fmaf(Mr, ci, fmaf(Mi, cr, fi2));
            cr = nr; ci = nic;
            fr = frn; fi2 = fin;
        }
    } else if (tid >= 64 && tid < 128) {
        int j = tid - 64;
        float k = kpart[j] + kpart[64 + j] + kpart[128 + j] + kpart[192 + j];
        karr_pk[64 + j] = packhl(k);
    } else if (tid >= 128 && tid < 192) {
        karr_pk[tid - 128] = 0u;
    }
    __syncthreads();   // S2

    {
        int i = w * 16 + l15;
        short8 kh0, kl0, kh1, kl1;
#pragma unroll
        for (int j = 0; j < 8; j++) {
            unsigned v0 = karr_pk[64 + i - (g * 8 + j)];
            kh0[j] = (short)(v0 >> 16); kl0[j] = (short)(v0 & 0xffffu);
            unsigned v1 = karr_pk[64 + i - (32 + g * 8 + j)];
            kh1[j] = (short)(v1 >> 16); kl1[j] = (short)(v1 & 0xffffu);
        }
        float Dh = D[h];
        unsigned short* orow = yhi + ((size_t)(b * HH + h)) * LL;
#pragma unroll
        for (int ni = 0; ni < 4; ni++) {
            int t = ni * 16 + l15;
            short8 uH0 = *(const short8*)(uh + t * 72 + g * 8);
            short8 uL0 = *(const short8*)(ul + t * 72 + g * 8);
            short8 uH1 = *(const short8*)(uh + t * 72 + 32 + g * 8);
            short8 uL1 = *(const short8*)(ul + t * 72 + 32 + g * 8);
            // X frags via vector LDS reads from transposed layout
            uint4 r0 = *(const uint4*)(&XsR[t * 36 + g * 8]);
            uint4 r1 = *(const uint4*)(&XsR[t * 36 + g * 8 + 4]);
            uint4 i0 = *(const uint4*)(&XsI[t * 36 + g * 8]);
            uint4 i1 = *(const uint4*)(&XsI[t * 36 + g * 8 + 4]);
            short8 xrh, xrl, xih, xil;
            xrh[0] = (short)(r0.x >> 16); xrl[0] = (short)(r0.x & 0xffffu);
            xrh[1] = (short)(r0.y >> 16); xrl[1] = (short)(r0.y & 0xffffu);
            xrh[2] = (short)(r0.z >> 16); xrl[2] = (short)(r0.z & 0xffffu);
            xrh[3] = (short)(r0.w >> 16); xrl[3] = (short)(r0.w & 0xffffu);
            xrh[4] = (short)(r1.x >> 16); xrl[4] = (short)(r1.x & 0xffffu);
            xrh[5] = (short)(r1.y >> 16); xrl[5] = (short)(r1.y & 0xffffu);
            xrh[6] = (short)(r1.z >> 16); xrl[6] = (short)(r1.z & 0xffffu);
            xrh[7] = (short)(r1.w >> 16); xrl[7] = (short)(r1.w & 0xffffu);
            xih[0] = (short)(i0.x >> 16); xil[0] = (short)(i0.x & 0xffffu);
            xih[1] = (short)(i0.y >> 16); xil[1] = (short)(i0.y & 0xffffu);
            xih[2] = (short)(i0.z >> 16); xil[2] = (short)(i0.z & 0xffffu);
            xih[3] = (short)(i0.w >> 16); xil[3] = (short)(i0.w & 0xffffu);
            xih[4] = (short)(i1.x >> 16); xil[4] = (short)(i1.x & 0xffffu);
            xih[5] = (short)(i1.y >> 16); xil[5] = (short)(i1.y & 0xffffu);
            xih[6] = (short)(i1.z >> 16); xil[6] = (short)(i1.z & 0xffffu);
            xih[7] = (short)(i1.w >> 16); xil[7] = (short)(i1.w & 0xffffu);
            f32x4 a = (f32x4){0.f, 0.f, 0.f, 0.f};
            a = __builtin_amdgcn_mfma_f32_16x16x32_bf16(kh0, uH0, a, 0, 0, 0);
            a = __builtin_amdgcn_mfma_f32_16x16x32_bf16(kl0, uH0, a, 0, 0, 0);
            a = __builtin_amdgcn_mfma_f32_16x16x32_bf16(kh0, uL0, a, 0, 0, 0);
            a = __builtin_amdgcn_mfma_f32_16x16x32_bf16(kh1, uH1, a, 0, 0, 0);
            a = __builtin_amdgcn_mfma_f32_16x16x32_bf16(kl1, uH1, a, 0, 0, 0);
            a = __builtin_amdgcn_mfma_f32_16x16x32_bf16(kh1, uL1, a, 0, 0, 0);
            a = __builtin_amdgcn_mfma_f32_16x16x32_bf16(e0h, xrh, a, 0, 0, 0);
            a = __builtin_amdgcn_mfma_f32_16x16x32_bf16(e0h, xrl, a, 0, 0, 0);
            a = __builtin_amdgcn_mfma_f32_16x16x32_bf16(e0l, xrh, a, 0, 0, 0);
            a = __builtin_amdgcn_mfma_f32_16x16x32_bf16(e1h, xih, a, 0, 0, 0);
            a = __builtin_amdgcn_mfma_f32_16x16x32_bf16(e1h, xil, a, 0, 0, 0);
            a = __builtin_amdgcn_mfma_f32_16x16x32_bf16(e1l, xih, a, 0, 0, 0);
            ushort4 ov;
            unsigned short* op = &ov.x;
#pragma unroll
            for (int r = 0; r < 4; r++) {
                int io = w * 16 + g * 4 + r;
                float uv = __uint_as_float(((unsigned)uh[t * 72 + io]) << 16)
                         + __uint_as_float(((unsigned)ul[t * 72 + io]) << 16);
                float y = a[r] + Dh * uv;
                op[r] = (unsigned short)f2bf(gelu_fast(y));
            }
            *(ushort4*)(&orow[t * 64 + w * 16 + g * 4]) = ov;
        }
    }
}

// ---------------- Kernel C: MFMA bf16 GEMM 64x64, double-buffered staging ----------------
__global__ __launch_bounds__(256) void gemm_glu_mfma(const unsigned short* __restrict__ yhi,
                                                     const float* __restrict__ W,
                                                     const unsigned short* __restrict__ whi,
                                                     const float* __restrict__ bias,
                                                     float* __restrict__ out, int preW) {
    const int b = blockIdx.z;
    const int d0 = blockIdx.y * 64;
    const int l0 = blockIdx.x * 64;
    const int tid = threadIdx.x;
    const int lane = tid & 63;
    const int wid = tid >> 6;
    const int wave_m = wid & 1;
    const int wave_n = wid >> 1;
    const int l15 = lane & 15;
    const int g = lane >> 4;

    __shared__ unsigned short Ysh[2][32 * 64];
    __shared__ char Wlds[2][128 * 64];

    f32x4 acc[4][2];
#pragma unroll
    for (int i = 0; i < 4; i++)
#pragma unroll
        for (int j = 0; j < 2; j++) acc[i][j] = (f32x4){0.f, 0.f, 0.f, 0.f};

#define STAGE(BUF, KT)                                                                   \
    {                                                                                    \
        const int h0s = (KT) * 32;                                                       \
        {                                                                                \
            int kr = tid >> 3;                                                           \
            int cc = tid & 7;                                                            \
            int scol = (cc * 8) ^ ((kr & 8) ? 8 : 0);                                    \
            const unsigned short* srcY = yhi + ((size_t)(b * HH + h0s + kr)) * LL + l0 + scol; \
            gload_lds16(srcY, (char*)Ysh[BUF] + tid * 16);                               \
        }                                                                                \
        if (preW) {                                                                      \
            _Pragma("unroll")                                                            \
            for (int e = 0; e < 2; e++) {                                                \
                int c = e * 256 + tid;                                                   \
                int row = c >> 2;                                                        \
                int gx = c & 3;                                                          \
                int qq = (row >> 1) & 3;                                                 \
                int grow = (row < 64) ? (d0 + row) : (448 + d0 + row);                   \
                const unsigned short* srcW = whi + (size_t)grow * 512 + h0s + ((gx ^ qq) * 8); \
                gload_lds16(srcW, Wlds[BUF] + c * 16);                                   \
            }                                                                            \
        } else {                                                                         \
            int row = tid >> 1;                                                          \
            int kb = (tid & 1) * 16;                                                     \
            int qq = (row >> 1) & 3;                                                     \
            int grow = (row < 64) ? (d0 + row) : (448 + d0 + row);                       \
            const float* srcW = W + (size_t)grow * 512 + h0s + kb;                       \
            float4 w0 = *(const float4*)(srcW);                                          \
            float4 w1 = *(const float4*)(srcW + 4);                                      \
            float4 w2 = *(const float4*)(srcW + 8);                                      \
            float4 w3 = *(const float4*)(srcW + 12);                                     \
            short8 v0, v1;                                                               \
            v0[0] = (short)f2bf(w0.x); v0[1] = (short)f2bf(w0.y);                        \
            v0[2] = (short)f2bf(w0.z); v0[3] = (short)f2bf(w0.w);                        \
            v0[4] = (short)f2bf(w1.x); v0[5] = (short)f2bf(w1.y);                        \
            v0[6] = (short)f2bf(w1.z); v0[7] = (short)f2bf(w1.w);                        \
            v1[0] = (short)f2bf(w2.x); v1[1] = (short)f2bf(w2.y);                        \
            v1[2] = (short)f2bf(w2.z); v1[3] = (short)f2bf(w2.w);                        \
            v1[4] = (short)f2bf(w3.x); v1[5] = (short)f2bf(w3.y);                        \
            v1[6] = (short)f2bf(w3.z); v1[7] = (short)f2bf(w3.w);                        \
            int g0 = kb >> 3;                                                            \
            *(short8*)(Wlds[BUF] + row * 64 + ((g0 ^ qq) * 16)) = v0;                    \
            *(short8*)(Wlds[BUF] + row * 64 + (((g0 + 1) ^ qq) * 16)) = v1;              \
        }                                                                                \
    }

    STAGE(0, 0)
    __syncthreads();

    int cur = 0;
    for (int kt = 0; kt < 16; kt++) {
        if (kt < 15) STAGE(cur ^ 1, kt + 1)

        short8 af[4];
#pragma unroll
        for (int mi = 0; mi < 4; mi++) {
            int rowb = (mi < 2) ? (wave_m * 32 + mi * 16) : (64 + wave_m * 32 + (mi - 2) * 16);
            int row = rowb + l15;
            int qq = (row >> 1) & 3;
            af[mi] = *(const short8*)(Wlds[cur] + row * 64 + ((g ^ qq) * 16));
        }
#pragma unroll
        for (int ni = 0; ni < 2; ni++) {
            int col = wave_n * 32 + ni * 16 + l15;
            int cs = col ^ ((g & 1) << 3);
            const unsigned short* yb = Ysh[cur] + (8 * g) * 64 + cs;
            short8 bh;
            bh[0] = (short)yb[0 * 64];
            bh[1] = (short)yb[1 * 64];
            bh[2] = (short)yb[2 * 64];
            bh[3] = (short)yb[3 * 64];
            bh[4] = (short)yb[4 * 64];
            bh[5] = (short)yb[5 * 64];
            bh[6] = (short)yb[6 * 64];
            bh[7] = (short)yb[7 * 64];
#pragma unroll
            for (int mi = 0; mi < 4; mi++) {
                acc[mi][ni] = __builtin_amdgcn_mfma_f32_16x16x32_bf16(af[mi], bh, acc[mi][ni], 0, 0, 0);
            }
        }
        __syncthreads();
        cur ^= 1;
    }
#undef STAGE

#pragma unroll
    for (int mi = 0; mi < 2; mi++) {
        int dbase = d0 + wave_m * 32 + mi * 16 + (g << 2);
#pragma unroll
        for (int r = 0; r < 4; r++) {
            int d = dbase + r;
            float b1 = bias[d], b2 = bias[DMOUT + d];
#pragma unroll
            for (int ni = 0; ni < 2; ni++) {
                int l = l0 + wave_n * 32 + ni * 16 + l15;
                float z1 = acc[mi][ni][r] + b1;
                float z2 = acc[mi + 2][ni][r] + b2;
                out[((size_t)(b * DMOUT + d)) * LL + l] = z1 * (1.0f / (1.0f + __expf(-z2)));
            }
        }
    }
}

extern "C" void kernel_launch(void* const* d_in, const int* in_sizes, int n_in,
                              void* d_out, int out_size, void* d_ws, size_t ws_size,
                              hipStream_t stream) {
    const float* u      = (const float*)d_in[0];
    const float* log_dt = (const float*)d_in[1];
    const float* A_re   = (const float*)d_in[2];
    const float* A_im   = (const float*)d_in[3];
    const float* B_re   = (const float*)d_in[4];
    const float* B_im   = (const float*)d_in[5];
    const float* C_re   = (const float*)d_in[6];
    const float* C_im   = (const float*)d_in[7];
    const float* D      = (const float*)d_in[8];
    const float* W      = (const float*)d_in[9];
    const float* bias   = (const float*)d_in[10];
    float* out = (float*)d_out;

    char* ws = (char*)d_ws;
    unsigned short* yhi = (unsigned short*)ws;                     // 16,777,216 B
    unsigned* A3t = (unsigned*)(ws + 16777216);                    //  8,388,608 B
    unsigned* Et  = (unsigned*)(ws + 16777216 + 8388608);          //  8,388,608 B
    unsigned short* whi = (unsigned short*)(ws + 33554432);        //  1,048,576 B (total 34.6 MB)
    int preW = (ws_size >= (size_t)(33554432 + 1048576)) ? 1 : 0;

    prep_kernel<<<HH, 256, 0, stream>>>(log_dt, A_re, A_im, B_re, B_im, C_re, C_im,
                                        W, A3t, Et, whi, preW);
    ssm_kernel<<<dim3(HH, BB), 256, 0, stream>>>(u, log_dt, A_re, A_im, B_re, B_im,
                                                 C_re, C_im, D, A3t, Et, yhi);
    gemm_glu_mfma<<<dim3(64, 8, BB), 256, 0, stream>>>(yhi, W, whi, bias, out, preW);
}

// Round 20
// 75.544 us; speedup vs baseline: 5.9006x; 1.0277x over previous
//
#include <hip/hip_runtime.h>
#include <math.h>

#define BB 4
#define HH 512
#define LL 4096
#define NN 32
#define DMOUT 512

typedef __attribute__((ext_vector_type(8))) short short8;
typedef __attribute__((ext_vector_type(4))) float f32x4;

__device__ __forceinline__ unsigned f2bf(float x) {
    unsigned u = __float_as_uint(x);
    return (u + 0x7fffu + ((u >> 16) & 1u)) >> 16;
}
__device__ __forceinline__ unsigned packhl(float x) {
    unsigned hb = f2bf(x);
    float xh = __uint_as_float(hb << 16);
    return (hb << 16) | f2bf(x - xh);
}
__device__ __forceinline__ float reconhl(unsigned v) {
    return __uint_as_float(v & 0xffff0000u) + __uint_as_float(v << 16);
}
__device__ __forceinline__ float gelu_fast(float y) {
    float s2 = y * fmaf(y * y, 0.044715f, 1.0f) * 1.5957691216057308f;
    return y * (1.0f / (1.0f + __expf(-s2)));
}
__device__ __forceinline__ void gload_lds16(const void* g, void* l) {
    __builtin_amdgcn_global_load_lds((const __attribute__((address_space(1))) void*)g,
                                     (__attribute__((address_space(3))) void*)l, 16, 0, 0);
}

// ---------------- Kernel P: per-h tables (A3t, Et) + W->bf16 (fused wsplit) ----------------
__global__ __launch_bounds__(256) void prep_kernel(
    const float* __restrict__ log_dt,
    const float* __restrict__ A_re, const float* __restrict__ A_im,
    const float* __restrict__ B_re, const float* __restrict__ B_im,
    const float* __restrict__ C_re, const float* __restrict__ C_im,
    const float* __restrict__ W,
    unsigned* __restrict__ A3t, unsigned* __restrict__ Et,
    unsigned short* __restrict__ whi, int preW) {
    const int h = blockIdx.x;
    const int tid = threadIdx.x;
    __shared__ float cst_lds[256];

    if (preW) {
        int i = (h * 256 + tid) * 4;
        float4 wv = *(const float4*)(W + i);
        ushort4 o;
        o.x = (unsigned short)f2bf(wv.x);
        o.y = (unsigned short)f2bf(wv.y);
        o.z = (unsigned short)f2bf(wv.z);
        o.w = (unsigned short)f2bf(wv.w);
        *(ushort4*)(whi + i) = o;
    }

    if (tid < 32) {
        int n = tid;
        float dt = expf(log_dt[h]);
        float ar = A_re[h * NN + n], ai = A_im[h * NN + n];
        float dtar = dt * ar, dtai = dt * ai;
        float ea = expf(dtar);
        float s, c; sincosf(dtai, &s, &c);
        float dA_r = ea * c, dA_i = ea * s;
        float em_r = dA_r - 1.0f, em_i = dA_i;
        float inv = 1.0f / (ar * ar + ai * ai);
        float t_r = (em_r * ar + em_i * ai) * inv;
        float t_i = (em_i * ar - em_r * ai) * inv;
        float br = B_re[h * NN + n], bi = B_im[h * NN + n];
        cst_lds[0 * 32 + n] = dtar;
        cst_lds[1 * 32 + n] = dtai;
        cst_lds[2 * 32 + n] = dA_r;
        cst_lds[3 * 32 + n] = dA_i;
        cst_lds[4 * 32 + n] = t_r * br - t_i * bi;
        cst_lds[5 * 32 + n] = t_r * bi + t_i * br;
        cst_lds[6 * 32 + n] = 2.0f * C_re[h * NN + n];
        cst_lds[7 * 32 + n] = 2.0f * C_im[h * NN + n];
    }
    __syncthreads();

    const int n = tid & 31, q = tid >> 5;
    const float dtar = cst_lds[0 * 32 + n], dtai = cst_lds[1 * 32 + n];
    const float dAr = cst_lds[2 * 32 + n], dAi = cst_lds[3 * 32 + n];
    const float dbr = cst_lds[4 * 32 + n], dbi = cst_lds[5 * 32 + n];
    const float tcr = cst_lds[6 * 32 + n], tci = cst_lds[7 * 32 + n];

    {
        float p = (float)(56 - q * 8);
        float mr = expf(p * dtar);
        float s, c; sincosf(p * dtai, &s, &c);
        float pr = mr * c, pi = mr * s;
        unsigned* base = A3t + (size_t)h * 4096;
#pragma unroll
        for (int jj = 7; jj >= 0; jj--) {
            int m = q * 8 + jj;
            base[m * 64 + n]      = packhl(dbr * pr - dbi * pi);
            base[m * 64 + 32 + n] = packhl(dbr * pi + dbi * pr);
            float nr2 = pr * dAr - pi * dAi;
            pi = pr * dAi + pi * dAr;
            pr = nr2;
        }
    }
    {
        float p = (float)(q * 8 + 1);
        float mr = expf(p * dtar);
        float s, c; sincosf(p * dtai, &s, &c);
        float pr = mr * c, pi = mr * s;
        unsigned* base = Et + (size_t)h * 4096;
#pragma unroll
        for (int i = q * 8; i <= q * 8 + 7; i++) {
            base[i * 64 + n]      = packhl(tcr * pr - tci * pi);
            base[i * 64 + 32 + n] = packhl(-(tcr * pi + tci * pr));
            float nr2 = pr * dAr - pi * dAi;
            pi = pr * dAi + pi * dAr;
            pr = nr2;
        }
    }
}

// ---------------- Kernel B: SSM conv via MFMA; 2 batches per block ----------------
__global__ __launch_bounds__(256, 4) void ssm_kernel(
    const float* __restrict__ u, const float* __restrict__ log_dt,
    const float* __restrict__ A_re, const float* __restrict__ A_im,
    const float* __restrict__ B_re, const float* __restrict__ B_im,
    const float* __restrict__ C_re, const float* __restrict__ C_im,
    const float* __restrict__ D,
    const unsigned* __restrict__ A3t, const unsigned* __restrict__ Et,
    unsigned short* __restrict__ yhi) {
    const int h = blockIdx.x;
    const int b0 = blockIdx.y * 2;
    const int tid = threadIdx.x;
    const int lane = tid & 63;
    const int w = tid >> 6;
    const int g = lane >> 4;
    const int l15 = lane & 15;

    __shared__ unsigned short uh[64 * 72];   // 9.2 KB
    __shared__ unsigned short ul[64 * 72];   // 9.2 KB
    __shared__ unsigned XsR[64 * 36];        // 9.2 KB [t][n] packed
    __shared__ unsigned XsI[64 * 36];        // 9.2 KB
    __shared__ unsigned karr_pk[128];
    __shared__ float kpart[256];
    __shared__ float cst_lds[256];

    // ---- per-mode constants (once)
    if (tid < 32) {
        int n = tid;
        float dt = expf(log_dt[h]);
        float ar = A_re[h * NN + n], ai = A_im[h * NN + n];
        float dtar = dt * ar, dtai = dt * ai;
        float ea = expf(dtar);
        float s, c; sincosf(dtai, &s, &c);
        float dA_r = ea * c, dA_i = ea * s;
        float em_r = dA_r - 1.0f, em_i = dA_i;
        float inv = 1.0f / (ar * ar + ai * ai);
        float t_r = (em_r * ar + em_i * ai) * inv;
        float t_i = (em_i * ar - em_r * ai) * inv;
        float br = B_re[h * NN + n], bi = B_im[h * NN + n];
        cst_lds[0 * 32 + n] = dtar;
        cst_lds[1 * 32 + n] = dtai;
        cst_lds[2 * 32 + n] = dA_r;
        cst_lds[3 * 32 + n] = dA_i;
        cst_lds[4 * 32 + n] = t_r * br - t_i * bi;
        cst_lds[5 * 32 + n] = t_r * bi + t_i * br;
        cst_lds[6 * 32 + n] = 2.0f * C_re[h * NN + n];
        cst_lds[7 * 32 + n] = 2.0f * C_im[h * NN + n];
    }
    __syncthreads();   // S0: cst ready

    // ---- fixed per-h work (once): A3 frags, E frags (regs), scan M, kpart
    short8 a3h0, a3l0, a3h1, a3l1;
    {
        int nprime = w * 16 + l15;
        const unsigned* a3b = A3t + (size_t)h * 4096 + nprime;
#pragma unroll
        for (int j = 0; j < 8; j++) {
            unsigned v = a3b[(g * 8 + j) * 64];
            a3h0[j] = (short)(v >> 16); a3l0[j] = (short)(v & 0xffffu);
            unsigned v2 = a3b[(32 + g * 8 + j) * 64];
            a3h1[j] = (short)(v2 >> 16); a3l1[j] = (short)(v2 & 0xffffu);
        }
    }
    short8 e0h, e0l, e1h, e1l;
    {
        int i = w * 16 + l15;
        const unsigned* eb = Et + (size_t)h * 4096 + i * 64;
#pragma unroll
        for (int j = 0; j < 8; j++) {
            int n = g * 8 + j;
            unsigned v = eb[n];
            e0h[j] = (short)(v >> 16); e0l[j] = (short)(v & 0xffffu);
            unsigned v2 = eb[32 + n];
            e1h[j] = (short)(v2 >> 16); e1l[j] = (short)(v2 & 0xffffu);
        }
    }
    float Mr = 0.f, Mi = 0.f;
    if (tid < 32) {
        int n = tid;
        float dtar = cst_lds[0 * 32 + n], dtai = cst_lds[1 * 32 + n];
        float mr = expf(64.0f * dtar);
        float s, c; sincosf(64.0f * dtai, &s, &c);
        Mr = mr * c; Mi = mr * s;
    }
    {
        int j = tid & 63, nr = tid >> 6;
        float acc = 0.0f;
        if (j == 0) {
#pragma unroll
            for (int q = 0; q < 8; q++) {
                int n = nr * 8 + q;
                acc = fmaf(cst_lds[6 * 32 + n], cst_lds[4 * 32 + n], acc);
                acc = fmaf(-cst_lds[7 * 32 + n], cst_lds[5 * 32 + n], acc);
            }
        } else {
            const unsigned* eb = Et + (size_t)h * 4096 + (j - 1) * 64;
#pragma unroll
            for (int q = 0; q < 8; q++) {
                int n = nr * 8 + q;
                acc = fmaf(reconhl(eb[n]), cst_lds[4 * 32 + n], acc);
                acc = fmaf(reconhl(eb[32 + n]), cst_lds[5 * 32 + n], acc);
            }
        }
        kpart[nr * 64 + j] = acc;
    }
    __syncthreads();   // S1: kpart ready

    if (tid >= 64 && tid < 128) {
        int j = tid - 64;
        float k = kpart[j] + kpart[64 + j] + kpart[128 + j] + kpart[192 + j];
        karr_pk[64 + j] = packhl(k);
    } else if (tid >= 128 && tid < 192) {
        karr_pk[tid - 128] = 0u;
    }
    const float Dh = D[h];

    // ---- per-batch loop
    for (int bb = 0; bb < 2; bb++) {
        const int b = b0 + bb;
        // stage u[b] -> bf16 hi/lo LDS (uh/ul free: bb=0 fresh; bb>0 covered by S_end)
        {
            const float* urow = u + ((size_t)(b * HH + h)) * LL;
#pragma unroll
            for (int r = 0; r < 4; r++) {
                int f = tid + 256 * r;
                float4 v = *(const float4*)(urow + f * 4);
                int t = f >> 4, mb = (f & 15) << 2;
                unsigned hx = f2bf(v.x), hy = f2bf(v.y), hz = f2bf(v.z), hw = f2bf(v.w);
                uint2 hwv;
                hwv.x = hx | (hy << 16);
                hwv.y = hz | (hw << 16);
                float rx = v.x - __uint_as_float(hx << 16);
                float ry = v.y - __uint_as_float(hy << 16);
                float rz = v.z - __uint_as_float(hz << 16);
                float rw = v.w - __uint_as_float(hw << 16);
                uint2 lwv;
                lwv.x = f2bf(rx) | (f2bf(ry) << 16);
                lwv.y = f2bf(rz) | (f2bf(rw) << 16);
                *(uint2*)(&uh[t * 72 + mb]) = hwv;
                *(uint2*)(&ul[t * 72 + mb]) = lwv;
            }
        }
        __syncthreads();   // S3: u ready (karr_pk also visible by now)

        // phase 1 (MFMA): F -> Xs transposed
        {
            int nprime2 = w * 16 + g * 4;
#pragma unroll
            for (int ni = 0; ni < 4; ni++) {
                int t = ni * 16 + l15;
                short8 uH0 = *(const short8*)(uh + t * 72 + g * 8);
                short8 uL0 = *(const short8*)(ul + t * 72 + g * 8);
                short8 uH1 = *(const short8*)(uh + t * 72 + 32 + g * 8);
                short8 uL1 = *(const short8*)(ul + t * 72 + 32 + g * 8);
                f32x4 a = (f32x4){0.f, 0.f, 0.f, 0.f};
                a = __builtin_amdgcn_mfma_f32_16x16x32_bf16(a3h0, uH0, a, 0, 0, 0);
                a = __builtin_amdgcn_mfma_f32_16x16x32_bf16(a3l0, uH0, a, 0, 0, 0);
                a = __builtin_amdgcn_mfma_f32_16x16x32_bf16(a3h0, uL0, a, 0, 0, 0);
                a = __builtin_amdgcn_mfma_f32_16x16x32_bf16(a3h1, uH1, a, 0, 0, 0);
                a = __builtin_amdgcn_mfma_f32_16x16x32_bf16(a3l1, uH1, a, 0, 0, 0);
                a = __builtin_amdgcn_mfma_f32_16x16x32_bf16(a3h1, uL1, a, 0, 0, 0);
                uint4 wv;
                wv.x = __float_as_uint(a[0]); wv.y = __float_as_uint(a[1]);
                wv.z = __float_as_uint(a[2]); wv.w = __float_as_uint(a[3]);
                if (nprime2 < 32) *(uint4*)(&XsR[t * 36 + nprime2]) = wv;
                else              *(uint4*)(&XsI[t * 36 + (nprime2 - 32)]) = wv;
            }
        }
        __syncthreads();   // S4: F ready

        if (tid < 32) {
            int n = tid;
            float cr = 0.f, ci = 0.f;
            unsigned* pR = XsR + n;
            unsigned* pI = XsI + n;
            float fr = __uint_as_float(pR[0]);
            float fi2 = __uint_as_float(pI[0]);
#pragma unroll 4
            for (int t = 0; t < 64; t++) {
                float frn = 0.f, fin = 0.f;
                if (t < 63) { frn = __uint_as_float(pR[(t + 1) * 36]); fin = __uint_as_float(pI[(t + 1) * 36]); }
                pR[t * 36] = packhl(cr);
                pI[t * 36] = packhl(ci);
                float nr = fmaf(Mr, cr, fmaf(-Mi, ci, fr));
                float nic = fmaf(Mr, ci, fmaf(Mi, cr, fi2));
                cr = nr; ci = nic;
                fr = frn; fi2 = fin;
            }
        }
        __syncthreads();   // S5: state ready

        // phase 3 (MFMA): y = K*U + E*X ; D-skip + GELU; store bf16-hi
        {
            int i = w * 16 + l15;
            short8 kh0, kl0, kh1, kl1;
#pragma unroll
            for (int j = 0; j < 8; j++) {
                unsigned v0 = karr_pk[64 + i - (g * 8 + j)];
                kh0[j] = (short)(v0 >> 16); kl0[j] = (short)(v0 & 0xffffu);
                unsigned v1 = karr_pk[64 + i - (32 + g * 8 + j)];
                kh1[j] = (short)(v1 >> 16); kl1[j] = (short)(v1 & 0xffffu);
            }
            unsigned short* orow = yhi + ((size_t)(b * HH + h)) * LL;
#pragma unroll
            for (int ni = 0; ni < 4; ni++) {
                int t = ni * 16 + l15;
                short8 uH0 = *(const short8*)(uh + t * 72 + g * 8);
                short8 uL0 = *(const short8*)(ul + t * 72 + g * 8);
                short8 uH1 = *(const short8*)(uh + t * 72 + 32 + g * 8);
                short8 uL1 = *(const short8*)(ul + t * 72 + 32 + g * 8);
                uint4 r0 = *(const uint4*)(&XsR[t * 36 + g * 8]);
                uint4 r1 = *(const uint4*)(&XsR[t * 36 + g * 8 + 4]);
                uint4 i0 = *(const uint4*)(&XsI[t * 36 + g * 8]);
                uint4 i1 = *(const uint4*)(&XsI[t * 36 + g * 8 + 4]);
                short8 xrh, xrl, xih, xil;
                xrh[0] = (short)(r0.x >> 16); xrl[0] = (short)(r0.x & 0xffffu);
                xrh[1] = (short)(r0.y >> 16); xrl[1] = (short)(r0.y & 0xffffu);
                xrh[2] = (short)(r0.z >> 16); xrl[2] = (short)(r0.z & 0xffffu);
                xrh[3] = (short)(r0.w >> 16); xrl[3] = (short)(r0.w & 0xffffu);
                xrh[4] = (short)(r1.x >> 16); xrl[4] = (short)(r1.x & 0xffffu);
                xrh[5] = (short)(r1.y >> 16); xrl[5] = (short)(r1.y & 0xffffu);
                xrh[6] = (short)(r1.z >> 16); xrl[6] = (short)(r1.z & 0xffffu);
                xrh[7] = (short)(r1.w >> 16); xrl[7] = (short)(r1.w & 0xffffu);
                xih[0] = (short)(i0.x >> 16); xil[0] = (short)(i0.x & 0xffffu);
                xih[1] = (short)(i0.y >> 16); xil[1] = (short)(i0.y & 0xffffu);
                xih[2] = (short)(i0.z >> 16); xil[2] = (short)(i0.z & 0xffffu);
                xih[3] = (short)(i0.w >> 16); xil[3] = (short)(i0.w & 0xffffu);
                xih[4] = (short)(i1.x >> 16); xil[4] = (short)(i1.x & 0xffffu);
                xih[5] = (short)(i1.y >> 16); xil[5] = (short)(i1.y & 0xffffu);
                xih[6] = (short)(i1.z >> 16); xil[6] = (short)(i1.z & 0xffffu);
                xih[7] = (short)(i1.w >> 16); xil[7] = (short)(i1.w & 0xffffu);
                f32x4 a = (f32x4){0.f, 0.f, 0.f, 0.f};
                a = __builtin_amdgcn_mfma_f32_16x16x32_bf16(kh0, uH0, a, 0, 0, 0);
                a = __builtin_amdgcn_mfma_f32_16x16x32_bf16(kl0, uH0, a, 0, 0, 0);
                a = __builtin_amdgcn_mfma_f32_16x16x32_bf16(kh0, uL0, a, 0, 0, 0);
                a = __builtin_amdgcn_mfma_f32_16x16x32_bf16(kh1, uH1, a, 0, 0, 0);
                a = __builtin_amdgcn_mfma_f32_16x16x32_bf16(kl1, uH1, a, 0, 0, 0);
                a = __builtin_amdgcn_mfma_f32_16x16x32_bf16(kh1, uL1, a, 0, 0, 0);
                a = __builtin_amdgcn_mfma_f32_16x16x32_bf16(e0h, xrh, a, 0, 0, 0);
                a = __builtin_amdgcn_mfma_f32_16x16x32_bf16(e0h, xrl, a, 0, 0, 0);
                a = __builtin_amdgcn_mfma_f32_16x16x32_bf16(e0l, xrh, a, 0, 0, 0);
                a = __builtin_amdgcn_mfma_f32_16x16x32_bf16(e1h, xih, a, 0, 0, 0);
                a = __builtin_amdgcn_mfma_f32_16x16x32_bf16(e1h, xil, a, 0, 0, 0);
                a = __builtin_amdgcn_mfma_f32_16x16x32_bf16(e1l, xih, a, 0, 0, 0);
                ushort4 ov;
                unsigned short* op = &ov.x;
#pragma unroll
                for (int r = 0; r < 4; r++) {
                    int io = w * 16 + g * 4 + r;
                    float uv = __uint_as_float(((unsigned)uh[t * 72 + io]) << 16)
                             + __uint_as_float(((unsigned)ul[t * 72 + io]) << 16);
                    float y = a[r] + Dh * uv;
                    op[r] = (unsigned short)f2bf(gelu_fast(y));
                }
                *(ushort4*)(&orow[t * 64 + w * 16 + g * 4]) = ov;
            }
        }
        __syncthreads();   // S6: uh/ul/Xs free for next bb
    }
}

// ---------------- Kernel C: MFMA bf16 GEMM 64x64, double-buffered staging ----------------
__global__ __launch_bounds__(256) void gemm_glu_mfma(const unsigned short* __restrict__ yhi,
                                                     const float* __restrict__ W,
                                                     const unsigned short* __restrict__ whi,
                                                     const float* __restrict__ bias,
                                                     float* __restrict__ out, int preW) {
    const int b = blockIdx.z;
    const int d0 = blockIdx.y * 64;
    const int l0 = blockIdx.x * 64;
    const int tid = threadIdx.x;
    const int lane = tid & 63;
    const int wid = tid >> 6;
    const int wave_m = wid & 1;
    const int wave_n = wid >> 1;
    const int l15 = lane & 15;
    const int g = lane >> 4;

    __shared__ unsigned short Ysh[2][32 * 64];
    __shared__ char Wlds[2][128 * 64];

    f32x4 acc[4][2];
#pragma unroll
    for (int i = 0; i < 4; i++)
#pragma unroll
        for (int j = 0; j < 2; j++) acc[i][j] = (f32x4){0.f, 0.f, 0.f, 0.f};

#define STAGE(BUF, KT)                                                                   \
    {                                                                                    \
        const int h0s = (KT) * 32;                                                       \
        {                                                                                \
            int kr = tid >> 3;                                                           \
            int cc = tid & 7;                                                            \
            int scol = (cc * 8) ^ ((kr & 8) ? 8 : 0);                                    \
            const unsigned short* srcY = yhi + ((size_t)(b * HH + h0s + kr)) * LL + l0 + scol; \
            gload_lds16(srcY, (char*)Ysh[BUF] + tid * 16);                               \
        }                                                                                \
        if (preW) {                                                                      \
            _Pragma("unroll")                                                            \
            for (int e = 0; e < 2; e++) {                                                \
                int c = e * 256 + tid;                                                   \
                int row = c >> 2;                                                        \
                int gx = c & 3;                                                          \
                int qq = (row >> 1) & 3;                                                 \
                int grow = (row < 64) ? (d0 + row) : (448 + d0 + row);                   \
                const unsigned short* srcW = whi + (size_t)grow * 512 + h0s + ((gx ^ qq) * 8); \
                gload_lds16(srcW, Wlds[BUF] + c * 16);                                   \
            }                                                                            \
        } else {                                                                         \
            int row = tid >> 1;                                                          \
            int kb = (tid & 1) * 16;                                                     \
            int qq = (row >> 1) & 3;                                                     \
            int grow = (row < 64) ? (d0 + row) : (448 + d0 + row);                       \
            const float* srcW = W + (size_t)grow * 512 + h0s + kb;                       \
            float4 w0 = *(const float4*)(srcW);                                          \
            float4 w1 = *(const float4*)(srcW + 4);                                      \
            float4 w2 = *(const float4*)(srcW + 8);                                      \
            float4 w3 = *(const float4*)(srcW + 12);                                     \
            short8 v0, v1;                                                               \
            v0[0] = (short)f2bf(w0.x); v0[1] = (short)f2bf(w0.y);                        \
            v0[2] = (short)f2bf(w0.z); v0[3] = (short)f2bf(w0.w);                        \
            v0[4] = (short)f2bf(w1.x); v0[5] = (short)f2bf(w1.y);                        \
            v0[6] = (short)f2bf(w1.z); v0[7] = (short)f2bf(w1.w);                        \
            v1[0] = (short)f2bf(w2.x); v1[1] = (short)f2bf(w2.y);                        \
            v1[2] = (short)f2bf(w2.z); v1[3] = (short)f2bf(w2.w);                        \
            v1[4] = (short)f2bf(w3.x); v1[5] = (short)f2bf(w3.y);                        \
            v1[6] = (short)f2bf(w3.z); v1[7] = (short)f2bf(w3.w);                        \
            int g0 = kb >> 3;                                                            \
            *(short8*)(Wlds[BUF] + row * 64 + ((g0 ^ qq) * 16)) = v0;                    \
            *(short8*)(Wlds[BUF] + row * 64 + (((g0 + 1) ^ qq) * 16)) = v1;              \
        }                                                                                \
    }

    STAGE(0, 0)
    __syncthreads();

    int cur = 0;
    for (int kt = 0; kt < 16; kt++) {
        if (kt < 15) STAGE(cur ^ 1, kt + 1)

        short8 af[4];
#pragma unroll
        for (int mi = 0; mi < 4; mi++) {
            int rowb = (mi < 2) ? (wave_m * 32 + mi * 16) : (64 + wave_m * 32 + (mi - 2) * 16);
            int row = rowb + l15;
            int qq = (row >> 1) & 3;
            af[mi] = *(const short8*)(Wlds[cur] + row * 64 + ((g ^ qq) * 16));
        }
#pragma unroll
        for (int ni = 0; ni < 2; ni++) {
            int col = wave_n * 32 + ni * 16 + l15;
            int cs = col ^ ((g & 1) << 3);
            const unsigned short* yb = Ysh[cur] + (8 * g) * 64 + cs;
            short8 bh;
            bh[0] = (short)yb[0 * 64];
            bh[1] = (short)yb[1 * 64];
            bh[2] = (short)yb[2 * 64];
            bh[3] = (short)yb[3 * 64];
            bh[4] = (short)yb[4 * 64];
            bh[5] = (short)yb[5 * 64];
            bh[6] = (short)yb[6 * 64];
            bh[7] = (short)yb[7 * 64];
#pragma unroll
            for (int mi = 0; mi < 4; mi++) {
                acc[mi][ni] = __builtin_amdgcn_mfma_f32_16x16x32_bf16(af[mi], bh, acc[mi][ni], 0, 0, 0);
            }
        }
        __syncthreads();
        cur ^= 1;
    }
#undef STAGE

#pragma unroll
    for (int mi = 0; mi < 2; mi++) {
        int dbase = d0 + wave_m * 32 + mi * 16 + (g << 2);
#pragma unroll
        for (int r = 0; r < 4; r++) {
            int d = dbase + r;
            float b1 = bias[d], b2 = bias[DMOUT + d];
#pragma unroll
            for (int ni = 0; ni < 2; ni++) {
                int l = l0 + wave_n * 32 + ni * 16 + l15;
                float z1 = acc[mi][ni][r] + b1;
                float z2 = acc[mi + 2][ni][r] + b2;
                out[((size_t)(b * DMOUT + d)) * LL + l] = z1 * (1.0f / (1.0f + __expf(-z2)));
            }
        }
    }
}

extern "C" void kernel_launch(void* const* d_in, const int* in_sizes, int n_in,
                              void* d_out, int out_size, void* d_ws, size_t ws_size,
                              hipStream_t stream) {
    const float* u      = (const float*)d_in[0];
    const float* log_dt = (const float*)d_in[1];
    const float* A_re   = (const float*)d_in[2];
    const float* A_im   = (const float*)d_in[3];
    const float* B_re   = (const float*)d_in[4];
    const float* B_im   = (const float*)d_in[5];
    const float* C_re   = (const float*)d_in[6];
    const float* C_im   = (const float*)d_in[7];
    const float* D      = (const float*)d_in[8];
    const float* W      = (const float*)d_in[9];
    const float* bias   = (const float*)d_in[10];
    float* out = (float*)d_out;

    char* ws = (char*)d_ws;
    unsigned short* yhi = (unsigned short*)ws;                     // 16,777,216 B
    unsigned* A3t = (unsigned*)(ws + 16777216);                    //  8,388,608 B
    unsigned* Et  = (unsigned*)(ws + 16777216 + 8388608);          //  8,388,608 B
    unsigned short* whi = (unsigned short*)(ws + 33554432);        //  1,048,576 B (total 34.6 MB)
    int preW = (ws_size >= (size_t)(33554432 + 1048576)) ? 1 : 0;

    prep_kernel<<<HH, 256, 0, stream>>>(log_dt, A_re, A_im, B_re, B_im, C_re, C_im,
                                        W, A3t, Et, whi, preW);
    ssm_kernel<<<dim3(HH, BB / 2), 256, 0, stream>>>(u, log_dt, A_re, A_im, B_re, B_im,
                                                     C_re, C_im, D, A3t, Et, yhi);
    gemm_glu_mfma<<<dim3(64, 8, BB), 256, 0, stream>>>(yhi, W, whi, bias, out, preW);
}